// Round 13
// baseline (739.563 us; speedup 1.0000x reference)
//
#include <hip/hip_runtime.h>
#include <hip/hip_bf16.h>

#define HDIM 256
#define NEG_SLOPE 0.2f
#define NB 128          // blocks for hist/scatter
#define SLICES 8        // edge slices per dst in the big-degree aggregator
#define TBN 64
#define TBK 32

typedef __attribute__((ext_vector_type(8))) short bf16x8;
typedef __attribute__((ext_vector_type(4))) float f32x4;

// split-bf16: x ~= bf16(hi) + bf16(lo); stored as two separate ushort arrays
__device__ inline uint f2pl(float x) {
  __hip_bfloat16 h = __float2bfloat16(x);
  ushort hi = *(ushort*)&h;
  float r = x - __bfloat162float(h);
  __hip_bfloat16 l = __float2bfloat16(r);
  ushort lo = *(ushort*)&l;
  return (uint)hi | ((uint)lo << 16);
}
__device__ inline ushort f2b(float x) {
  __hip_bfloat16 h = __float2bfloat16(x);
  return *(ushort*)&h;
}
__device__ inline float b2f(ushort u) {
  uint x = ((uint)u) << 16;
  return __int_as_float((int)x);
}

static inline int cdiv(int a, int b) { return (a + b - 1) / b; }

// ---------------------------------------------------------------- utilities
__global__ void fillf_kernel(float* __restrict__ p, float v, int n) {
  int i = blockIdx.x * blockDim.x + threadIdx.x;
  if (i < n) p[i] = v;
}

__global__ void fill_out2_kernel(float* __restrict__ out, const float* __restrict__ b3, int M) {
  int i = blockIdx.x * 256 + threadIdx.x;
  if (i >= M) return;
  out[(size_t)i * 2 + 0] = b3[0];
  out[(size_t)i * 2 + 1] = b3[1];
}

// W[K][N] fp32 -> WTh/WTl[N][K] split
__global__ void wconv_split_kernel(const float* __restrict__ W,
                                   ushort* __restrict__ WTh, ushort* __restrict__ WTl,
                                   int K, int N) {
  int i = blockIdx.x * 256 + threadIdx.x;
  if (i >= K * N) return;
  int k = i / N, n = i - k * N;
  uint p = f2pl(W[i]);
  WTh[(size_t)n * K + k] = (ushort)(p & 0xffff);
  WTl[(size_t)n * K + k] = (ushort)(p >> 16);
}

// batched layer-weight conversion: all 3 edge types x L layers in one launch
__global__ void wconv_split3_kernel(
    const float* __restrict__ Wpp, const float* __restrict__ Wdp, const float* __restrict__ Wcp,
    ushort* __restrict__ WTpph, ushort* __restrict__ WTppl,
    ushort* __restrict__ WTdph, ushort* __restrict__ WTdpl,
    ushort* __restrict__ WTcph, ushort* __restrict__ WTcpl, int L) {
  const int per = HDIM * HDIM;
  int i = blockIdx.x * 256 + threadIdx.x;
  if (i >= 3 * L * per) return;
  int mat = i / per;
  int r = i - mat * per;
  int l = mat / 3, ty = mat - l * 3;
  const float* W = (ty == 0 ? Wpp : ty == 1 ? Wdp : Wcp) + (size_t)l * per;
  ushort* Th = (ty == 0 ? WTpph : ty == 1 ? WTdph : WTcph) + (size_t)l * per;
  ushort* Tl = (ty == 0 ? WTppl : ty == 1 ? WTdpl : WTcpl) + (size_t)l * per;
  int k = r >> 8, n = r & (HDIM - 1);    // r = k*HDIM + n
  uint p = f2pl(W[r]);
  Th[(size_t)n * HDIM + k] = (ushort)(p & 0xffff);
  Tl[(size_t)n * HDIM + k] = (ushort)(p >> 16);
}

__global__ void f32_to_split_kernel(const float* __restrict__ in,
                                    ushort* __restrict__ oh, ushort* __restrict__ ol, int n) {
  int i = blockIdx.x * 256 + threadIdx.x;
  if (i >= n) return;
  uint p = f2pl(in[i]);
  oh[i] = (ushort)(p & 0xffff);
  ol[i] = (ushort)(p >> 16);
}

// wv[b][k] = sum_n W[k][n]*a[n]  (the folded attention vector W @ a)
__global__ __launch_bounds__(256) void matvec_all_kernel(
    const float* __restrict__ Wpp, const float* __restrict__ aspp, const float* __restrict__ adpp,
    const float* __restrict__ Wdp, const float* __restrict__ asdp, const float* __restrict__ addp,
    const float* __restrict__ Wcp, const float* __restrict__ ascp, const float* __restrict__ adcp,
    float* __restrict__ wv) {
  int b = blockIdx.x;
  int l = b / 6, r = b - l * 6, type = r >> 1, isd = r & 1;
  const float* W = (type == 0 ? Wpp : type == 1 ? Wdp : Wcp) + (size_t)l * HDIM * HDIM;
  const float* a = (type == 0 ? (isd ? adpp : aspp)
                  : type == 1 ? (isd ? addp : asdp)
                              : (isd ? adcp : ascp)) + (size_t)l * HDIM;
  int k = threadIdx.x;
  const float4* Wr = (const float4*)(W + (size_t)k * HDIM);
  float s = 0.f;
#pragma unroll 8
  for (int n4 = 0; n4 < HDIM / 4; ++n4) {
    float4 w = Wr[n4];
    float4 av = *(const float4*)(a + n4 * 4);
    s += w.x * av.x + w.y * av.y + w.z * av.z + w.w * av.w;
  }
  wv[(size_t)b * HDIM + k] = s;
}

// layer-0 protein prep: bf16 copy of prot_emb + the two pp rowdots, one pass
__global__ __launch_bounds__(256) void prep_p_kernel(
    const float* __restrict__ in, ushort* __restrict__ outb,
    const float* __restrict__ a1, const float* __restrict__ a2,
    float* __restrict__ o1, float* __restrict__ o2, int n) {
  int row = blockIdx.x * 4 + (threadIdx.x >> 6);
  if (row >= n) return;
  int lane = threadIdx.x & 63;
  float s1 = 0.f, s2 = 0.f;
#pragma unroll
  for (int u = 0; u < 4; ++u) {
    int c = lane + u * 64;
    float hv = in[(size_t)row * HDIM + c];
    outb[(size_t)row * HDIM + c] = f2b(hv);
    s1 += hv * a1[c];
    s2 += hv * a2[c];
  }
#pragma unroll
  for (int off = 32; off; off >>= 1) {
    s1 += __shfl_down(s1, off);
    s2 += __shfl_down(s2, off);
  }
  if (lane == 0) { o1[row] = s1; o2[row] = s2; }
}

// h1 combine -> split planes (P3 carries bias b1). Done ONCE per element.
__global__ __launch_bounds__(256) void combine_h1_kernel(
    const float* __restrict__ P1, const float* __restrict__ P2, const float* __restrict__ P3,
    const int* __restrict__ g1, const int* __restrict__ g2, const int* __restrict__ g3,
    int row0, ushort* __restrict__ h1h, ushort* __restrict__ h1l, int M, int K) {
  int t = blockIdx.x * 256 + threadIdx.x;
  int kq = K >> 2;
  if (t >= M * kq) return;
  int row = t / kq, c4 = t - row * kq;
  int bi = row0 + row;
  size_t o = (size_t)c4 * 4;
  float4 a = *(const float4*)(P1 + (size_t)g1[bi] * K + o);
  float4 b = *(const float4*)(P2 + (size_t)g2[bi] * K + o);
  float4 c = *(const float4*)(P3 + (size_t)g3[bi] * K + o);
  uint p0 = f2pl(fmaxf(a.x + b.x + c.x, 0.f));
  uint p1 = f2pl(fmaxf(a.y + b.y + c.y, 0.f));
  uint p2 = f2pl(fmaxf(a.z + b.z + c.z, 0.f));
  uint p3 = f2pl(fmaxf(a.w + b.w + c.w, 0.f));
  ushort4 h = {(ushort)(p0 & 0xffff), (ushort)(p1 & 0xffff), (ushort)(p2 & 0xffff), (ushort)(p3 & 0xffff)};
  ushort4 l = {(ushort)(p0 >> 16), (ushort)(p1 >> 16), (ushort)(p2 >> 16), (ushort)(p3 >> 16)};
  *(ushort4*)(h1h + (size_t)row * K + o) = h;
  *(ushort4*)(h1l + (size_t)row * K + o) = l;
}

// ---------------------------------------------------------------- MFMA GEMM
// C = act(A@B + bias), fp32 out. A,B pre-split hi/lo ushort arrays.
// Round-13: A staged through LDS (rotated-slot conflict-free layout,
// 2-deep register pipeline); B fragments loaded DIRECTLY from global with a
// one-tile register prefetch. B's fragment mapping is lane-contiguous
// (row n0+wn*32+t*16+l16, 8 ushorts at k0+quad*8) and the B panel is small
// and shared by every M-block -> L1/L2-resident by construction (unlike
// round-11's A-direct, where 16KB/k-step of per-block-unique data thrashed
// L1). Deletes B's global->reg->LDS->reg round trip: LDS/block-k-step
// 48KB -> 32KB, LDS size 48KB -> 32KB. Bitwise-identical math.
// M fast grid dim (XCD-local A-panel reuse). FUSE3: fused head3 epilogue.
template <int TBM_, int ACT, int FUSE3>
__global__ __launch_bounds__(256) void mfma_gemm(
    const ushort* __restrict__ Ahg, const ushort* __restrict__ Alg,
    const ushort* __restrict__ Bhg, const ushort* __restrict__ Blg,
    int ldb, const float* __restrict__ bias, const float* __restrict__ W3g,
    float* __restrict__ C, int M, int N, int K) {
  __shared__ __align__(16) ushort Ah[2][4][TBM_ / 16][16][8];
  __shared__ __align__(16) ushort Al[2][4][TBM_ / 16][16][8];

  constexpr int NU = TBM_ / 64;   // A 16B-load instrs per thread (64 rows/round)
  constexpr int TM = TBM_ / 32;   // 16-row tiles per wave (M dir)

  const int tid = threadIdx.x;
  const int lane = tid & 63;
  const int wid = tid >> 6;
  const int wm = wid & 1, wn = wid >> 1;
  const int l16 = lane & 15;
  const int quad = lane >> 4;
  const int m0 = blockIdx.x * TBM_;
  const int n0 = blockIdx.y * TBN;

  const int gq = lane & 3;         // k-granule (8 ushorts = 16B) this lane stages
  const int co = gq * 8;           // ushort col within 32-ushort k-chunk
  const int r4 = lane >> 2;        // row within 16-row stripe
  const int wslot = (r4 + 2 * gq) & 15;          // rotated write slot
  const int rslot = (l16 + 2 * quad) & 15;       // rotated read slot

  // B fragment base offsets (this lane's OWN MFMA fragment)
  size_t boff[2];
#pragma unroll
  for (int t = 0; t < 2; ++t)
    boff[t] = (size_t)(n0 + wn * 32 + t * 16 + l16) * ldb + quad * 8;

  uint4 rah0[NU], ral0[NU];        // A register set 0
  uint4 rah1[NU], ral1[NU];        // A register set 1
  bf16x8 fbh0[2], fbl0[2];         // B fragment set 0
  bf16x8 fbh1[2], fbl1[2];         // B fragment set 1

  auto LOADA = [&](uint4* rah, uint4* ral, int k0) {
#pragma unroll
    for (int u = 0; u < NU; ++u) {
      int r = wid * (TBM_ / 4) + r4 + 16 * u;
      int gm = m0 + r;
      if (gm < M) {
        size_t o = (size_t)gm * K + k0 + co;
        rah[u] = *(const uint4*)(Ahg + o);
        ral[u] = *(const uint4*)(Alg + o);
      } else {
        rah[u] = make_uint4(0, 0, 0, 0);
        ral[u] = make_uint4(0, 0, 0, 0);
      }
    }
  };
  auto LOADB = [&](bf16x8* bh, bf16x8* bl, int k0) {
#pragma unroll
    for (int t = 0; t < 2; ++t) {
      bh[t] = *(const bf16x8*)(Bhg + boff[t] + k0);
      bl[t] = *(const bf16x8*)(Blg + boff[t] + k0);
    }
  };
  auto STORE = [&](const uint4* rah, const uint4* ral, int b) {
#pragma unroll
    for (int u = 0; u < NU; ++u) {
      int ch = (wid * (TBM_ / 4) + 16 * u) >> 4;   // row chunk (r4 < 16)
      *(uint4*)&Ah[b][gq][ch][wslot][0] = rah[u];
      *(uint4*)&Al[b][gq][ch][wslot][0] = ral[u];
    }
  };

  f32x4 acc[TM][2];
#pragma unroll
  for (int i = 0; i < TM; ++i)
#pragma unroll
    for (int j = 0; j < 2; ++j) acc[i][j] = (f32x4){0.f, 0.f, 0.f, 0.f};

  auto COMPUTE = [&](int b, const bf16x8* bhf, const bf16x8* blf) {
    bf16x8 ahf[TM], alf[TM];
#pragma unroll
    for (int t = 0; t < TM; ++t) {
      int ch = wm * (TBM_ / 32) + t;
      ahf[t] = *(const bf16x8*)&Ah[b][quad][ch][rslot][0];
      alf[t] = *(const bf16x8*)&Al[b][quad][ch][rslot][0];
    }
#pragma unroll
    for (int tm = 0; tm < TM; ++tm)
#pragma unroll
      for (int tn = 0; tn < 2; ++tn) {
        acc[tm][tn] = __builtin_amdgcn_mfma_f32_16x16x32_bf16(ahf[tm], bhf[tn], acc[tm][tn], 0, 0, 0);
        acc[tm][tn] = __builtin_amdgcn_mfma_f32_16x16x32_bf16(ahf[tm], blf[tn], acc[tm][tn], 0, 0, 0);
        acc[tm][tn] = __builtin_amdgcn_mfma_f32_16x16x32_bf16(alf[tm], bhf[tn], acc[tm][tn], 0, 0, 0);
      }
  };

  // prologue: A tiles 0,1 in regs; tile0 -> buf0; B frag for tile 0
  const int NK = K / TBK;            // even, >= 4 for all shapes used
  LOADA(rah0, ral0, 0);
  LOADA(rah1, ral1, TBK);
  STORE(rah0, ral0, 0);
  LOADB(fbh0, fbl0, 0);
  int k = 2 * TBK;
  for (int t = 0; t < (NK - 2) / 2; ++t) {
    __syncthreads();
    LOADA(rah0, ral0, k);             // A tile t+2 in flight
    LOADB(fbh1, fbl1, k - TBK);       // B frag for tile t+1
    COMPUTE(0, fbh0, fbl0);           // tile t (buf0)
    STORE(rah1, ral1, 1);             // A tile t+1 -> buf1
    k += TBK;
    __syncthreads();
    LOADA(rah1, ral1, k);
    LOADB(fbh0, fbl0, k - TBK);       // B frag for tile t+2
    COMPUTE(1, fbh1, fbl1);
    STORE(rah0, ral0, 0);
    k += TBK;
  }
  __syncthreads();
  LOADB(fbh1, fbl1, (NK - 1) * TBK);
  COMPUTE(0, fbh0, fbl0);             // tile NK-2
  STORE(rah1, ral1, 1);
  __syncthreads();
  COMPUTE(1, fbh1, fbl1);             // tile NK-1

  if (FUSE3) {
    // relu(acc+bias) . W3 -> per-row (s0,s1); reduce over the 16 l16 lanes
    // sharing a row; leader atomicAdds into b3-prefilled C[M][2].
#pragma unroll
    for (int tm = 0; tm < TM; ++tm) {
#pragma unroll
      for (int r = 0; r < 4; ++r) {
        int row = m0 + wm * (TBM_ / 2) + tm * 16 + quad * 4 + r;
        float s0 = 0.f, s1 = 0.f;
#pragma unroll
        for (int tn = 0; tn < 2; ++tn) {
          int col = n0 + wn * 32 + tn * 16 + l16;
          float v = fmaxf(acc[tm][tn][r] + bias[col], 0.f);
          s0 += v * W3g[col * 2 + 0];
          s1 += v * W3g[col * 2 + 1];
        }
#pragma unroll
        for (int o = 1; o < 16; o <<= 1) {
          s0 += __shfl_xor(s0, o);
          s1 += __shfl_xor(s1, o);
        }
        if (l16 == 0 && row < M) {
          atomicAdd(&C[(size_t)row * 2 + 0], s0);
          atomicAdd(&C[(size_t)row * 2 + 1], s1);
        }
      }
    }
  } else {
#pragma unroll
    for (int tn = 0; tn < 2; ++tn) {
      int col = n0 + wn * 32 + tn * 16 + l16;
      float bv = bias ? bias[col] : 0.f;
#pragma unroll
      for (int tm = 0; tm < TM; ++tm) {
#pragma unroll
        for (int r = 0; r < 4; ++r) {
          int row = m0 + wm * (TBM_ / 2) + tm * 16 + quad * 4 + r;
          if (row >= M) continue;
          float v = acc[tm][tn][r] + bv;
          if (ACT == 1) v = fmaxf(v, 0.f);
          C[(size_t)row * N + col] = v;
        }
      }
    }
  }
}

template <int TBM_, int ACT>
static void gemm_launch(hipStream_t s,
                        const ushort* Ahg, const ushort* Alg,
                        const ushort* Bhg, const ushort* Blg,
                        int ldb, const float* bias, float* C,
                        int M, int N, int K) {
  dim3 g(cdiv(M, TBM_), N / TBN);   // M fast: XCD-local A-panel reuse
  mfma_gemm<TBM_, ACT, 0><<<g, 256, 0, s>>>(Ahg, Alg, Bhg, Blg, ldb, bias, nullptr, C, M, N, K);
}

// fused-W2 at TBM=128 (round-12's TBM=64 regressed: FETCH 37->65MB killed
// the A-panel L2 economy; occupancy gain didn't cover it)
static void gemm_launch_f3(hipStream_t s,
                           const ushort* Ahg, const ushort* Alg,
                           const ushort* Bhg, const ushort* Blg,
                           int ldb, const float* bias, const float* W3,
                           float* C, int M, int N, int K) {
  dim3 g(cdiv(M, 128), N / TBN);
  mfma_gemm<128, 1, 1><<<g, 256, 0, s>>>(Ahg, Alg, Bhg, Blg, ldb, bias, W3, C, M, N, K);
}

// ---------------------------------------------------------------- row dots
__global__ __launch_bounds__(256) void rowdot_kernel(
    const float* __restrict__ H, const float* __restrict__ a,
    float* __restrict__ out, int n) {
  int row = blockIdx.x * 4 + (threadIdx.x >> 6);
  if (row >= n) return;
  int lane = threadIdx.x & 63;
  const float* h = H + (size_t)row * HDIM;
  float s = 0.f;
#pragma unroll
  for (int u = 0; u < 4; ++u) {
    int c = lane + u * 64;
    s += h[c] * a[c];
  }
#pragma unroll
  for (int off = 32; off; off >>= 1) s += __shfl_down(s, off);
  if (lane == 0) out[row] = s;
}

// ---------------------------------------------------------------- counting sort by dst
__global__ __launch_bounds__(256) void hist_kernel(
    const int* __restrict__ src, const int* __restrict__ dst, int E, int nloops,
    int Nd, int* __restrict__ offs) {
  extern __shared__ int bins[];
  int tot = E + nloops;
  int chunk = (tot + NB - 1) / NB;
  int b = blockIdx.x;
  int s0 = b * chunk, s1 = min(s0 + chunk, tot);
  for (int i = threadIdx.x; i < Nd; i += 256) bins[i] = 0;
  __syncthreads();
  for (int i = s0 + threadIdx.x; i < s1; i += 256) {
    int d = (i < E) ? dst[i] : (i - E);
    atomicAdd(&bins[d], 1);
  }
  __syncthreads();
  for (int i = threadIdx.x; i < Nd; i += 256) offs[(size_t)i * NB + b] = bins[i];
}

__global__ __launch_bounds__(256) void scan_bins_kernel(
    int* __restrict__ offs, int* __restrict__ binsum, int Nd) {
  int d = blockIdx.x * 4 + (threadIdx.x >> 6);
  if (d >= Nd) return;
  int lane = threadIdx.x & 63;
  int* p = offs + (size_t)d * NB;
  int v0 = p[2 * lane], v1 = p[2 * lane + 1];
  int s = v0 + v1;
  int t = s;
#pragma unroll
  for (int o = 1; o < 64; o <<= 1) { int u = __shfl_up(t, o); if (lane >= o) t += u; }
  int excl = t - s;
  p[2 * lane] = excl;
  p[2 * lane + 1] = excl + v0;
  if (lane == 63) binsum[d] = t;
}

__global__ __launch_bounds__(256) void scan_base_kernel(
    const int* __restrict__ binsum, int* __restrict__ rowptr, int Nd) {
  __shared__ int wsum[4];
  __shared__ int carry;
  if (threadIdx.x == 0) carry = 0;
  __syncthreads();
  int lane = threadIdx.x & 63, w = threadIdx.x >> 6;
  for (int t0 = 0; t0 < Nd; t0 += 256) {
    int i = t0 + threadIdx.x;
    int v = (i < Nd) ? binsum[i] : 0;
    int t = v;
#pragma unroll
    for (int o = 1; o < 64; o <<= 1) { int u = __shfl_up(t, o); if (lane >= o) t += u; }
    if (lane == 63) wsum[w] = t;
    __syncthreads();
    int add = carry;
    for (int k = 0; k < w; ++k) add += wsum[k];
    if (i < Nd) rowptr[i] = t - v + add;
    __syncthreads();
    if (threadIdx.x == 0) carry += wsum[0] + wsum[1] + wsum[2] + wsum[3];
    __syncthreads();
  }
  if (threadIdx.x == 0) rowptr[Nd] = carry;
}

__global__ __launch_bounds__(256) void scatter_kernel(
    const int* __restrict__ src, const int* __restrict__ dst, int E, int nloops,
    int Nd, const int* __restrict__ offs, const int* __restrict__ rowptr,
    uint* __restrict__ sd) {
  extern __shared__ int bins[];
  int tot = E + nloops;
  int chunk = (tot + NB - 1) / NB;
  int b = blockIdx.x;
  int s0 = b * chunk, s1 = min(s0 + chunk, tot);
  for (int i = threadIdx.x; i < Nd; i += 256) bins[i] = 0;
  __syncthreads();
  for (int i = s0 + threadIdx.x; i < s1; i += 256) {
    int s_, d_;
    if (i < E) { s_ = src[i]; d_ = dst[i]; }
    else       { s_ = d_ = i - E; }
    int local = atomicAdd(&bins[d_], 1);
    int pos = rowptr[d_] + offs[(size_t)d_ * NB + b] + local;
    sd[pos] = (uint)s_ | ((uint)d_ << 16);
  }
}

// ---------------------------------------------------------------- fused GAT edge phase
__global__ __launch_bounds__(256) void gat_agg_split(
    const int* __restrict__ rowptr, const uint* __restrict__ sd,
    const float* __restrict__ als, const float* __restrict__ ald,
    const ushort* __restrict__ Xb,
    ushort* __restrict__ aggh, ushort* __restrict__ aggl, int n) {
  int d = blockIdx.x * 4 + (threadIdx.x >> 6);
  if (d >= n) return;
  int lane = threadIdx.x & 63;
  int r0 = rowptr[d], r1 = rowptr[d + 1];
  float aldd = ald[d];
  float dsum = 0.f;
  for (int j = r0 + lane; j < r1; j += 64) {
    float e = als[sd[j] & 0xffff] + aldd;
    e = (e > 0.f) ? e : NEG_SLOPE * e;
    dsum += __expf(e);
  }
#pragma unroll
  for (int o = 32; o; o >>= 1) dsum += __shfl_xor(dsum, o);
  float rden = 1.f / (dsum + 1e-16f);

  float4 acc = make_float4(0.f, 0.f, 0.f, 0.f);
  for (int b = r0; b < r1; b += 64) {
    int j = b + lane;
    float exv = 0.f; int srcv = 0;
    if (j < r1) {
      uint p = sd[j];
      srcv = p & 0xffff;
      float e = als[srcv] + aldd;
      e = (e > 0.f) ? e : NEG_SLOPE * e;
      exv = __expf(e) * rden;
    }
    int cnt = min(64, r1 - b);
    for (int t0 = 0; t0 < cnt; t0 += 8) {
      float cf[8]; int sv[8];
#pragma unroll
      for (int u = 0; u < 8; ++u) {
        cf[u] = __shfl(exv, t0 + u);
        sv[u] = __shfl(srcv, t0 + u);
      }
      ushort4 hv[8];
#pragma unroll
      for (int u = 0; u < 8; ++u)
        hv[u] = *(const ushort4*)(Xb + (size_t)sv[u] * HDIM + lane * 4);
#pragma unroll
      for (int u = 0; u < 8; ++u) {
        acc.x += cf[u] * b2f(hv[u].x);
        acc.y += cf[u] * b2f(hv[u].y);
        acc.z += cf[u] * b2f(hv[u].z);
        acc.w += cf[u] * b2f(hv[u].w);
      }
    }
  }
  uint p0 = f2pl(acc.x), p1 = f2pl(acc.y), p2 = f2pl(acc.z), p3 = f2pl(acc.w);
  ushort4 h = {(ushort)(p0 & 0xffff), (ushort)(p1 & 0xffff), (ushort)(p2 & 0xffff), (ushort)(p3 & 0xffff)};
  ushort4 l = {(ushort)(p0 >> 16), (ushort)(p1 >> 16), (ushort)(p2 >> 16), (ushort)(p3 >> 16)};
  *(ushort4*)(aggh + (size_t)d * HDIM + lane * 4) = h;
  *(ushort4*)(aggl + (size_t)d * HDIM + lane * 4) = l;
}

__global__ __launch_bounds__(256) void gat_agg_slice(
    const int* __restrict__ rowptr, const uint* __restrict__ sd,
    const float* __restrict__ als, const float* __restrict__ ald,
    const ushort* __restrict__ Xb, float* __restrict__ out32, int n) {
  int d = blockIdx.x / SLICES;
  int sl = blockIdx.x - d * SLICES;
  if (d >= n) return;
  int lane = threadIdx.x & 63, w = threadIdx.x >> 6;
  int r0 = rowptr[d], r1 = rowptr[d + 1];
  float aldd = ald[d];
  float dsum = 0.f;
  for (int j = r0 + threadIdx.x; j < r1; j += 256) {
    float e = als[sd[j] & 0xffff] + aldd;
    e = (e > 0.f) ? e : NEG_SLOPE * e;
    dsum += __expf(e);
  }
#pragma unroll
  for (int o = 32; o; o >>= 1) dsum += __shfl_xor(dsum, o);
  __shared__ float wd[4];
  if (lane == 0) wd[w] = dsum;
  __syncthreads();
  float rden = 1.f / (wd[0] + wd[1] + wd[2] + wd[3] + 1e-16f);
  int deg = r1 - r0;
  int per_b = (deg + SLICES - 1) / SLICES;
  int b0 = r0 + sl * per_b, b1 = min(b0 + per_b, r1);
  int wdeg = b1 - b0;
  if (wdeg <= 0) return;
  int per_w = (wdeg + 3) >> 2;
  int w0 = b0 + w * per_w, w1 = min(w0 + per_w, b1);

  float4 acc = make_float4(0.f, 0.f, 0.f, 0.f);
  for (int b = w0; b < w1; b += 64) {
    int j = b + lane;
    float exv = 0.f; int srcv = 0;
    if (j < w1) {
      uint p = sd[j];
      srcv = p & 0xffff;
      float e = als[srcv] + aldd;
      e = (e > 0.f) ? e : NEG_SLOPE * e;
      exv = __expf(e) * rden;
    }
    int cnt = min(64, w1 - b);
    for (int t0 = 0; t0 < cnt; t0 += 8) {
      float cf[8]; int sv[8];
#pragma unroll
      for (int u = 0; u < 8; ++u) {
        cf[u] = __shfl(exv, t0 + u);
        sv[u] = __shfl(srcv, t0 + u);
      }
      ushort4 hv[8];
#pragma unroll
      for (int u = 0; u < 8; ++u)
        hv[u] = *(const ushort4*)(Xb + (size_t)sv[u] * HDIM + lane * 4);
#pragma unroll
      for (int u = 0; u < 8; ++u) {
        acc.x += cf[u] * b2f(hv[u].x);
        acc.y += cf[u] * b2f(hv[u].y);
        acc.z += cf[u] * b2f(hv[u].z);
        acc.w += cf[u] * b2f(hv[u].w);
      }
    }
  }
  float* o = out32 + (size_t)d * HDIM + lane * 4;
  atomicAdd(o + 0, acc.x); atomicAdd(o + 1, acc.y);
  atomicAdd(o + 2, acc.z); atomicAdd(o + 3, acc.w);
}

// ---------------------------------------------------------------- norms
__global__ __launch_bounds__(256) void l2norm_f32b_dots_kernel(
    const float* __restrict__ in, float* __restrict__ outf, ushort* __restrict__ outb,
    const float* __restrict__ v1, const float* __restrict__ v2,
    const float* __restrict__ v3, const float* __restrict__ v4,
    float* __restrict__ o1, float* __restrict__ o2,
    float* __restrict__ o3, float* __restrict__ o4, int n) {
  int row = blockIdx.x * 4 + (threadIdx.x >> 6);
  if (row >= n) return;
  int lane = threadIdx.x & 63;
  float v[4];
  float ss = 0.f;
#pragma unroll
  for (int u = 0; u < 4; ++u) {
    float t = in[(size_t)row * HDIM + lane + u * 64];
    v[u] = t; ss += t * t;
  }
#pragma unroll
  for (int off = 32; off; off >>= 1) ss += __shfl_xor(ss, off);
  float sc = 1.0f / fmaxf(sqrtf(ss), 1e-12f);
  float d1 = 0.f, d2 = 0.f, d3 = 0.f, d4 = 0.f;
#pragma unroll
  for (int u = 0; u < 4; ++u) {
    float f = v[u] * sc;
    int c = lane + u * 64;
    outf[(size_t)row * HDIM + c] = f;
    outb[(size_t)row * HDIM + c] = f2b(f);
    d1 += f * v1[c];
    d2 += f * v2[c];
    if (o3) { d3 += f * v3[c]; d4 += f * v4[c]; }
  }
#pragma unroll
  for (int off = 32; off; off >>= 1) {
    d1 += __shfl_xor(d1, off);
    d2 += __shfl_xor(d2, off);
    if (o3) { d3 += __shfl_xor(d3, off); d4 += __shfl_xor(d4, off); }
  }
  if (lane == 0) {
    o1[row] = d1; o2[row] = d2;
    if (o3) { o3[row] = d3; o4[row] = d4; }
  }
}

// fp32 in -> l2norm -> split hi/lo out
__global__ __launch_bounds__(256) void l2norm_split_kernel(
    const float* __restrict__ in,
    ushort* __restrict__ oh, ushort* __restrict__ ol, int n) {
  int row = blockIdx.x * 4 + (threadIdx.x >> 6);
  if (row >= n) return;
  int lane = threadIdx.x & 63;
  float v[4];
  float ss = 0.f;
#pragma unroll
  for (int u = 0; u < 4; ++u) {
    int c = lane + u * 64;
    float t = in[(size_t)row * HDIM + c];
    v[u] = t;
    ss += t * t;
  }
#pragma unroll
  for (int off = 32; off; off >>= 1) ss += __shfl_xor(ss, off);
  float sc = 1.0f / fmaxf(sqrtf(ss), 1e-12f);
#pragma unroll
  for (int u = 0; u < 4; ++u) {
    int c = lane + u * 64;
    uint p = f2pl(v[u] * sc);
    oh[(size_t)row * HDIM + c] = (ushort)(p & 0xffff);
    ol[(size_t)row * HDIM + c] = (ushort)(p >> 16);
  }
}

// ---------------------------------------------------------------- host side
static void build_sorted(hipStream_t stream,
                         const int* src, const int* dst, int E, int nloops, int Nd,
                         int* offs, int* binsum, int* rowptr, uint* sd) {
  size_t lds = (size_t)Nd * sizeof(int);
  hist_kernel<<<NB, 256, lds, stream>>>(src, dst, E, nloops, Nd, offs);
  scan_bins_kernel<<<cdiv(Nd, 4), 256, 0, stream>>>(offs, binsum, Nd);
  scan_base_kernel<<<1, 256, 0, stream>>>(binsum, rowptr, Nd);
  scatter_kernel<<<NB, 256, lds, stream>>>(src, dst, E, nloops, Nd, offs, rowptr, sd);
}

extern "C" void kernel_launch(void* const* d_in, const int* in_sizes, int n_in,
                              void* d_out, int out_size, void* d_ws, size_t ws_size,
                              hipStream_t stream) {
  const float* drug_emb = (const float*)d_in[0];
  const float* prot_emb = (const float*)d_in[1];
  const float* cell_emb = (const float*)d_in[2];
  const float* W_pp = (const float*)d_in[3];
  const float* as_pp = (const float*)d_in[4];
  const float* ad_pp = (const float*)d_in[5];
  const float* b_pp = (const float*)d_in[6];
  const float* W_dp = (const float*)d_in[7];
  const float* as_dp = (const float*)d_in[8];
  const float* ad_dp = (const float*)d_in[9];
  const float* b_dp = (const float*)d_in[10];
  const float* W_cp = (const float*)d_in[11];
  const float* as_cp = (const float*)d_in[12];
  const float* ad_cp = (const float*)d_in[13];
  const float* b_cp = (const float*)d_in[14];
  const float* W1 = (const float*)d_in[15];
  const float* b1 = (const float*)d_in[16];
  const float* W2 = (const float*)d_in[17];
  const float* b2 = (const float*)d_in[18];
  const float* W3 = (const float*)d_in[19];
  const float* b3 = (const float*)d_in[20];
  const int* edge_pp = (const int*)d_in[21];
  const int* edge_dp = (const int*)d_in[22];
  const int* edge_cp = (const int*)d_in[23];
  const int* drug1 = (const int*)d_in[24];
  const int* drug2 = (const int*)d_in[25];
  const int* cellb = (const int*)d_in[26];

  const int ND = in_sizes[0] / HDIM;   // 2000
  const int NP = in_sizes[1] / HDIM;   // 19000
  const int NC = in_sizes[2] / HDIM;   // 100
  const int L = in_sizes[3] / (HDIM * HDIM);  // 2
  const int E_pp = in_sizes[21] / 2;
  const int E_dp = in_sizes[22] / 2;
  const int E_cp = in_sizes[23] / 2;
  const int B = in_sizes[24];          // 8192
  (void)n_in; (void)out_size;

  const int* src_pp = edge_pp;          const int* dst_pp = edge_pp + E_pp;
  const int* src_dp = edge_dp;          const int* dst_dp = edge_dp + E_dp;
  const int* src_cp = edge_cp;          const int* dst_cp = edge_cp + E_cp;
  const int tot_pp = E_pp + NP, tot_dp = E_dp, tot_cp = E_cp;
  int maxN = NP > ND ? NP : ND; if (NC > maxN) maxN = NC;

  // ---------------- workspace
  char* wsb = (char*)d_ws;
  size_t off = 0;
  auto alloc = [&](size_t bytes) -> void* {
    void* p = wsb + off;
    off += (bytes + 255) & ~(size_t)255;
    return p;
  };

  float* Xp  = (float*)alloc((size_t)NP * HDIM * 4);    // protein state fp32
  ushort* Xpb = (ushort*)alloc((size_t)NP * HDIM * 2);  // protein state bf16 (gather)
  float* Xd  = (float*)alloc((size_t)ND * HDIM * 4);
  float* Xc  = (float*)alloc((size_t)NC * HDIM * 4);
  ushort* xdnh = (ushort*)alloc((size_t)ND * HDIM * 2);
  ushort* xdnl = (ushort*)alloc((size_t)ND * HDIM * 2);
  ushort* xcnh = (ushort*)alloc((size_t)NC * HDIM * 2);
  ushort* xcnl = (ushort*)alloc((size_t)NC * HDIM * 2);
  ushort* WTpph = (ushort*)alloc((size_t)L * HDIM * HDIM * 2);
  ushort* WTppl = (ushort*)alloc((size_t)L * HDIM * HDIM * 2);
  ushort* WTdph = (ushort*)alloc((size_t)L * HDIM * HDIM * 2);
  ushort* WTdpl = (ushort*)alloc((size_t)L * HDIM * HDIM * 2);
  ushort* WTcph = (ushort*)alloc((size_t)L * HDIM * HDIM * 2);
  ushort* WTcpl = (ushort*)alloc((size_t)L * HDIM * HDIM * 2);
  ushort* cth = (ushort*)alloc((size_t)NC * HDIM * 2);  // cp split staging
  ushort* ctl = (ushort*)alloc((size_t)NC * HDIM * 2);
  float* wv  = (float*)alloc((size_t)L * 6 * HDIM * 4); // folded W@a vectors
  float* pals = (float*)alloc((size_t)maxN * 4);        // pp src logits
  float* pald = (float*)alloc((size_t)maxN * 4);        // pp dst logits
  float* als1 = (float*)alloc((size_t)maxN * 4);        // dp src logits
  float* als2 = (float*)alloc((size_t)maxN * 4);        // cp src logits
  float* ald1 = (float*)alloc((size_t)maxN * 4);
  float* ald2 = (float*)alloc((size_t)maxN * 4);
  int* binsum = (int*)alloc((size_t)maxN * 4);
  int* rp_pp = (int*)alloc((size_t)(NP + 1) * 4);
  int* rp_dp = (int*)alloc((size_t)(ND + 1) * 4);
  int* rp_cp = (int*)alloc((size_t)(NC + 1) * 4);
  uint* sd_pp = (uint*)alloc((size_t)tot_pp * 4);
  uint* sd_dp = (uint*)alloc((size_t)tot_dp * 4);
  uint* sd_cp = (uint*)alloc((size_t)tot_cp * 4);
  float* out32 = (float*)alloc((size_t)NC * HDIM * 4);  // cp partial accumulator
  size_t S0 = off;

  // scratch S overlays: [offs] -> [aggh|aggl|tmp] -> [W1T*|W2T*|P1|P2|P3|h1*]
  int* offs = (int*)(wsb + S0);
  build_sorted(stream, src_pp, dst_pp, E_pp, NP, NP, offs, binsum, rp_pp, sd_pp);
  build_sorted(stream, src_dp, dst_dp, E_dp, 0, ND, offs, binsum, rp_dp, sd_dp);
  build_sorted(stream, src_cp, dst_cp, E_cp, 0, NC, offs, binsum, rp_cp, sd_cp);

  // ---- weight split planes (batched) + folded attention vectors + protein prep
  wconv_split3_kernel<<<cdiv(3 * L * HDIM * HDIM, 256), 256, 0, stream>>>(
      W_pp, W_dp, W_cp, WTpph, WTppl, WTdph, WTdpl, WTcph, WTcpl, L);
  matvec_all_kernel<<<L * 6, 256, 0, stream>>>(W_pp, as_pp, ad_pp, W_dp, as_dp, ad_dp,
                                               W_cp, as_cp, ad_cp, wv);
  // layer-0: Xpb bf16 copy + pp logits in one pass over prot_emb
  prep_p_kernel<<<cdiv(NP, 4), 256, 0, stream>>>(prot_emb, Xpb, wv + 0 * HDIM, wv + 1 * HDIM,
                                                 pals, pald, NP);

  size_t aggB = ((size_t)NP * HDIM * 2 + 255) & ~(size_t)255;
  ushort* aggh = (ushort*)(wsb + S0);
  ushort* aggl = (ushort*)(wsb + S0 + aggB);
  float* tmp = (float*)(wsb + S0 + 2 * aggB);

  for (int l = 0; l < L; ++l) {
    const int WOFF = l * HDIM * HDIM, VOFF = l * HDIM;
    const float* wvl = wv + (size_t)l * 6 * HDIM;
    bool last = (l == L - 1);
    const float* wvn = last ? wvl : wv + (size_t)(l + 1) * 6 * HDIM;
    const float* Xd_cur = (l == 0) ? drug_emb : Xd;
    const float* Xc_cur = (l == 0) ? cell_emb : Xc;

    // ---- p-p: aggregate x -> transform -> l2norm (+fused dots for dp/cp/next-pp)
    gat_agg_split<<<cdiv(NP, 4), 256, 0, stream>>>(rp_pp, sd_pp, pals, pald, Xpb, aggh, aggl, NP);
    gemm_launch<128, 0>(stream, aggh, aggl, WTpph + WOFF, WTppl + WOFF, HDIM,
                        b_pp + VOFF, tmp, NP, HDIM, HDIM);
    l2norm_f32b_dots_kernel<<<cdiv(NP, 4), 256, 0, stream>>>(
        tmp, Xp, Xpb,
        wvl + 2 * HDIM, wvl + 4 * HDIM,
        last ? nullptr : (wvn + 0 * HDIM), last ? nullptr : (wvn + 1 * HDIM),
        als1, als2, last ? nullptr : pals, last ? nullptr : pald, NP);

    rowdot_kernel<<<cdiv(ND, 4), 256, 0, stream>>>(Xd_cur, wvl + 3 * HDIM, ald1, ND);
    rowdot_kernel<<<cdiv(NC, 4), 256, 0, stream>>>(Xc_cur, wvl + 5 * HDIM, ald2, NC);

    // ---- d-p: aggregate then transform (M=ND)
    gat_agg_split<<<cdiv(ND, 4), 256, 0, stream>>>(rp_dp, sd_dp, als1, ald1, Xpb, aggh, aggl, ND);
    gemm_launch<64, 1>(stream, aggh, aggl, WTdph + WOFF, WTdpl + WOFF, HDIM,
                       b_dp + VOFF, Xd, ND, HDIM, HDIM);

    // ---- c-p: slice-aggregate -> split -> transform (M=NC)
    fillf_kernel<<<cdiv(NC * HDIM, 256), 256, 0, stream>>>(out32, 0.f, NC * HDIM);
    gat_agg_slice<<<NC * SLICES, 256, 0, stream>>>(rp_cp, sd_cp, als2, ald2, Xpb, out32, NC);
    f32_to_split_kernel<<<cdiv(NC * HDIM, 256), 256, 0, stream>>>(out32, cth, ctl, NC * HDIM);
    gemm_launch<64, 1>(stream, cth, ctl, WTcph + WOFF, WTcpl + WOFF, HDIM,
                       b_cp + VOFF, Xc, NC, HDIM, HDIM);
  }

  // ---------------- head
  l2norm_split_kernel<<<cdiv(ND, 4), 256, 0, stream>>>(Xd, xdnh, xdnl, ND);
  l2norm_split_kernel<<<cdiv(NC, 4), 256, 0, stream>>>(Xc, xcnh, xcnl, NC);

  const int N1 = 6 * HDIM;   // 1536
  const int N2 = 2 * HDIM;   // 512
  const int K1 = 3 * HDIM;   // 768
  ushort* W1Th = (ushort*)(wsb + S0);                   // [1536][768]
  ushort* W1Tl = W1Th + (size_t)N1 * K1;
  ushort* W2Th = W1Tl + (size_t)N1 * K1;                // [512][1536]
  ushort* W2Tl = W2Th + (size_t)N2 * N1;
  float* P1 = (float*)(W2Tl + (size_t)N2 * N1);         // [ND][1536]
  float* P2 = P1 + (size_t)ND * N1;
  float* P3 = P2 + (size_t)ND * N1;                     // [NC][1536]
  ushort* h1h = (ushort*)(P3 + (size_t)NC * N1);        // [CH][1536] split
  size_t wsz = ws_size ? ws_size : ((size_t)1 << 30);
  size_t fixed = S0 + ((size_t)N1 * K1 + (size_t)N2 * N1) * 4
               + ((size_t)(2 * ND + NC) * N1) * 4;
  int CH = 8192;
  while (CH > 1024 && fixed + (size_t)CH * N1 * 4 > wsz) CH >>= 1;
  ushort* h1l = h1h + (size_t)CH * N1;

  wconv_split_kernel<<<cdiv(K1 * N1, 256), 256, 0, stream>>>(W1, W1Th, W1Tl, K1, N1);
  wconv_split_kernel<<<cdiv(N1 * N2, 256), 256, 0, stream>>>(W2, W2Th, W2Tl, N1, N2);

  gemm_launch<64, 0>(stream, xdnh, xdnl, W1Th, W1Tl, K1, nullptr, P1, ND, N1, HDIM);
  gemm_launch<64, 0>(stream, xdnh, xdnl, W1Th + HDIM, W1Tl + HDIM, K1, nullptr, P2, ND, N1, HDIM);
  gemm_launch<64, 0>(stream, xcnh, xcnl, W1Th + 2 * HDIM, W1Tl + 2 * HDIM, K1, b1, P3, NC, N1, HDIM);

  float* outp = (float*)d_out;
  fill_out2_kernel<<<cdiv(B, 256), 256, 0, stream>>>(outp, b3, B);
  for (int c0 = 0; c0 < B; c0 += CH) {
    int M = (B - c0) < CH ? (B - c0) : CH;
    combine_h1_kernel<<<cdiv(M * (N1 / 4), 256), 256, 0, stream>>>(
        P1, P2, P3, drug1, drug2, cellb, c0, h1h, h1l, M, N1);
    gemm_launch_f3(stream, h1h, h1l, W2Th, W2Tl, N1, b2, W3,
                   outp + (size_t)c0 * 2, M, N2, N1);
  }
}

// Round 14
// 689.961 us; speedup vs baseline: 1.0719x; 1.0719x over previous
//
#include <hip/hip_runtime.h>
#include <hip/hip_bf16.h>

#define HDIM 256
#define NEG_SLOPE 0.2f
#define NB 128          // blocks for hist/scatter
#define SLICES 8        // edge slices per dst in the big-degree aggregator
#define TBN 64
#define TBK 32

typedef __attribute__((ext_vector_type(8))) short bf16x8;
typedef __attribute__((ext_vector_type(4))) float f32x4;

// split-bf16: x ~= bf16(hi) + bf16(lo); stored as two separate ushort arrays
__device__ inline uint f2pl(float x) {
  __hip_bfloat16 h = __float2bfloat16(x);
  ushort hi = *(ushort*)&h;
  float r = x - __bfloat162float(h);
  __hip_bfloat16 l = __float2bfloat16(r);
  ushort lo = *(ushort*)&l;
  return (uint)hi | ((uint)lo << 16);
}
__device__ inline ushort f2b(float x) {
  __hip_bfloat16 h = __float2bfloat16(x);
  return *(ushort*)&h;
}
__device__ inline float b2f(ushort u) {
  uint x = ((uint)u) << 16;
  return __int_as_float((int)x);
}

static inline int cdiv(int a, int b) { return (a + b - 1) / b; }

// ---------------------------------------------------------------- utilities
__global__ void fillf_kernel(float* __restrict__ p, float v, int n) {
  int i = blockIdx.x * blockDim.x + threadIdx.x;
  if (i < n) p[i] = v;
}

__global__ void fill_out2_kernel(float* __restrict__ out, const float* __restrict__ b3, int M) {
  int i = blockIdx.x * 256 + threadIdx.x;
  if (i >= M) return;
  out[(size_t)i * 2 + 0] = b3[0];
  out[(size_t)i * 2 + 1] = b3[1];
}

// W[K][N] fp32 -> WTh/WTl[N][K] split
__global__ void wconv_split_kernel(const float* __restrict__ W,
                                   ushort* __restrict__ WTh, ushort* __restrict__ WTl,
                                   int K, int N) {
  int i = blockIdx.x * 256 + threadIdx.x;
  if (i >= K * N) return;
  int k = i / N, n = i - k * N;
  uint p = f2pl(W[i]);
  WTh[(size_t)n * K + k] = (ushort)(p & 0xffff);
  WTl[(size_t)n * K + k] = (ushort)(p >> 16);
}

// batched layer-weight conversion: all 3 edge types x L layers in one launch
__global__ void wconv_split3_kernel(
    const float* __restrict__ Wpp, const float* __restrict__ Wdp, const float* __restrict__ Wcp,
    ushort* __restrict__ WTpph, ushort* __restrict__ WTppl,
    ushort* __restrict__ WTdph, ushort* __restrict__ WTdpl,
    ushort* __restrict__ WTcph, ushort* __restrict__ WTcpl, int L) {
  const int per = HDIM * HDIM;
  int i = blockIdx.x * 256 + threadIdx.x;
  if (i >= 3 * L * per) return;
  int mat = i / per;
  int r = i - mat * per;
  int l = mat / 3, ty = mat - l * 3;
  const float* W = (ty == 0 ? Wpp : ty == 1 ? Wdp : Wcp) + (size_t)l * per;
  ushort* Th = (ty == 0 ? WTpph : ty == 1 ? WTdph : WTcph) + (size_t)l * per;
  ushort* Tl = (ty == 0 ? WTppl : ty == 1 ? WTdpl : WTcpl) + (size_t)l * per;
  int k = r >> 8, n = r & (HDIM - 1);    // r = k*HDIM + n
  uint p = f2pl(W[r]);
  Th[(size_t)n * HDIM + k] = (ushort)(p & 0xffff);
  Tl[(size_t)n * HDIM + k] = (ushort)(p >> 16);
}

__global__ void f32_to_split_kernel(const float* __restrict__ in,
                                    ushort* __restrict__ oh, ushort* __restrict__ ol, int n) {
  int i = blockIdx.x * 256 + threadIdx.x;
  if (i >= n) return;
  uint p = f2pl(in[i]);
  oh[i] = (ushort)(p & 0xffff);
  ol[i] = (ushort)(p >> 16);
}

// wv[b][k] = sum_n W[k][n]*a[n]  (the folded attention vector W @ a)
__global__ __launch_bounds__(256) void matvec_all_kernel(
    const float* __restrict__ Wpp, const float* __restrict__ aspp, const float* __restrict__ adpp,
    const float* __restrict__ Wdp, const float* __restrict__ asdp, const float* __restrict__ addp,
    const float* __restrict__ Wcp, const float* __restrict__ ascp, const float* __restrict__ adcp,
    float* __restrict__ wv) {
  int b = blockIdx.x;
  int l = b / 6, r = b - l * 6, type = r >> 1, isd = r & 1;
  const float* W = (type == 0 ? Wpp : type == 1 ? Wdp : Wcp) + (size_t)l * HDIM * HDIM;
  const float* a = (type == 0 ? (isd ? adpp : aspp)
                  : type == 1 ? (isd ? addp : asdp)
                              : (isd ? adcp : ascp)) + (size_t)l * HDIM;
  int k = threadIdx.x;
  const float4* Wr = (const float4*)(W + (size_t)k * HDIM);
  float s = 0.f;
#pragma unroll 8
  for (int n4 = 0; n4 < HDIM / 4; ++n4) {
    float4 w = Wr[n4];
    float4 av = *(const float4*)(a + n4 * 4);
    s += w.x * av.x + w.y * av.y + w.z * av.z + w.w * av.w;
  }
  wv[(size_t)b * HDIM + k] = s;
}

// layer-0 protein prep: bf16 copy of prot_emb + the two pp rowdots, one pass
__global__ __launch_bounds__(256) void prep_p_kernel(
    const float* __restrict__ in, ushort* __restrict__ outb,
    const float* __restrict__ a1, const float* __restrict__ a2,
    float* __restrict__ o1, float* __restrict__ o2, int n) {
  int row = blockIdx.x * 4 + (threadIdx.x >> 6);
  if (row >= n) return;
  int lane = threadIdx.x & 63;
  float s1 = 0.f, s2 = 0.f;
#pragma unroll
  for (int u = 0; u < 4; ++u) {
    int c = lane + u * 64;
    float hv = in[(size_t)row * HDIM + c];
    outb[(size_t)row * HDIM + c] = f2b(hv);
    s1 += hv * a1[c];
    s2 += hv * a2[c];
  }
#pragma unroll
  for (int off = 32; off; off >>= 1) {
    s1 += __shfl_down(s1, off);
    s2 += __shfl_down(s2, off);
  }
  if (lane == 0) { o1[row] = s1; o2[row] = s2; }
}

// h1 combine -> split planes (P3 carries bias b1). Done ONCE per element.
__global__ __launch_bounds__(256) void combine_h1_kernel(
    const float* __restrict__ P1, const float* __restrict__ P2, const float* __restrict__ P3,
    const int* __restrict__ g1, const int* __restrict__ g2, const int* __restrict__ g3,
    int row0, ushort* __restrict__ h1h, ushort* __restrict__ h1l, int M, int K) {
  int t = blockIdx.x * 256 + threadIdx.x;
  int kq = K >> 2;
  if (t >= M * kq) return;
  int row = t / kq, c4 = t - row * kq;
  int bi = row0 + row;
  size_t o = (size_t)c4 * 4;
  float4 a = *(const float4*)(P1 + (size_t)g1[bi] * K + o);
  float4 b = *(const float4*)(P2 + (size_t)g2[bi] * K + o);
  float4 c = *(const float4*)(P3 + (size_t)g3[bi] * K + o);
  uint p0 = f2pl(fmaxf(a.x + b.x + c.x, 0.f));
  uint p1 = f2pl(fmaxf(a.y + b.y + c.y, 0.f));
  uint p2 = f2pl(fmaxf(a.z + b.z + c.z, 0.f));
  uint p3 = f2pl(fmaxf(a.w + b.w + c.w, 0.f));
  ushort4 h = {(ushort)(p0 & 0xffff), (ushort)(p1 & 0xffff), (ushort)(p2 & 0xffff), (ushort)(p3 & 0xffff)};
  ushort4 l = {(ushort)(p0 >> 16), (ushort)(p1 >> 16), (ushort)(p2 >> 16), (ushort)(p3 >> 16)};
  *(ushort4*)(h1h + (size_t)row * K + o) = h;
  *(ushort4*)(h1l + (size_t)row * K + o) = l;
}

// ---------------------------------------------------------------- MFMA GEMM
// C = act(A@B + bias), fp32 out. A,B pre-split hi/lo ushort arrays.
// ROUND-10 PROVEN STRUCTURE (best known). Neighboring structures all
// regressed: TBM=64 grid (FETCH 37->65MB), A-direct (L1 thrash), B-direct
// (L2 latency on critical path). LDS staging is load-bearing for BOTH
// operands at 2 blocks/CU.
// LDS layout: granule-major WITH slot rotation:
//   plane[gq][row>>4][slot][8ush], slot = ((row&15) + 2*gq) & 15.
// Reads: one contiguous 256B region per quad-phase -> conflict-free.
// Writes: slots {r4+2gq} cover each bank-quad exactly 2x -> free.
// 2-deep register pipeline; one barrier per k-step; M fast grid dim (XCD-
// local A-panel L2 reuse). FUSE3: head3 fused epilogue (atomicAdd logits).
template <int TBM_, int ACT, int FUSE3>
__global__ __launch_bounds__(256) void mfma_gemm(
    const ushort* __restrict__ Ahg, const ushort* __restrict__ Alg,
    const ushort* __restrict__ Bhg, const ushort* __restrict__ Blg,
    int ldb, const float* __restrict__ bias, const float* __restrict__ W3g,
    float* __restrict__ C, int M, int N, int K) {
  __shared__ __align__(16) ushort Ah[2][4][TBM_ / 16][16][8];
  __shared__ __align__(16) ushort Al[2][4][TBM_ / 16][16][8];
  __shared__ __align__(16) ushort Bh[2][4][TBN / 16][16][8];
  __shared__ __align__(16) ushort Bl[2][4][TBN / 16][16][8];

  constexpr int NU = TBM_ / 64;   // A 16B-load instrs per thread (64 rows/round)
  constexpr int TM = TBM_ / 32;   // 16-row tiles per wave (M dir)

  const int tid = threadIdx.x;
  const int lane = tid & 63;
  const int wid = tid >> 6;
  const int wm = wid & 1, wn = wid >> 1;
  const int l16 = lane & 15;
  const int quad = lane >> 4;
  const int m0 = blockIdx.x * TBM_;
  const int n0 = blockIdx.y * TBN;

  const int gq = lane & 3;         // k-granule (8 ushorts = 16B) this lane stages
  const int co = gq * 8;           // ushort col within 32-ushort k-chunk
  const int r4 = lane >> 2;        // row within 16-row stripe
  const int wslot = (r4 + 2 * gq) & 15;          // rotated write slot
  const int rslot = (l16 + 2 * quad) & 15;       // rotated read slot

  uint4 rah0[NU], ral0[NU], rbh0, rbl0;   // register set 0
  uint4 rah1[NU], ral1[NU], rbh1, rbl1;   // register set 1

  auto LOADA = [&](uint4* rah, uint4* ral, uint4& rbh, uint4& rbl, int k0) {
#pragma unroll
    for (int u = 0; u < NU; ++u) {
      int r = wid * (TBM_ / 4) + r4 + 16 * u;
      int gm = m0 + r;
      if (gm < M) {
        size_t o = (size_t)gm * K + k0 + co;
        rah[u] = *(const uint4*)(Ahg + o);
        ral[u] = *(const uint4*)(Alg + o);
      } else {
        rah[u] = make_uint4(0, 0, 0, 0);
        ral[u] = make_uint4(0, 0, 0, 0);
      }
    }
    {
      int r = wid * 16 + r4;
      size_t o = (size_t)(n0 + r) * ldb + k0 + co;
      rbh = *(const uint4*)(Bhg + o);
      rbl = *(const uint4*)(Blg + o);
    }
  };
  auto STORE = [&](const uint4* rah, const uint4* ral, const uint4& rbh, const uint4& rbl, int b) {
#pragma unroll
    for (int u = 0; u < NU; ++u) {
      int ch = (wid * (TBM_ / 4) + 16 * u) >> 4;   // row chunk (r4 < 16)
      *(uint4*)&Ah[b][gq][ch][wslot][0] = rah[u];
      *(uint4*)&Al[b][gq][ch][wslot][0] = ral[u];
    }
    *(uint4*)&Bh[b][gq][wid][wslot][0] = rbh;
    *(uint4*)&Bl[b][gq][wid][wslot][0] = rbl;
  };

  f32x4 acc[TM][2];
#pragma unroll
  for (int i = 0; i < TM; ++i)
#pragma unroll
    for (int j = 0; j < 2; ++j) acc[i][j] = (f32x4){0.f, 0.f, 0.f, 0.f};

  auto COMPUTE = [&](int b) {
    bf16x8 ahf[TM], alf[TM], bhf[2], blf[2];
#pragma unroll
    for (int t = 0; t < TM; ++t) {
      int ch = wm * (TBM_ / 32) + t;
      ahf[t] = *(const bf16x8*)&Ah[b][quad][ch][rslot][0];
      alf[t] = *(const bf16x8*)&Al[b][quad][ch][rslot][0];
    }
#pragma unroll
    for (int t = 0; t < 2; ++t) {
      int ch = wn * 2 + t;
      bhf[t] = *(const bf16x8*)&Bh[b][quad][ch][rslot][0];
      blf[t] = *(const bf16x8*)&Bl[b][quad][ch][rslot][0];
    }
#pragma unroll
    for (int tm = 0; tm < TM; ++tm)
#pragma unroll
      for (int tn = 0; tn < 2; ++tn) {
        acc[tm][tn] = __builtin_amdgcn_mfma_f32_16x16x32_bf16(ahf[tm], bhf[tn], acc[tm][tn], 0, 0, 0);
        acc[tm][tn] = __builtin_amdgcn_mfma_f32_16x16x32_bf16(ahf[tm], blf[tn], acc[tm][tn], 0, 0, 0);
        acc[tm][tn] = __builtin_amdgcn_mfma_f32_16x16x32_bf16(alf[tm], bhf[tn], acc[tm][tn], 0, 0, 0);
      }
  };

  // prologue: tiles t0,t1 in regs; t0 -> buf0
  const int NK = K / TBK;            // even, >= 4 for all shapes used
  LOADA(rah0, ral0, rbh0, rbl0, 0);
  LOADA(rah1, ral1, rbh1, rbl1, TBK);
  STORE(rah0, ral0, rbh0, rbl0, 0);
  int k = 2 * TBK;
  for (int t = 0; t < (NK - 2) / 2; ++t) {
    __syncthreads();
    LOADA(rah0, ral0, rbh0, rbl0, k);   // t+2 in flight
    COMPUTE(0);                          // tile t (buf0)
    STORE(rah1, ral1, rbh1, rbl1, 1);    // t+1 -> buf1
    k += TBK;
    __syncthreads();
    LOADA(rah1, ral1, rbh1, rbl1, k);
    COMPUTE(1);
    STORE(rah0, ral0, rbh0, rbl0, 0);
    k += TBK;
  }
  __syncthreads();
  COMPUTE(0);
  STORE(rah1, ral1, rbh1, rbl1, 1);
  __syncthreads();
  COMPUTE(1);

  if (FUSE3) {
    // relu(acc+bias) . W3 -> per-row (s0,s1); reduce over the 16 l16 lanes
    // sharing a row; leader atomicAdds into b3-prefilled C[M][2].
#pragma unroll
    for (int tm = 0; tm < TM; ++tm) {
#pragma unroll
      for (int r = 0; r < 4; ++r) {
        int row = m0 + wm * (TBM_ / 2) + tm * 16 + quad * 4 + r;
        float s0 = 0.f, s1 = 0.f;
#pragma unroll
        for (int tn = 0; tn < 2; ++tn) {
          int col = n0 + wn * 32 + tn * 16 + l16;
          float v = fmaxf(acc[tm][tn][r] + bias[col], 0.f);
          s0 += v * W3g[col * 2 + 0];
          s1 += v * W3g[col * 2 + 1];
        }
#pragma unroll
        for (int o = 1; o < 16; o <<= 1) {
          s0 += __shfl_xor(s0, o);
          s1 += __shfl_xor(s1, o);
        }
        if (l16 == 0 && row < M) {
          atomicAdd(&C[(size_t)row * 2 + 0], s0);
          atomicAdd(&C[(size_t)row * 2 + 1], s1);
        }
      }
    }
  } else {
#pragma unroll
    for (int tn = 0; tn < 2; ++tn) {
      int col = n0 + wn * 32 + tn * 16 + l16;
      float bv = bias ? bias[col] : 0.f;
#pragma unroll
      for (int tm = 0; tm < TM; ++tm) {
#pragma unroll
        for (int r = 0; r < 4; ++r) {
          int row = m0 + wm * (TBM_ / 2) + tm * 16 + quad * 4 + r;
          if (row >= M) continue;
          float v = acc[tm][tn][r] + bv;
          if (ACT == 1) v = fmaxf(v, 0.f);
          C[(size_t)row * N + col] = v;
        }
      }
    }
  }
}

template <int TBM_, int ACT>
static void gemm_launch(hipStream_t s,
                        const ushort* Ahg, const ushort* Alg,
                        const ushort* Bhg, const ushort* Blg,
                        int ldb, const float* bias, float* C,
                        int M, int N, int K) {
  dim3 g(cdiv(M, TBM_), N / TBN);   // M fast: XCD-local A-panel reuse
  mfma_gemm<TBM_, ACT, 0><<<g, 256, 0, s>>>(Ahg, Alg, Bhg, Blg, ldb, bias, nullptr, C, M, N, K);
}

static void gemm_launch_f3(hipStream_t s,
                           const ushort* Ahg, const ushort* Alg,
                           const ushort* Bhg, const ushort* Blg,
                           int ldb, const float* bias, const float* W3,
                           float* C, int M, int N, int K) {
  dim3 g(cdiv(M, 128), N / TBN);
  mfma_gemm<128, 1, 1><<<g, 256, 0, s>>>(Ahg, Alg, Bhg, Blg, ldb, bias, W3, C, M, N, K);
}

// ---------------------------------------------------------------- row dots
// dp-dst + cp-dst in ONE launch (segment dispatch; both paths identical to
// the proven rowdot body)
__global__ __launch_bounds__(256) void rowdot_dc_kernel(
    const float* __restrict__ Hd, const float* __restrict__ ad, float* __restrict__ od, int nd,
    const float* __restrict__ Hc, const float* __restrict__ ac, float* __restrict__ oc, int nc,
    int bsplit) {
  int b = blockIdx.x;
  const float* H; const float* a; float* o; int n; int row;
  if (b < bsplit) { H = Hd; a = ad; o = od; n = nd; row = b * 4 + (threadIdx.x >> 6); }
  else            { H = Hc; a = ac; o = oc; n = nc; row = (b - bsplit) * 4 + (threadIdx.x >> 6); }
  if (row >= n) return;
  int lane = threadIdx.x & 63;
  const float* h = H + (size_t)row * HDIM;
  float s = 0.f;
#pragma unroll
  for (int u = 0; u < 4; ++u) {
    int c = lane + u * 64;
    s += h[c] * a[c];
  }
#pragma unroll
  for (int off = 32; off; off >>= 1) s += __shfl_down(s, off);
  if (lane == 0) o[row] = s;
}

// ---------------------------------------------------------------- counting sort by dst
__global__ __launch_bounds__(256) void hist_kernel(
    const int* __restrict__ src, const int* __restrict__ dst, int E, int nloops,
    int Nd, int* __restrict__ offs) {
  extern __shared__ int bins[];
  int tot = E + nloops;
  int chunk = (tot + NB - 1) / NB;
  int b = blockIdx.x;
  int s0 = b * chunk, s1 = min(s0 + chunk, tot);
  for (int i = threadIdx.x; i < Nd; i += 256) bins[i] = 0;
  __syncthreads();
  for (int i = s0 + threadIdx.x; i < s1; i += 256) {
    int d = (i < E) ? dst[i] : (i - E);
    atomicAdd(&bins[d], 1);
  }
  __syncthreads();
  for (int i = threadIdx.x; i < Nd; i += 256) offs[(size_t)i * NB + b] = bins[i];
}

__global__ __launch_bounds__(256) void scan_bins_kernel(
    int* __restrict__ offs, int* __restrict__ binsum, int Nd) {
  int d = blockIdx.x * 4 + (threadIdx.x >> 6);
  if (d >= Nd) return;
  int lane = threadIdx.x & 63;
  int* p = offs + (size_t)d * NB;
  int v0 = p[2 * lane], v1 = p[2 * lane + 1];
  int s = v0 + v1;
  int t = s;
#pragma unroll
  for (int o = 1; o < 64; o <<= 1) { int u = __shfl_up(t, o); if (lane >= o) t += u; }
  int excl = t - s;
  p[2 * lane] = excl;
  p[2 * lane + 1] = excl + v0;
  if (lane == 63) binsum[d] = t;
}

__global__ __launch_bounds__(256) void scan_base_kernel(
    const int* __restrict__ binsum, int* __restrict__ rowptr, int Nd) {
  __shared__ int wsum[4];
  __shared__ int carry;
  if (threadIdx.x == 0) carry = 0;
  __syncthreads();
  int lane = threadIdx.x & 63, w = threadIdx.x >> 6;
  for (int t0 = 0; t0 < Nd; t0 += 256) {
    int i = t0 + threadIdx.x;
    int v = (i < Nd) ? binsum[i] : 0;
    int t = v;
#pragma unroll
    for (int o = 1; o < 64; o <<= 1) { int u = __shfl_up(t, o); if (lane >= o) t += u; }
    if (lane == 63) wsum[w] = t;
    __syncthreads();
    int add = carry;
    for (int k = 0; k < w; ++k) add += wsum[k];
    if (i < Nd) rowptr[i] = t - v + add;
    __syncthreads();
    if (threadIdx.x == 0) carry += wsum[0] + wsum[1] + wsum[2] + wsum[3];
    __syncthreads();
  }
  if (threadIdx.x == 0) rowptr[Nd] = carry;
}

__global__ __launch_bounds__(256) void scatter_kernel(
    const int* __restrict__ src, const int* __restrict__ dst, int E, int nloops,
    int Nd, const int* __restrict__ offs, const int* __restrict__ rowptr,
    uint* __restrict__ sd) {
  extern __shared__ int bins[];
  int tot = E + nloops;
  int chunk = (tot + NB - 1) / NB;
  int b = blockIdx.x;
  int s0 = b * chunk, s1 = min(s0 + chunk, tot);
  for (int i = threadIdx.x; i < Nd; i += 256) bins[i] = 0;
  __syncthreads();
  for (int i = s0 + threadIdx.x; i < s1; i += 256) {
    int s_, d_;
    if (i < E) { s_ = src[i]; d_ = dst[i]; }
    else       { s_ = d_ = i - E; }
    int local = atomicAdd(&bins[d_], 1);
    int pos = rowptr[d_] + offs[(size_t)d_ * NB + b] + local;
    sd[pos] = (uint)s_ | ((uint)d_ << 16);
  }
}

// ---------------------------------------------------------------- fused GAT edge phase
__global__ __launch_bounds__(256) void gat_agg_split(
    const int* __restrict__ rowptr, const uint* __restrict__ sd,
    const float* __restrict__ als, const float* __restrict__ ald,
    const ushort* __restrict__ Xb,
    ushort* __restrict__ aggh, ushort* __restrict__ aggl, int n) {
  int d = blockIdx.x * 4 + (threadIdx.x >> 6);
  if (d >= n) return;
  int lane = threadIdx.x & 63;
  int r0 = rowptr[d], r1 = rowptr[d + 1];
  float aldd = ald[d];
  float dsum = 0.f;
  for (int j = r0 + lane; j < r1; j += 64) {
    float e = als[sd[j] & 0xffff] + aldd;
    e = (e > 0.f) ? e : NEG_SLOPE * e;
    dsum += __expf(e);
  }
#pragma unroll
  for (int o = 32; o; o >>= 1) dsum += __shfl_xor(dsum, o);
  float rden = 1.f / (dsum + 1e-16f);

  float4 acc = make_float4(0.f, 0.f, 0.f, 0.f);
  for (int b = r0; b < r1; b += 64) {
    int j = b + lane;
    float exv = 0.f; int srcv = 0;
    if (j < r1) {
      uint p = sd[j];
      srcv = p & 0xffff;
      float e = als[srcv] + aldd;
      e = (e > 0.f) ? e : NEG_SLOPE * e;
      exv = __expf(e) * rden;
    }
    int cnt = min(64, r1 - b);
    for (int t0 = 0; t0 < cnt; t0 += 8) {
      float cf[8]; int sv[8];
#pragma unroll
      for (int u = 0; u < 8; ++u) {
        cf[u] = __shfl(exv, t0 + u);
        sv[u] = __shfl(srcv, t0 + u);
      }
      ushort4 hv[8];
#pragma unroll
      for (int u = 0; u < 8; ++u)
        hv[u] = *(const ushort4*)(Xb + (size_t)sv[u] * HDIM + lane * 4);
#pragma unroll
      for (int u = 0; u < 8; ++u) {
        acc.x += cf[u] * b2f(hv[u].x);
        acc.y += cf[u] * b2f(hv[u].y);
        acc.z += cf[u] * b2f(hv[u].z);
        acc.w += cf[u] * b2f(hv[u].w);
      }
    }
  }
  uint p0 = f2pl(acc.x), p1 = f2pl(acc.y), p2 = f2pl(acc.z), p3 = f2pl(acc.w);
  ushort4 h = {(ushort)(p0 & 0xffff), (ushort)(p1 & 0xffff), (ushort)(p2 & 0xffff), (ushort)(p3 & 0xffff)};
  ushort4 l = {(ushort)(p0 >> 16), (ushort)(p1 >> 16), (ushort)(p2 >> 16), (ushort)(p3 >> 16)};
  *(ushort4*)(aggh + (size_t)d * HDIM + lane * 4) = h;
  *(ushort4*)(aggl + (size_t)d * HDIM + lane * 4) = l;
}

__global__ __launch_bounds__(256) void gat_agg_slice(
    const int* __restrict__ rowptr, const uint* __restrict__ sd,
    const float* __restrict__ als, const float* __restrict__ ald,
    const ushort* __restrict__ Xb, float* __restrict__ out32, int n) {
  int d = blockIdx.x / SLICES;
  int sl = blockIdx.x - d * SLICES;
  if (d >= n) return;
  int lane = threadIdx.x & 63, w = threadIdx.x >> 6;
  int r0 = rowptr[d], r1 = rowptr[d + 1];
  float aldd = ald[d];
  float dsum = 0.f;
  for (int j = r0 + threadIdx.x; j < r1; j += 256) {
    float e = als[sd[j] & 0xffff] + aldd;
    e = (e > 0.f) ? e : NEG_SLOPE * e;
    dsum += __expf(e);
  }
#pragma unroll
  for (int o = 32; o; o >>= 1) dsum += __shfl_xor(dsum, o);
  __shared__ float wd[4];
  if (lane == 0) wd[w] = dsum;
  __syncthreads();
  float rden = 1.f / (wd[0] + wd[1] + wd[2] + wd[3] + 1e-16f);
  int deg = r1 - r0;
  int per_b = (deg + SLICES - 1) / SLICES;
  int b0 = r0 + sl * per_b, b1 = min(b0 + per_b, r1);
  int wdeg = b1 - b0;
  if (wdeg <= 0) return;
  int per_w = (wdeg + 3) >> 2;
  int w0 = b0 + w * per_w, w1 = min(w0 + per_w, b1);

  float4 acc = make_float4(0.f, 0.f, 0.f, 0.f);
  for (int b = w0; b < w1; b += 64) {
    int j = b + lane;
    float exv = 0.f; int srcv = 0;
    if (j < w1) {
      uint p = sd[j];
      srcv = p & 0xffff;
      float e = als[srcv] + aldd;
      e = (e > 0.f) ? e : NEG_SLOPE * e;
      exv = __expf(e) * rden;
    }
    int cnt = min(64, w1 - b);
    for (int t0 = 0; t0 < cnt; t0 += 8) {
      float cf[8]; int sv[8];
#pragma unroll
      for (int u = 0; u < 8; ++u) {
        cf[u] = __shfl(exv, t0 + u);
        sv[u] = __shfl(srcv, t0 + u);
      }
      ushort4 hv[8];
#pragma unroll
      for (int u = 0; u < 8; ++u)
        hv[u] = *(const ushort4*)(Xb + (size_t)sv[u] * HDIM + lane * 4);
#pragma unroll
      for (int u = 0; u < 8; ++u) {
        acc.x += cf[u] * b2f(hv[u].x);
        acc.y += cf[u] * b2f(hv[u].y);
        acc.z += cf[u] * b2f(hv[u].z);
        acc.w += cf[u] * b2f(hv[u].w);
      }
    }
  }
  float* o = out32 + (size_t)d * HDIM + lane * 4;
  atomicAdd(o + 0, acc.x); atomicAdd(o + 1, acc.y);
  atomicAdd(o + 2, acc.z); atomicAdd(o + 3, acc.w);
}

// ---------------------------------------------------------------- norms
__global__ __launch_bounds__(256) void l2norm_f32b_dots_kernel(
    const float* __restrict__ in, float* __restrict__ outf, ushort* __restrict__ outb,
    const float* __restrict__ v1, const float* __restrict__ v2,
    const float* __restrict__ v3, const float* __restrict__ v4,
    float* __restrict__ o1, float* __restrict__ o2,
    float* __restrict__ o3, float* __restrict__ o4, int n) {
  int row = blockIdx.x * 4 + (threadIdx.x >> 6);
  if (row >= n) return;
  int lane = threadIdx.x & 63;
  float v[4];
  float ss = 0.f;
#pragma unroll
  for (int u = 0; u < 4; ++u) {
    float t = in[(size_t)row * HDIM + lane + u * 64];
    v[u] = t; ss += t * t;
  }
#pragma unroll
  for (int off = 32; off; off >>= 1) ss += __shfl_xor(ss, off);
  float sc = 1.0f / fmaxf(sqrtf(ss), 1e-12f);
  float d1 = 0.f, d2 = 0.f, d3 = 0.f, d4 = 0.f;
#pragma unroll
  for (int u = 0; u < 4; ++u) {
    float f = v[u] * sc;
    int c = lane + u * 64;
    outf[(size_t)row * HDIM + c] = f;
    outb[(size_t)row * HDIM + c] = f2b(f);
    d1 += f * v1[c];
    d2 += f * v2[c];
    if (o3) { d3 += f * v3[c]; d4 += f * v4[c]; }
  }
#pragma unroll
  for (int off = 32; off; off >>= 1) {
    d1 += __shfl_xor(d1, off);
    d2 += __shfl_xor(d2, off);
    if (o3) { d3 += __shfl_xor(d3, off); d4 += __shfl_xor(d4, off); }
  }
  if (lane == 0) {
    o1[row] = d1; o2[row] = d2;
    if (o3) { o3[row] = d3; o4[row] = d4; }
  }
}

// fp32 in -> l2norm -> split hi/lo out; drug + cell tables in ONE launch
__global__ __launch_bounds__(256) void l2norm_split_dc_kernel(
    const float* __restrict__ Xd, ushort* __restrict__ dh, ushort* __restrict__ dl, int nd,
    const float* __restrict__ Xc, ushort* __restrict__ ch, ushort* __restrict__ cl, int nc,
    int bsplit) {
  int b = blockIdx.x;
  const float* in; ushort* oh; ushort* ol; int n; int row;
  if (b < bsplit) { in = Xd; oh = dh; ol = dl; n = nd; row = b * 4 + (threadIdx.x >> 6); }
  else            { in = Xc; oh = ch; ol = cl; n = nc; row = (b - bsplit) * 4 + (threadIdx.x >> 6); }
  if (row >= n) return;
  int lane = threadIdx.x & 63;
  float v[4];
  float ss = 0.f;
#pragma unroll
  for (int u = 0; u < 4; ++u) {
    int c = lane + u * 64;
    float t = in[(size_t)row * HDIM + c];
    v[u] = t;
    ss += t * t;
  }
#pragma unroll
  for (int off = 32; off; off >>= 1) ss += __shfl_xor(ss, off);
  float sc = 1.0f / fmaxf(sqrtf(ss), 1e-12f);
#pragma unroll
  for (int u = 0; u < 4; ++u) {
    int c = lane + u * 64;
    uint p = f2pl(v[u] * sc);
    oh[(size_t)row * HDIM + c] = (ushort)(p & 0xffff);
    ol[(size_t)row * HDIM + c] = (ushort)(p >> 16);
  }
}

// ---------------------------------------------------------------- host side
static void build_sorted(hipStream_t stream,
                         const int* src, const int* dst, int E, int nloops, int Nd,
                         int* offs, int* binsum, int* rowptr, uint* sd) {
  size_t lds = (size_t)Nd * sizeof(int);
  hist_kernel<<<NB, 256, lds, stream>>>(src, dst, E, nloops, Nd, offs);
  scan_bins_kernel<<<cdiv(Nd, 4), 256, 0, stream>>>(offs, binsum, Nd);
  scan_base_kernel<<<1, 256, 0, stream>>>(binsum, rowptr, Nd);
  scatter_kernel<<<NB, 256, lds, stream>>>(src, dst, E, nloops, Nd, offs, rowptr, sd);
}

extern "C" void kernel_launch(void* const* d_in, const int* in_sizes, int n_in,
                              void* d_out, int out_size, void* d_ws, size_t ws_size,
                              hipStream_t stream) {
  const float* drug_emb = (const float*)d_in[0];
  const float* prot_emb = (const float*)d_in[1];
  const float* cell_emb = (const float*)d_in[2];
  const float* W_pp = (const float*)d_in[3];
  const float* as_pp = (const float*)d_in[4];
  const float* ad_pp = (const float*)d_in[5];
  const float* b_pp = (const float*)d_in[6];
  const float* W_dp = (const float*)d_in[7];
  const float* as_dp = (const float*)d_in[8];
  const float* ad_dp = (const float*)d_in[9];
  const float* b_dp = (const float*)d_in[10];
  const float* W_cp = (const float*)d_in[11];
  const float* as_cp = (const float*)d_in[12];
  const float* ad_cp = (const float*)d_in[13];
  const float* b_cp = (const float*)d_in[14];
  const float* W1 = (const float*)d_in[15];
  const float* b1 = (const float*)d_in[16];
  const float* W2 = (const float*)d_in[17];
  const float* b2 = (const float*)d_in[18];
  const float* W3 = (const float*)d_in[19];
  const float* b3 = (const float*)d_in[20];
  const int* edge_pp = (const int*)d_in[21];
  const int* edge_dp = (const int*)d_in[22];
  const int* edge_cp = (const int*)d_in[23];
  const int* drug1 = (const int*)d_in[24];
  const int* drug2 = (const int*)d_in[25];
  const int* cellb = (const int*)d_in[26];

  const int ND = in_sizes[0] / HDIM;   // 2000
  const int NP = in_sizes[1] / HDIM;   // 19000
  const int NC = in_sizes[2] / HDIM;   // 100
  const int L = in_sizes[3] / (HDIM * HDIM);  // 2
  const int E_pp = in_sizes[21] / 2;
  const int E_dp = in_sizes[22] / 2;
  const int E_cp = in_sizes[23] / 2;
  const int B = in_sizes[24];          // 8192
  (void)n_in; (void)out_size;

  const int* src_pp = edge_pp;          const int* dst_pp = edge_pp + E_pp;
  const int* src_dp = edge_dp;          const int* dst_dp = edge_dp + E_dp;
  const int* src_cp = edge_cp;          const int* dst_cp = edge_cp + E_cp;
  const int tot_pp = E_pp + NP, tot_dp = E_dp, tot_cp = E_cp;
  int maxN = NP > ND ? NP : ND; if (NC > maxN) maxN = NC;

  // ---------------- workspace
  char* wsb = (char*)d_ws;
  size_t off = 0;
  auto alloc = [&](size_t bytes) -> void* {
    void* p = wsb + off;
    off += (bytes + 255) & ~(size_t)255;
    return p;
  };

  float* Xp  = (float*)alloc((size_t)NP * HDIM * 4);    // protein state fp32
  ushort* Xpb = (ushort*)alloc((size_t)NP * HDIM * 2);  // protein state bf16 (gather)
  float* Xd  = (float*)alloc((size_t)ND * HDIM * 4);
  float* Xc  = (float*)alloc((size_t)NC * HDIM * 4);
  ushort* xdnh = (ushort*)alloc((size_t)ND * HDIM * 2);
  ushort* xdnl = (ushort*)alloc((size_t)ND * HDIM * 2);
  ushort* xcnh = (ushort*)alloc((size_t)NC * HDIM * 2);
  ushort* xcnl = (ushort*)alloc((size_t)NC * HDIM * 2);
  ushort* WTpph = (ushort*)alloc((size_t)L * HDIM * HDIM * 2);
  ushort* WTppl = (ushort*)alloc((size_t)L * HDIM * HDIM * 2);
  ushort* WTdph = (ushort*)alloc((size_t)L * HDIM * HDIM * 2);
  ushort* WTdpl = (ushort*)alloc((size_t)L * HDIM * HDIM * 2);
  ushort* WTcph = (ushort*)alloc((size_t)L * HDIM * HDIM * 2);
  ushort* WTcpl = (ushort*)alloc((size_t)L * HDIM * HDIM * 2);
  ushort* cth = (ushort*)alloc((size_t)NC * HDIM * 2);  // cp split staging
  ushort* ctl = (ushort*)alloc((size_t)NC * HDIM * 2);
  float* wv  = (float*)alloc((size_t)L * 6 * HDIM * 4); // folded W@a vectors
  float* pals = (float*)alloc((size_t)maxN * 4);        // pp src logits
  float* pald = (float*)alloc((size_t)maxN * 4);        // pp dst logits
  float* als1 = (float*)alloc((size_t)maxN * 4);        // dp src logits
  float* als2 = (float*)alloc((size_t)maxN * 4);        // cp src logits
  float* ald1 = (float*)alloc((size_t)maxN * 4);
  float* ald2 = (float*)alloc((size_t)maxN * 4);
  int* binsum = (int*)alloc((size_t)maxN * 4);
  int* rp_pp = (int*)alloc((size_t)(NP + 1) * 4);
  int* rp_dp = (int*)alloc((size_t)(ND + 1) * 4);
  int* rp_cp = (int*)alloc((size_t)(NC + 1) * 4);
  uint* sd_pp = (uint*)alloc((size_t)tot_pp * 4);
  uint* sd_dp = (uint*)alloc((size_t)tot_dp * 4);
  uint* sd_cp = (uint*)alloc((size_t)tot_cp * 4);
  float* out32 = (float*)alloc((size_t)NC * HDIM * 4);  // cp partial accumulator
  size_t S0 = off;

  // scratch S overlays: [offs] -> [aggh|aggl|tmp] -> [W1T*|W2T*|P1|P2|P3|h1*]
  int* offs = (int*)(wsb + S0);
  build_sorted(stream, src_pp, dst_pp, E_pp, NP, NP, offs, binsum, rp_pp, sd_pp);
  build_sorted(stream, src_dp, dst_dp, E_dp, 0, ND, offs, binsum, rp_dp, sd_dp);
  build_sorted(stream, src_cp, dst_cp, E_cp, 0, NC, offs, binsum, rp_cp, sd_cp);

  // ---- weight split planes (batched) + folded attention vectors + protein prep
  wconv_split3_kernel<<<cdiv(3 * L * HDIM * HDIM, 256), 256, 0, stream>>>(
      W_pp, W_dp, W_cp, WTpph, WTppl, WTdph, WTdpl, WTcph, WTcpl, L);
  matvec_all_kernel<<<L * 6, 256, 0, stream>>>(W_pp, as_pp, ad_pp, W_dp, as_dp, ad_dp,
                                               W_cp, as_cp, ad_cp, wv);
  // layer-0: Xpb bf16 copy + pp logits in one pass over prot_emb
  prep_p_kernel<<<cdiv(NP, 4), 256, 0, stream>>>(prot_emb, Xpb, wv + 0 * HDIM, wv + 1 * HDIM,
                                                 pals, pald, NP);

  size_t aggB = ((size_t)NP * HDIM * 2 + 255) & ~(size_t)255;
  ushort* aggh = (ushort*)(wsb + S0);
  ushort* aggl = (ushort*)(wsb + S0 + aggB);
  float* tmp = (float*)(wsb + S0 + 2 * aggB);

  for (int l = 0; l < L; ++l) {
    const int WOFF = l * HDIM * HDIM, VOFF = l * HDIM;
    const float* wvl = wv + (size_t)l * 6 * HDIM;
    bool last = (l == L - 1);
    const float* wvn = last ? wvl : wv + (size_t)(l + 1) * 6 * HDIM;
    const float* Xd_cur = (l == 0) ? drug_emb : Xd;
    const float* Xc_cur = (l == 0) ? cell_emb : Xc;

    // ---- p-p: aggregate x -> transform -> l2norm (+fused dots for dp/cp/next-pp)
    gat_agg_split<<<cdiv(NP, 4), 256, 0, stream>>>(rp_pp, sd_pp, pals, pald, Xpb, aggh, aggl, NP);
    gemm_launch<128, 0>(stream, aggh, aggl, WTpph + WOFF, WTppl + WOFF, HDIM,
                        b_pp + VOFF, tmp, NP, HDIM, HDIM);
    l2norm_f32b_dots_kernel<<<cdiv(NP, 4), 256, 0, stream>>>(
        tmp, Xp, Xpb,
        wvl + 2 * HDIM, wvl + 4 * HDIM,
        last ? nullptr : (wvn + 0 * HDIM), last ? nullptr : (wvn + 1 * HDIM),
        als1, als2, last ? nullptr : pals, last ? nullptr : pald, NP);

    rowdot_dc_kernel<<<cdiv(ND, 4) + cdiv(NC, 4), 256, 0, stream>>>(
        Xd_cur, wvl + 3 * HDIM, ald1, ND,
        Xc_cur, wvl + 5 * HDIM, ald2, NC, cdiv(ND, 4));

    // ---- d-p: aggregate then transform (M=ND)
    gat_agg_split<<<cdiv(ND, 4), 256, 0, stream>>>(rp_dp, sd_dp, als1, ald1, Xpb, aggh, aggl, ND);
    gemm_launch<64, 1>(stream, aggh, aggl, WTdph + WOFF, WTdpl + WOFF, HDIM,
                       b_dp + VOFF, Xd, ND, HDIM, HDIM);

    // ---- c-p: slice-aggregate -> split -> transform (M=NC)
    fillf_kernel<<<cdiv(NC * HDIM, 256), 256, 0, stream>>>(out32, 0.f, NC * HDIM);
    gat_agg_slice<<<NC * SLICES, 256, 0, stream>>>(rp_cp, sd_cp, als2, ald2, Xpb, out32, NC);
    f32_to_split_kernel<<<cdiv(NC * HDIM, 256), 256, 0, stream>>>(out32, cth, ctl, NC * HDIM);
    gemm_launch<64, 1>(stream, cth, ctl, WTcph + WOFF, WTcpl + WOFF, HDIM,
                       b_cp + VOFF, Xc, NC, HDIM, HDIM);
  }

  // ---------------- head
  l2norm_split_dc_kernel<<<cdiv(ND, 4) + cdiv(NC, 4), 256, 0, stream>>>(
      Xd, xdnh, xdnl, ND, Xc, xcnh, xcnl, NC, cdiv(ND, 4));

  const int N1 = 6 * HDIM;   // 1536
  const int N2 = 2 * HDIM;   // 512
  const int K1 = 3 * HDIM;   // 768
  ushort* W1Th = (ushort*)(wsb + S0);                   // [1536][768]
  ushort* W1Tl = W1Th + (size_t)N1 * K1;
  ushort* W2Th = W1Tl + (size_t)N1 * K1;                // [512][1536]
  ushort* W2Tl = W2Th + (size_t)N2 * N1;
  float* P1 = (float*)(W2Tl + (size_t)N2 * N1);         // [ND][1536]
  float* P2 = P1 + (size_t)ND * N1;
  float* P3 = P2 + (size_t)ND * N1;                     // [NC][1536]
  ushort* h1h = (ushort*)(P3 + (size_t)NC * N1);        // [CH][1536] split
  size_t wsz = ws_size ? ws_size : ((size_t)1 << 30);
  size_t fixed = S0 + ((size_t)N1 * K1 + (size_t)N2 * N1) * 4
               + ((size_t)(2 * ND + NC) * N1) * 4;
  int CH = 8192;
  while (CH > 1024 && fixed + (size_t)CH * N1 * 4 > wsz) CH >>= 1;
  ushort* h1l = h1h + (size_t)CH * N1;

  wconv_split_kernel<<<cdiv(K1 * N1, 256), 256, 0, stream>>>(W1, W1Th, W1Tl, K1, N1);
  wconv_split_kernel<<<cdiv(N1 * N2, 256), 256, 0, stream>>>(W2, W2Th, W2Tl, N1, N2);

  gemm_launch<64, 0>(stream, xdnh, xdnl, W1Th, W1Tl, K1, nullptr, P1, ND, N1, HDIM);
  gemm_launch<64, 0>(stream, xdnh, xdnl, W1Th + HDIM, W1Tl + HDIM, K1, nullptr, P2, ND, N1, HDIM);
  gemm_launch<64, 0>(stream, xcnh, xcnl, W1Th + 2 * HDIM, W1Tl + 2 * HDIM, K1, b1, P3, NC, N1, HDIM);

  float* outp = (float*)d_out;
  fill_out2_kernel<<<cdiv(B, 256), 256, 0, stream>>>(outp, b3, B);
  for (int c0 = 0; c0 < B; c0 += CH) {
    int M = (B - c0) < CH ? (B - c0) : CH;
    combine_h1_kernel<<<cdiv(M * (N1 / 4), 256), 256, 0, stream>>>(
        P1, P2, P3, drug1, drug2, cellb, c0, h1h, h1l, M, N1);
    gemm_launch_f3(stream, h1h, h1l, W2Th, W2Tl, N1, b2, W3,
                   outp + (size_t)c0 * 2, M, N2, N1);
  }
}

// Round 15
// 680.156 us; speedup vs baseline: 1.0873x; 1.0144x over previous
//
#include <hip/hip_runtime.h>
#include <hip/hip_bf16.h>

#define HDIM 256
#define NEG_SLOPE 0.2f
#define NB 128          // blocks for hist/scatter
#define SLICES 8        // edge slices per dst in the big-degree aggregator
#define TBN 64
#define TBK 32

typedef __attribute__((ext_vector_type(8))) short bf16x8;
typedef __attribute__((ext_vector_type(4))) float f32x4;

// split-bf16: x ~= bf16(hi) + bf16(lo); stored as two separate ushort arrays
__device__ inline uint f2pl(float x) {
  __hip_bfloat16 h = __float2bfloat16(x);
  ushort hi = *(ushort*)&h;
  float r = x - __bfloat162float(h);
  __hip_bfloat16 l = __float2bfloat16(r);
  ushort lo = *(ushort*)&l;
  return (uint)hi | ((uint)lo << 16);
}
__device__ inline ushort f2b(float x) {
  __hip_bfloat16 h = __float2bfloat16(x);
  return *(ushort*)&h;
}
__device__ inline float b2f(ushort u) {
  uint x = ((uint)u) << 16;
  return __int_as_float((int)x);
}

static inline int cdiv(int a, int b) { return (a + b - 1) / b; }

// ---------------------------------------------------------------- utilities
__global__ void fill_out2_kernel(float* __restrict__ out, const float* __restrict__ b3, int M) {
  int i = blockIdx.x * 256 + threadIdx.x;
  if (i >= M) return;
  out[(size_t)i * 2 + 0] = b3[0];
  out[(size_t)i * 2 + 1] = b3[1];
}

// W[K][N] fp32 -> WTh/WTl[N][K] split
__global__ void wconv_split_kernel(const float* __restrict__ W,
                                   ushort* __restrict__ WTh, ushort* __restrict__ WTl,
                                   int K, int N) {
  int i = blockIdx.x * 256 + threadIdx.x;
  if (i >= K * N) return;
  int k = i / N, n = i - k * N;
  uint p = f2pl(W[i]);
  WTh[(size_t)n * K + k] = (ushort)(p & 0xffff);
  WTl[(size_t)n * K + k] = (ushort)(p >> 16);
}

// batched layer-weight conversion: all 3 edge types x L layers in one launch
__global__ void wconv_split3_kernel(
    const float* __restrict__ Wpp, const float* __restrict__ Wdp, const float* __restrict__ Wcp,
    ushort* __restrict__ WTpph, ushort* __restrict__ WTppl,
    ushort* __restrict__ WTdph, ushort* __restrict__ WTdpl,
    ushort* __restrict__ WTcph, ushort* __restrict__ WTcpl, int L) {
  const int per = HDIM * HDIM;
  int i = blockIdx.x * 256 + threadIdx.x;
  if (i >= 3 * L * per) return;
  int mat = i / per;
  int r = i - mat * per;
  int l = mat / 3, ty = mat - l * 3;
  const float* W = (ty == 0 ? Wpp : ty == 1 ? Wdp : Wcp) + (size_t)l * per;
  ushort* Th = (ty == 0 ? WTpph : ty == 1 ? WTdph : WTcph) + (size_t)l * per;
  ushort* Tl = (ty == 0 ? WTppl : ty == 1 ? WTdpl : WTcpl) + (size_t)l * per;
  int k = r >> 8, n = r & (HDIM - 1);    // r = k*HDIM + n
  uint p = f2pl(W[r]);
  Th[(size_t)n * HDIM + k] = (ushort)(p & 0xffff);
  Tl[(size_t)n * HDIM + k] = (ushort)(p >> 16);
}

__global__ void f32_to_split_kernel(const float* __restrict__ in,
                                    ushort* __restrict__ oh, ushort* __restrict__ ol, int n) {
  int i = blockIdx.x * 256 + threadIdx.x;
  if (i >= n) return;
  uint p = f2pl(in[i]);
  oh[i] = (ushort)(p & 0xffff);
  ol[i] = (ushort)(p >> 16);
}

// wv[b][k] = sum_n W[k][n]*a[n]  (the folded attention vector W @ a)
__global__ __launch_bounds__(256) void matvec_all_kernel(
    const float* __restrict__ Wpp, const float* __restrict__ aspp, const float* __restrict__ adpp,
    const float* __restrict__ Wdp, const float* __restrict__ asdp, const float* __restrict__ addp,
    const float* __restrict__ Wcp, const float* __restrict__ ascp, const float* __restrict__ adcp,
    float* __restrict__ wv) {
  int b = blockIdx.x;
  int l = b / 6, r = b - l * 6, type = r >> 1, isd = r & 1;
  const float* W = (type == 0 ? Wpp : type == 1 ? Wdp : Wcp) + (size_t)l * HDIM * HDIM;
  const float* a = (type == 0 ? (isd ? adpp : aspp)
                  : type == 1 ? (isd ? addp : asdp)
                              : (isd ? adcp : ascp)) + (size_t)l * HDIM;
  int k = threadIdx.x;
  const float4* Wr = (const float4*)(W + (size_t)k * HDIM);
  float s = 0.f;
#pragma unroll 8
  for (int n4 = 0; n4 < HDIM / 4; ++n4) {
    float4 w = Wr[n4];
    float4 av = *(const float4*)(a + n4 * 4);
    s += w.x * av.x + w.y * av.y + w.z * av.z + w.w * av.w;
  }
  wv[(size_t)b * HDIM + k] = s;
}

// layer-0 protein prep: bf16 copy of prot_emb + the two pp rowdots, one pass
__global__ __launch_bounds__(256) void prep_p_kernel(
    const float* __restrict__ in, ushort* __restrict__ outb,
    const float* __restrict__ a1, const float* __restrict__ a2,
    float* __restrict__ o1, float* __restrict__ o2, int n) {
  int row = blockIdx.x * 4 + (threadIdx.x >> 6);
  if (row >= n) return;
  int lane = threadIdx.x & 63;
  float s1 = 0.f, s2 = 0.f;
#pragma unroll
  for (int u = 0; u < 4; ++u) {
    int c = lane + u * 64;
    float hv = in[(size_t)row * HDIM + c];
    outb[(size_t)row * HDIM + c] = f2b(hv);
    s1 += hv * a1[c];
    s2 += hv * a2[c];
  }
#pragma unroll
  for (int off = 32; off; off >>= 1) {
    s1 += __shfl_down(s1, off);
    s2 += __shfl_down(s2, off);
  }
  if (lane == 0) { o1[row] = s1; o2[row] = s2; }
}

// h1 combine -> split planes (P3 carries bias b1). Done ONCE per element.
__global__ __launch_bounds__(256) void combine_h1_kernel(
    const float* __restrict__ P1, const float* __restrict__ P2, const float* __restrict__ P3,
    const int* __restrict__ g1, const int* __restrict__ g2, const int* __restrict__ g3,
    int row0, ushort* __restrict__ h1h, ushort* __restrict__ h1l, int M, int K) {
  int t = blockIdx.x * 256 + threadIdx.x;
  int kq = K >> 2;
  if (t >= M * kq) return;
  int row = t / kq, c4 = t - row * kq;
  int bi = row0 + row;
  size_t o = (size_t)c4 * 4;
  float4 a = *(const float4*)(P1 + (size_t)g1[bi] * K + o);
  float4 b = *(const float4*)(P2 + (size_t)g2[bi] * K + o);
  float4 c = *(const float4*)(P3 + (size_t)g3[bi] * K + o);
  uint p0 = f2pl(fmaxf(a.x + b.x + c.x, 0.f));
  uint p1 = f2pl(fmaxf(a.y + b.y + c.y, 0.f));
  uint p2 = f2pl(fmaxf(a.z + b.z + c.z, 0.f));
  uint p3 = f2pl(fmaxf(a.w + b.w + c.w, 0.f));
  ushort4 h = {(ushort)(p0 & 0xffff), (ushort)(p1 & 0xffff), (ushort)(p2 & 0xffff), (ushort)(p3 & 0xffff)};
  ushort4 l = {(ushort)(p0 >> 16), (ushort)(p1 >> 16), (ushort)(p2 >> 16), (ushort)(p3 >> 16)};
  *(ushort4*)(h1h + (size_t)row * K + o) = h;
  *(ushort4*)(h1l + (size_t)row * K + o) = l;
}

// ---------------------------------------------------------------- MFMA GEMM
// C = act(A@B + bias), fp32 out. A,B pre-split hi/lo ushort arrays.
// ROUND-10 PROVEN STRUCTURE (best known; all structural neighbors regressed).
// LDS layout: granule-major WITH slot rotation:
//   plane[gq][row>>4][slot][8ush], slot = ((row&15) + 2*gq) & 15.
// Reads: one contiguous 256B region per quad-phase -> conflict-free.
// Writes: slots {r4+2gq} cover each bank-quad exactly 2x -> free.
// 2-deep register pipeline; one barrier per k-step; M fast grid dim (XCD-
// local A-panel L2 reuse). FUSE3: head3 fused epilogue (atomicAdd logits).
template <int TBM_, int ACT, int FUSE3>
__global__ __launch_bounds__(256) void mfma_gemm(
    const ushort* __restrict__ Ahg, const ushort* __restrict__ Alg,
    const ushort* __restrict__ Bhg, const ushort* __restrict__ Blg,
    int ldb, const float* __restrict__ bias, const float* __restrict__ W3g,
    float* __restrict__ C, int M, int N, int K) {
  __shared__ __align__(16) ushort Ah[2][4][TBM_ / 16][16][8];
  __shared__ __align__(16) ushort Al[2][4][TBM_ / 16][16][8];
  __shared__ __align__(16) ushort Bh[2][4][TBN / 16][16][8];
  __shared__ __align__(16) ushort Bl[2][4][TBN / 16][16][8];

  constexpr int NU = TBM_ / 64;   // A 16B-load instrs per thread (64 rows/round)
  constexpr int TM = TBM_ / 32;   // 16-row tiles per wave (M dir)

  const int tid = threadIdx.x;
  const int lane = tid & 63;
  const int wid = tid >> 6;
  const int wm = wid & 1, wn = wid >> 1;
  const int l16 = lane & 15;
  const int quad = lane >> 4;
  const int m0 = blockIdx.x * TBM_;
  const int n0 = blockIdx.y * TBN;

  const int gq = lane & 3;         // k-granule (8 ushorts = 16B) this lane stages
  const int co = gq * 8;           // ushort col within 32-ushort k-chunk
  const int r4 = lane >> 2;        // row within 16-row stripe
  const int wslot = (r4 + 2 * gq) & 15;          // rotated write slot
  const int rslot = (l16 + 2 * quad) & 15;       // rotated read slot

  uint4 rah0[NU], ral0[NU], rbh0, rbl0;   // register set 0
  uint4 rah1[NU], ral1[NU], rbh1, rbl1;   // register set 1

  auto LOADA = [&](uint4* rah, uint4* ral, uint4& rbh, uint4& rbl, int k0) {
#pragma unroll
    for (int u = 0; u < NU; ++u) {
      int r = wid * (TBM_ / 4) + r4 + 16 * u;
      int gm = m0 + r;
      if (gm < M) {
        size_t o = (size_t)gm * K + k0 + co;
        rah[u] = *(const uint4*)(Ahg + o);
        ral[u] = *(const uint4*)(Alg + o);
      } else {
        rah[u] = make_uint4(0, 0, 0, 0);
        ral[u] = make_uint4(0, 0, 0, 0);
      }
    }
    {
      int r = wid * 16 + r4;
      size_t o = (size_t)(n0 + r) * ldb + k0 + co;
      rbh = *(const uint4*)(Bhg + o);
      rbl = *(const uint4*)(Blg + o);
    }
  };
  auto STORE = [&](const uint4* rah, const uint4* ral, const uint4& rbh, const uint4& rbl, int b) {
#pragma unroll
    for (int u = 0; u < NU; ++u) {
      int ch = (wid * (TBM_ / 4) + 16 * u) >> 4;   // row chunk (r4 < 16)
      *(uint4*)&Ah[b][gq][ch][wslot][0] = rah[u];
      *(uint4*)&Al[b][gq][ch][wslot][0] = ral[u];
    }
    *(uint4*)&Bh[b][gq][wid][wslot][0] = rbh;
    *(uint4*)&Bl[b][gq][wid][wslot][0] = rbl;
  };

  f32x4 acc[TM][2];
#pragma unroll
  for (int i = 0; i < TM; ++i)
#pragma unroll
    for (int j = 0; j < 2; ++j) acc[i][j] = (f32x4){0.f, 0.f, 0.f, 0.f};

  auto COMPUTE = [&](int b) {
    bf16x8 ahf[TM], alf[TM], bhf[2], blf[2];
#pragma unroll
    for (int t = 0; t < TM; ++t) {
      int ch = wm * (TBM_ / 32) + t;
      ahf[t] = *(const bf16x8*)&Ah[b][quad][ch][rslot][0];
      alf[t] = *(const bf16x8*)&Al[b][quad][ch][rslot][0];
    }
#pragma unroll
    for (int t = 0; t < 2; ++t) {
      int ch = wn * 2 + t;
      bhf[t] = *(const bf16x8*)&Bh[b][quad][ch][rslot][0];
      blf[t] = *(const bf16x8*)&Bl[b][quad][ch][rslot][0];
    }
#pragma unroll
    for (int tm = 0; tm < TM; ++tm)
#pragma unroll
      for (int tn = 0; tn < 2; ++tn) {
        acc[tm][tn] = __builtin_amdgcn_mfma_f32_16x16x32_bf16(ahf[tm], bhf[tn], acc[tm][tn], 0, 0, 0);
        acc[tm][tn] = __builtin_amdgcn_mfma_f32_16x16x32_bf16(ahf[tm], blf[tn], acc[tm][tn], 0, 0, 0);
        acc[tm][tn] = __builtin_amdgcn_mfma_f32_16x16x32_bf16(alf[tm], bhf[tn], acc[tm][tn], 0, 0, 0);
      }
  };

  // prologue: tiles t0,t1 in regs; t0 -> buf0
  const int NK = K / TBK;            // even, >= 4 for all shapes used
  LOADA(rah0, ral0, rbh0, rbl0, 0);
  LOADA(rah1, ral1, rbh1, rbl1, TBK);
  STORE(rah0, ral0, rbh0, rbl0, 0);
  int k = 2 * TBK;
  for (int t = 0; t < (NK - 2) / 2; ++t) {
    __syncthreads();
    LOADA(rah0, ral0, rbh0, rbl0, k);   // t+2 in flight
    COMPUTE(0);                          // tile t (buf0)
    STORE(rah1, ral1, rbh1, rbl1, 1);    // t+1 -> buf1
    k += TBK;
    __syncthreads();
    LOADA(rah1, ral1, rbh1, rbl1, k);
    COMPUTE(1);
    STORE(rah0, ral0, rbh0, rbl0, 0);
    k += TBK;
  }
  __syncthreads();
  COMPUTE(0);
  STORE(rah1, ral1, rbh1, rbl1, 1);
  __syncthreads();
  COMPUTE(1);

  if (FUSE3) {
    // relu(acc+bias) . W3 -> per-row (s0,s1); reduce over the 16 l16 lanes
    // sharing a row; leader atomicAdds into b3-prefilled C[M][2].
#pragma unroll
    for (int tm = 0; tm < TM; ++tm) {
#pragma unroll
      for (int r = 0; r < 4; ++r) {
        int row = m0 + wm * (TBM_ / 2) + tm * 16 + quad * 4 + r;
        float s0 = 0.f, s1 = 0.f;
#pragma unroll
        for (int tn = 0; tn < 2; ++tn) {
          int col = n0 + wn * 32 + tn * 16 + l16;
          float v = fmaxf(acc[tm][tn][r] + bias[col], 0.f);
          s0 += v * W3g[col * 2 + 0];
          s1 += v * W3g[col * 2 + 1];
        }
#pragma unroll
        for (int o = 1; o < 16; o <<= 1) {
          s0 += __shfl_xor(s0, o);
          s1 += __shfl_xor(s1, o);
        }
        if (l16 == 0 && row < M) {
          atomicAdd(&C[(size_t)row * 2 + 0], s0);
          atomicAdd(&C[(size_t)row * 2 + 1], s1);
        }
      }
    }
  } else {
#pragma unroll
    for (int tn = 0; tn < 2; ++tn) {
      int col = n0 + wn * 32 + tn * 16 + l16;
      float bv = bias ? bias[col] : 0.f;
#pragma unroll
      for (int tm = 0; tm < TM; ++tm) {
#pragma unroll
        for (int r = 0; r < 4; ++r) {
          int row = m0 + wm * (TBM_ / 2) + tm * 16 + quad * 4 + r;
          if (row >= M) continue;
          float v = acc[tm][tn][r] + bv;
          if (ACT == 1) v = fmaxf(v, 0.f);
          C[(size_t)row * N + col] = v;
        }
      }
    }
  }
}

template <int TBM_, int ACT>
static void gemm_launch(hipStream_t s,
                        const ushort* Ahg, const ushort* Alg,
                        const ushort* Bhg, const ushort* Blg,
                        int ldb, const float* bias, float* C,
                        int M, int N, int K) {
  dim3 g(cdiv(M, TBM_), N / TBN);   // M fast: XCD-local A-panel reuse
  mfma_gemm<TBM_, ACT, 0><<<g, 256, 0, s>>>(Ahg, Alg, Bhg, Blg, ldb, bias, nullptr, C, M, N, K);
}

static void gemm_launch_f3(hipStream_t s,
                           const ushort* Ahg, const ushort* Alg,
                           const ushort* Bhg, const ushort* Blg,
                           int ldb, const float* bias, const float* W3,
                           float* C, int M, int N, int K) {
  dim3 g(cdiv(M, 128), N / TBN);
  mfma_gemm<128, 1, 1><<<g, 256, 0, s>>>(Ahg, Alg, Bhg, Blg, ldb, bias, W3, C, M, N, K);
}

// ---------------------------------------------------------------- row dots + out32 zero
// dp-dst rowdot + cp-dst rowdot + out32 zeroing in ONE launch (segment
// dispatch; rowdot bodies identical to the proven kernel; zeroing ordered
// before the cp slice aggregation that atomicAdds into out32)
__global__ __launch_bounds__(256) void rowdot_dc_z_kernel(
    const float* __restrict__ Hd, const float* __restrict__ ad, float* __restrict__ od, int nd,
    const float* __restrict__ Hc, const float* __restrict__ ac, float* __restrict__ oc, int nc,
    float* __restrict__ z, int nz, int bs1, int bs2) {
  int b = blockIdx.x;
  if (b >= bs2) {                        // zero segment
    int i = (b - bs2) * 256 + threadIdx.x;
    if (i < nz) z[i] = 0.f;
    return;
  }
  const float* H; const float* a; float* o; int n; int row;
  if (b < bs1) { H = Hd; a = ad; o = od; n = nd; row = b * 4 + (threadIdx.x >> 6); }
  else         { H = Hc; a = ac; o = oc; n = nc; row = (b - bs1) * 4 + (threadIdx.x >> 6); }
  if (row >= n) return;
  int lane = threadIdx.x & 63;
  const float* h = H + (size_t)row * HDIM;
  float s = 0.f;
#pragma unroll
  for (int u = 0; u < 4; ++u) {
    int c = lane + u * 64;
    s += h[c] * a[c];
  }
#pragma unroll
  for (int off = 32; off; off >>= 1) s += __shfl_down(s, off);
  if (lane == 0) o[row] = s;
}

// ---------------------------------------------------------------- counting sort by dst
__global__ __launch_bounds__(256) void hist_kernel(
    const int* __restrict__ src, const int* __restrict__ dst, int E, int nloops,
    int Nd, int* __restrict__ offs) {
  extern __shared__ int bins[];
  int tot = E + nloops;
  int chunk = (tot + NB - 1) / NB;
  int b = blockIdx.x;
  int s0 = b * chunk, s1 = min(s0 + chunk, tot);
  for (int i = threadIdx.x; i < Nd; i += 256) bins[i] = 0;
  __syncthreads();
  for (int i = s0 + threadIdx.x; i < s1; i += 256) {
    int d = (i < E) ? dst[i] : (i - E);
    atomicAdd(&bins[d], 1);
  }
  __syncthreads();
  for (int i = threadIdx.x; i < Nd; i += 256) offs[(size_t)i * NB + b] = bins[i];
}

__global__ __launch_bounds__(256) void scan_bins_kernel(
    int* __restrict__ offs, int* __restrict__ binsum, int Nd) {
  int d = blockIdx.x * 4 + (threadIdx.x >> 6);
  if (d >= Nd) return;
  int lane = threadIdx.x & 63;
  int* p = offs + (size_t)d * NB;
  int v0 = p[2 * lane], v1 = p[2 * lane + 1];
  int s = v0 + v1;
  int t = s;
#pragma unroll
  for (int o = 1; o < 64; o <<= 1) { int u = __shfl_up(t, o); if (lane >= o) t += u; }
  int excl = t - s;
  p[2 * lane] = excl;
  p[2 * lane + 1] = excl + v0;
  if (lane == 63) binsum[d] = t;
}

__global__ __launch_bounds__(256) void scan_base_kernel(
    const int* __restrict__ binsum, int* __restrict__ rowptr, int Nd) {
  __shared__ int wsum[4];
  __shared__ int carry;
  if (threadIdx.x == 0) carry = 0;
  __syncthreads();
  int lane = threadIdx.x & 63, w = threadIdx.x >> 6;
  for (int t0 = 0; t0 < Nd; t0 += 256) {
    int i = t0 + threadIdx.x;
    int v = (i < Nd) ? binsum[i] : 0;
    int t = v;
#pragma unroll
    for (int o = 1; o < 64; o <<= 1) { int u = __shfl_up(t, o); if (lane >= o) t += u; }
    if (lane == 63) wsum[w] = t;
    __syncthreads();
    int add = carry;
    for (int k = 0; k < w; ++k) add += wsum[k];
    if (i < Nd) rowptr[i] = t - v + add;
    __syncthreads();
    if (threadIdx.x == 0) carry += wsum[0] + wsum[1] + wsum[2] + wsum[3];
    __syncthreads();
  }
  if (threadIdx.x == 0) rowptr[Nd] = carry;
}

__global__ __launch_bounds__(256) void scatter_kernel(
    const int* __restrict__ src, const int* __restrict__ dst, int E, int nloops,
    int Nd, const int* __restrict__ offs, const int* __restrict__ rowptr,
    uint* __restrict__ sd) {
  extern __shared__ int bins[];
  int tot = E + nloops;
  int chunk = (tot + NB - 1) / NB;
  int b = blockIdx.x;
  int s0 = b * chunk, s1 = min(s0 + chunk, tot);
  for (int i = threadIdx.x; i < Nd; i += 256) bins[i] = 0;
  __syncthreads();
  for (int i = s0 + threadIdx.x; i < s1; i += 256) {
    int s_, d_;
    if (i < E) { s_ = src[i]; d_ = dst[i]; }
    else       { s_ = d_ = i - E; }
    int local = atomicAdd(&bins[d_], 1);
    int pos = rowptr[d_] + offs[(size_t)d_ * NB + b] + local;
    sd[pos] = (uint)s_ | ((uint)d_ << 16);
  }
}

// ---------------------------------------------------------------- fused GAT edge phase
// pp aggregator: wave per dst, split-plane output (proven body)
__global__ __launch_bounds__(256) void gat_agg_split(
    const int* __restrict__ rowptr, const uint* __restrict__ sd,
    const float* __restrict__ als, const float* __restrict__ ald,
    const ushort* __restrict__ Xb,
    ushort* __restrict__ aggh, ushort* __restrict__ aggl, int n) {
  int d = blockIdx.x * 4 + (threadIdx.x >> 6);
  if (d >= n) return;
  int lane = threadIdx.x & 63;
  int r0 = rowptr[d], r1 = rowptr[d + 1];
  float aldd = ald[d];
  float dsum = 0.f;
  for (int j = r0 + lane; j < r1; j += 64) {
    float e = als[sd[j] & 0xffff] + aldd;
    e = (e > 0.f) ? e : NEG_SLOPE * e;
    dsum += __expf(e);
  }
#pragma unroll
  for (int o = 32; o; o >>= 1) dsum += __shfl_xor(dsum, o);
  float rden = 1.f / (dsum + 1e-16f);

  float4 acc = make_float4(0.f, 0.f, 0.f, 0.f);
  for (int b = r0; b < r1; b += 64) {
    int j = b + lane;
    float exv = 0.f; int srcv = 0;
    if (j < r1) {
      uint p = sd[j];
      srcv = p & 0xffff;
      float e = als[srcv] + aldd;
      e = (e > 0.f) ? e : NEG_SLOPE * e;
      exv = __expf(e) * rden;
    }
    int cnt = min(64, r1 - b);
    for (int t0 = 0; t0 < cnt; t0 += 8) {
      float cf[8]; int sv[8];
#pragma unroll
      for (int u = 0; u < 8; ++u) {
        cf[u] = __shfl(exv, t0 + u);
        sv[u] = __shfl(srcv, t0 + u);
      }
      ushort4 hv[8];
#pragma unroll
      for (int u = 0; u < 8; ++u)
        hv[u] = *(const ushort4*)(Xb + (size_t)sv[u] * HDIM + lane * 4);
#pragma unroll
      for (int u = 0; u < 8; ++u) {
        acc.x += cf[u] * b2f(hv[u].x);
        acc.y += cf[u] * b2f(hv[u].y);
        acc.z += cf[u] * b2f(hv[u].z);
        acc.w += cf[u] * b2f(hv[u].w);
      }
    }
  }
  uint p0 = f2pl(acc.x), p1 = f2pl(acc.y), p2 = f2pl(acc.z), p3 = f2pl(acc.w);
  ushort4 h = {(ushort)(p0 & 0xffff), (ushort)(p1 & 0xffff), (ushort)(p2 & 0xffff), (ushort)(p3 & 0xffff)};
  ushort4 l = {(ushort)(p0 >> 16), (ushort)(p1 >> 16), (ushort)(p2 >> 16), (ushort)(p3 >> 16)};
  *(ushort4*)(aggh + (size_t)d * HDIM + lane * 4) = h;
  *(ushort4*)(aggl + (size_t)d * HDIM + lane * 4) = l;
}

// dp aggregate + cp slice-aggregate in ONE launch. Block-uniform segment
// dispatch; both bodies are the UNMODIFIED proven kernels (round-14). dp
// and cp phases are independent (disjoint inputs/outputs) so their small
// grids (500 + 800 blocks) co-schedule across the 256 CUs instead of
// serializing as two underfilled launches.
__global__ __launch_bounds__(256) void agg_dp_cp_kernel(
    const int* __restrict__ rp_d, const uint* __restrict__ sd_d,
    const float* __restrict__ als_d, const float* __restrict__ ald_d,
    ushort* __restrict__ aggh, ushort* __restrict__ aggl, int nd, int bsplit,
    const int* __restrict__ rp_c, const uint* __restrict__ sd_c,
    const float* __restrict__ als_c, const float* __restrict__ ald_c,
    float* __restrict__ out32, int nc, const ushort* __restrict__ Xb) {
  __shared__ float wd[4];
  if (blockIdx.x < bsplit) {
    // ---- dp: gat_agg_split body
    int d = blockIdx.x * 4 + (threadIdx.x >> 6);
    if (d >= nd) return;
    int lane = threadIdx.x & 63;
    int r0 = rp_d[d], r1 = rp_d[d + 1];
    float aldd = ald_d[d];
    float dsum = 0.f;
    for (int j = r0 + lane; j < r1; j += 64) {
      float e = als_d[sd_d[j] & 0xffff] + aldd;
      e = (e > 0.f) ? e : NEG_SLOPE * e;
      dsum += __expf(e);
    }
#pragma unroll
    for (int o = 32; o; o >>= 1) dsum += __shfl_xor(dsum, o);
    float rden = 1.f / (dsum + 1e-16f);

    float4 acc = make_float4(0.f, 0.f, 0.f, 0.f);
    for (int b = r0; b < r1; b += 64) {
      int j = b + lane;
      float exv = 0.f; int srcv = 0;
      if (j < r1) {
        uint p = sd_d[j];
        srcv = p & 0xffff;
        float e = als_d[srcv] + aldd;
        e = (e > 0.f) ? e : NEG_SLOPE * e;
        exv = __expf(e) * rden;
      }
      int cnt = min(64, r1 - b);
      for (int t0 = 0; t0 < cnt; t0 += 8) {
        float cf[8]; int sv[8];
#pragma unroll
        for (int u = 0; u < 8; ++u) {
          cf[u] = __shfl(exv, t0 + u);
          sv[u] = __shfl(srcv, t0 + u);
        }
        ushort4 hv[8];
#pragma unroll
        for (int u = 0; u < 8; ++u)
          hv[u] = *(const ushort4*)(Xb + (size_t)sv[u] * HDIM + lane * 4);
#pragma unroll
        for (int u = 0; u < 8; ++u) {
          acc.x += cf[u] * b2f(hv[u].x);
          acc.y += cf[u] * b2f(hv[u].y);
          acc.z += cf[u] * b2f(hv[u].z);
          acc.w += cf[u] * b2f(hv[u].w);
        }
      }
    }
    uint p0 = f2pl(acc.x), p1 = f2pl(acc.y), p2 = f2pl(acc.z), p3 = f2pl(acc.w);
    ushort4 h = {(ushort)(p0 & 0xffff), (ushort)(p1 & 0xffff), (ushort)(p2 & 0xffff), (ushort)(p3 & 0xffff)};
    ushort4 l = {(ushort)(p0 >> 16), (ushort)(p1 >> 16), (ushort)(p2 >> 16), (ushort)(p3 >> 16)};
    *(ushort4*)(aggh + (size_t)d * HDIM + lane * 4) = h;
    *(ushort4*)(aggl + (size_t)d * HDIM + lane * 4) = l;
  } else {
    // ---- cp: gat_agg_slice body (atomicAdd partials into pre-zeroed out32)
    int bb = blockIdx.x - bsplit;
    int d = bb / SLICES;
    int sl = bb - d * SLICES;
    if (d >= nc) return;
    int lane = threadIdx.x & 63, w = threadIdx.x >> 6;
    int r0 = rp_c[d], r1 = rp_c[d + 1];
    float aldd = ald_c[d];
    float dsum = 0.f;
    for (int j = r0 + threadIdx.x; j < r1; j += 256) {
      float e = als_c[sd_c[j] & 0xffff] + aldd;
      e = (e > 0.f) ? e : NEG_SLOPE * e;
      dsum += __expf(e);
    }
#pragma unroll
    for (int o = 32; o; o >>= 1) dsum += __shfl_xor(dsum, o);
    if (lane == 0) wd[w] = dsum;
    __syncthreads();
    float rden = 1.f / (wd[0] + wd[1] + wd[2] + wd[3] + 1e-16f);
    int deg = r1 - r0;
    int per_b = (deg + SLICES - 1) / SLICES;
    int b0 = r0 + sl * per_b, b1 = min(b0 + per_b, r1);
    int wdeg = b1 - b0;
    if (wdeg <= 0) return;
    int per_w = (wdeg + 3) >> 2;
    int w0 = b0 + w * per_w, w1 = min(w0 + per_w, b1);

    float4 acc = make_float4(0.f, 0.f, 0.f, 0.f);
    for (int b = w0; b < w1; b += 64) {
      int j = b + lane;
      float exv = 0.f; int srcv = 0;
      if (j < w1) {
        uint p = sd_c[j];
        srcv = p & 0xffff;
        float e = als_c[srcv] + aldd;
        e = (e > 0.f) ? e : NEG_SLOPE * e;
        exv = __expf(e) * rden;
      }
      int cnt = min(64, w1 - b);
      for (int t0 = 0; t0 < cnt; t0 += 8) {
        float cf[8]; int sv[8];
#pragma unroll
        for (int u = 0; u < 8; ++u) {
          cf[u] = __shfl(exv, t0 + u);
          sv[u] = __shfl(srcv, t0 + u);
        }
        ushort4 hv[8];
#pragma unroll
        for (int u = 0; u < 8; ++u)
          hv[u] = *(const ushort4*)(Xb + (size_t)sv[u] * HDIM + lane * 4);
#pragma unroll
        for (int u = 0; u < 8; ++u) {
          acc.x += cf[u] * b2f(hv[u].x);
          acc.y += cf[u] * b2f(hv[u].y);
          acc.z += cf[u] * b2f(hv[u].z);
          acc.w += cf[u] * b2f(hv[u].w);
        }
      }
    }
    float* o = out32 + (size_t)d * HDIM + lane * 4;
    atomicAdd(o + 0, acc.x); atomicAdd(o + 1, acc.y);
    atomicAdd(o + 2, acc.z); atomicAdd(o + 3, acc.w);
  }
}

// ---------------------------------------------------------------- norms
__global__ __launch_bounds__(256) void l2norm_f32b_dots_kernel(
    const float* __restrict__ in, float* __restrict__ outf, ushort* __restrict__ outb,
    const float* __restrict__ v1, const float* __restrict__ v2,
    const float* __restrict__ v3, const float* __restrict__ v4,
    float* __restrict__ o1, float* __restrict__ o2,
    float* __restrict__ o3, float* __restrict__ o4, int n) {
  int row = blockIdx.x * 4 + (threadIdx.x >> 6);
  if (row >= n) return;
  int lane = threadIdx.x & 63;
  float v[4];
  float ss = 0.f;
#pragma unroll
  for (int u = 0; u < 4; ++u) {
    float t = in[(size_t)row * HDIM + lane + u * 64];
    v[u] = t; ss += t * t;
  }
#pragma unroll
  for (int off = 32; off; off >>= 1) ss += __shfl_xor(ss, off);
  float sc = 1.0f / fmaxf(sqrtf(ss), 1e-12f);
  float d1 = 0.f, d2 = 0.f, d3 = 0.f, d4 = 0.f;
#pragma unroll
  for (int u = 0; u < 4; ++u) {
    float f = v[u] * sc;
    int c = lane + u * 64;
    outf[(size_t)row * HDIM + c] = f;
    outb[(size_t)row * HDIM + c] = f2b(f);
    d1 += f * v1[c];
    d2 += f * v2[c];
    if (o3) { d3 += f * v3[c]; d4 += f * v4[c]; }
  }
#pragma unroll
  for (int off = 32; off; off >>= 1) {
    d1 += __shfl_xor(d1, off);
    d2 += __shfl_xor(d2, off);
    if (o3) { d3 += __shfl_xor(d3, off); d4 += __shfl_xor(d4, off); }
  }
  if (lane == 0) {
    o1[row] = d1; o2[row] = d2;
    if (o3) { o3[row] = d3; o4[row] = d4; }
  }
}

// fp32 in -> l2norm -> split hi/lo out; drug + cell tables in ONE launch
__global__ __launch_bounds__(256) void l2norm_split_dc_kernel(
    const float* __restrict__ Xd, ushort* __restrict__ dh, ushort* __restrict__ dl, int nd,
    const float* __restrict__ Xc, ushort* __restrict__ ch, ushort* __restrict__ cl, int nc,
    int bsplit) {
  int b = blockIdx.x;
  const float* in; ushort* oh; ushort* ol; int n; int row;
  if (b < bsplit) { in = Xd; oh = dh; ol = dl; n = nd; row = b * 4 + (threadIdx.x >> 6); }
  else            { in = Xc; oh = ch; ol = cl; n = nc; row = (b - bsplit) * 4 + (threadIdx.x >> 6); }
  if (row >= n) return;
  int lane = threadIdx.x & 63;
  float v[4];
  float ss = 0.f;
#pragma unroll
  for (int u = 0; u < 4; ++u) {
    int c = lane + u * 64;
    float t = in[(size_t)row * HDIM + c];
    v[u] = t;
    ss += t * t;
  }
#pragma unroll
  for (int off = 32; off; off >>= 1) ss += __shfl_xor(ss, off);
  float sc = 1.0f / fmaxf(sqrtf(ss), 1e-12f);
#pragma unroll
  for (int u = 0; u < 4; ++u) {
    int c = lane + u * 64;
    uint p = f2pl(v[u] * sc);
    oh[(size_t)row * HDIM + c] = (ushort)(p & 0xffff);
    ol[(size_t)row * HDIM + c] = (ushort)(p >> 16);
  }
}

// ---------------------------------------------------------------- host side
static void build_sorted(hipStream_t stream,
                         const int* src, const int* dst, int E, int nloops, int Nd,
                         int* offs, int* binsum, int* rowptr, uint* sd) {
  size_t lds = (size_t)Nd * sizeof(int);
  hist_kernel<<<NB, 256, lds, stream>>>(src, dst, E, nloops, Nd, offs);
  scan_bins_kernel<<<cdiv(Nd, 4), 256, 0, stream>>>(offs, binsum, Nd);
  scan_base_kernel<<<1, 256, 0, stream>>>(binsum, rowptr, Nd);
  scatter_kernel<<<NB, 256, lds, stream>>>(src, dst, E, nloops, Nd, offs, rowptr, sd);
}

extern "C" void kernel_launch(void* const* d_in, const int* in_sizes, int n_in,
                              void* d_out, int out_size, void* d_ws, size_t ws_size,
                              hipStream_t stream) {
  const float* drug_emb = (const float*)d_in[0];
  const float* prot_emb = (const float*)d_in[1];
  const float* cell_emb = (const float*)d_in[2];
  const float* W_pp = (const float*)d_in[3];
  const float* as_pp = (const float*)d_in[4];
  const float* ad_pp = (const float*)d_in[5];
  const float* b_pp = (const float*)d_in[6];
  const float* W_dp = (const float*)d_in[7];
  const float* as_dp = (const float*)d_in[8];
  const float* ad_dp = (const float*)d_in[9];
  const float* b_dp = (const float*)d_in[10];
  const float* W_cp = (const float*)d_in[11];
  const float* as_cp = (const float*)d_in[12];
  const float* ad_cp = (const float*)d_in[13];
  const float* b_cp = (const float*)d_in[14];
  const float* W1 = (const float*)d_in[15];
  const float* b1 = (const float*)d_in[16];
  const float* W2 = (const float*)d_in[17];
  const float* b2 = (const float*)d_in[18];
  const float* W3 = (const float*)d_in[19];
  const float* b3 = (const float*)d_in[20];
  const int* edge_pp = (const int*)d_in[21];
  const int* edge_dp = (const int*)d_in[22];
  const int* edge_cp = (const int*)d_in[23];
  const int* drug1 = (const int*)d_in[24];
  const int* drug2 = (const int*)d_in[25];
  const int* cellb = (const int*)d_in[26];

  const int ND = in_sizes[0] / HDIM;   // 2000
  const int NP = in_sizes[1] / HDIM;   // 19000
  const int NC = in_sizes[2] / HDIM;   // 100
  const int L = in_sizes[3] / (HDIM * HDIM);  // 2
  const int E_pp = in_sizes[21] / 2;
  const int E_dp = in_sizes[22] / 2;
  const int E_cp = in_sizes[23] / 2;
  const int B = in_sizes[24];          // 8192
  (void)n_in; (void)out_size;

  const int* src_pp = edge_pp;          const int* dst_pp = edge_pp + E_pp;
  const int* src_dp = edge_dp;          const int* dst_dp = edge_dp + E_dp;
  const int* src_cp = edge_cp;          const int* dst_cp = edge_cp + E_cp;
  const int tot_pp = E_pp + NP, tot_dp = E_dp, tot_cp = E_cp;
  int maxN = NP > ND ? NP : ND; if (NC > maxN) maxN = NC;

  // ---------------- workspace
  char* wsb = (char*)d_ws;
  size_t off = 0;
  auto alloc = [&](size_t bytes) -> void* {
    void* p = wsb + off;
    off += (bytes + 255) & ~(size_t)255;
    return p;
  };

  float* Xp  = (float*)alloc((size_t)NP * HDIM * 4);    // protein state fp32
  ushort* Xpb = (ushort*)alloc((size_t)NP * HDIM * 2);  // protein state bf16 (gather)
  float* Xd  = (float*)alloc((size_t)ND * HDIM * 4);
  float* Xc  = (float*)alloc((size_t)NC * HDIM * 4);
  ushort* xdnh = (ushort*)alloc((size_t)ND * HDIM * 2);
  ushort* xdnl = (ushort*)alloc((size_t)ND * HDIM * 2);
  ushort* xcnh = (ushort*)alloc((size_t)NC * HDIM * 2);
  ushort* xcnl = (ushort*)alloc((size_t)NC * HDIM * 2);
  ushort* WTpph = (ushort*)alloc((size_t)L * HDIM * HDIM * 2);
  ushort* WTppl = (ushort*)alloc((size_t)L * HDIM * HDIM * 2);
  ushort* WTdph = (ushort*)alloc((size_t)L * HDIM * HDIM * 2);
  ushort* WTdpl = (ushort*)alloc((size_t)L * HDIM * HDIM * 2);
  ushort* WTcph = (ushort*)alloc((size_t)L * HDIM * HDIM * 2);
  ushort* WTcpl = (ushort*)alloc((size_t)L * HDIM * HDIM * 2);
  ushort* cth = (ushort*)alloc((size_t)NC * HDIM * 2);  // cp split staging
  ushort* ctl = (ushort*)alloc((size_t)NC * HDIM * 2);
  float* wv  = (float*)alloc((size_t)L * 6 * HDIM * 4); // folded W@a vectors
  float* pals = (float*)alloc((size_t)maxN * 4);        // pp src logits
  float* pald = (float*)alloc((size_t)maxN * 4);        // pp dst logits
  float* als1 = (float*)alloc((size_t)maxN * 4);        // dp src logits
  float* als2 = (float*)alloc((size_t)maxN * 4);        // cp src logits
  float* ald1 = (float*)alloc((size_t)maxN * 4);
  float* ald2 = (float*)alloc((size_t)maxN * 4);
  int* binsum = (int*)alloc((size_t)maxN * 4);
  int* rp_pp = (int*)alloc((size_t)(NP + 1) * 4);
  int* rp_dp = (int*)alloc((size_t)(ND + 1) * 4);
  int* rp_cp = (int*)alloc((size_t)(NC + 1) * 4);
  uint* sd_pp = (uint*)alloc((size_t)tot_pp * 4);
  uint* sd_dp = (uint*)alloc((size_t)tot_dp * 4);
  uint* sd_cp = (uint*)alloc((size_t)tot_cp * 4);
  float* out32 = (float*)alloc((size_t)NC * HDIM * 4);  // cp partial accumulator
  size_t S0 = off;

  // scratch S overlays: [offs] -> [aggh|aggl|tmp] -> [W1T*|W2T*|P1|P2|P3|h1*]
  int* offs = (int*)(wsb + S0);
  build_sorted(stream, src_pp, dst_pp, E_pp, NP, NP, offs, binsum, rp_pp, sd_pp);
  build_sorted(stream, src_dp, dst_dp, E_dp, 0, ND, offs, binsum, rp_dp, sd_dp);
  build_sorted(stream, src_cp, dst_cp, E_cp, 0, NC, offs, binsum, rp_cp, sd_cp);

  // ---- weight split planes (batched) + folded attention vectors + protein prep
  wconv_split3_kernel<<<cdiv(3 * L * HDIM * HDIM, 256), 256, 0, stream>>>(
      W_pp, W_dp, W_cp, WTpph, WTppl, WTdph, WTdpl, WTcph, WTcpl, L);
  matvec_all_kernel<<<L * 6, 256, 0, stream>>>(W_pp, as_pp, ad_pp, W_dp, as_dp, ad_dp,
                                               W_cp, as_cp, ad_cp, wv);
  // layer-0: Xpb bf16 copy + pp logits in one pass over prot_emb
  prep_p_kernel<<<cdiv(NP, 4), 256, 0, stream>>>(prot_emb, Xpb, wv + 0 * HDIM, wv + 1 * HDIM,
                                                 pals, pald, NP);

  size_t aggB = ((size_t)NP * HDIM * 2 + 255) & ~(size_t)255;
  ushort* aggh = (ushort*)(wsb + S0);
  ushort* aggl = (ushort*)(wsb + S0 + aggB);
  float* tmp = (float*)(wsb + S0 + 2 * aggB);

  for (int l = 0; l < L; ++l) {
    const int WOFF = l * HDIM * HDIM, VOFF = l * HDIM;
    const float* wvl = wv + (size_t)l * 6 * HDIM;
    bool last = (l == L - 1);
    const float* wvn = last ? wvl : wv + (size_t)(l + 1) * 6 * HDIM;
    const float* Xd_cur = (l == 0) ? drug_emb : Xd;
    const float* Xc_cur = (l == 0) ? cell_emb : Xc;

    // ---- p-p: aggregate x -> transform -> l2norm (+fused dots for dp/cp/next-pp)
    gat_agg_split<<<cdiv(NP, 4), 256, 0, stream>>>(rp_pp, sd_pp, pals, pald, Xpb, aggh, aggl, NP);
    gemm_launch<128, 0>(stream, aggh, aggl, WTpph + WOFF, WTppl + WOFF, HDIM,
                        b_pp + VOFF, tmp, NP, HDIM, HDIM);
    l2norm_f32b_dots_kernel<<<cdiv(NP, 4), 256, 0, stream>>>(
        tmp, Xp, Xpb,
        wvl + 2 * HDIM, wvl + 4 * HDIM,
        last ? nullptr : (wvn + 0 * HDIM), last ? nullptr : (wvn + 1 * HDIM),
        als1, als2, last ? nullptr : pals, last ? nullptr : pald, NP);

    // dp rowdot + cp rowdot + out32 zeroing, one launch
    {
      int bs1 = cdiv(ND, 4), bs2 = bs1 + cdiv(NC, 4);
      int nz = NC * HDIM;
      rowdot_dc_z_kernel<<<bs2 + cdiv(nz, 256), 256, 0, stream>>>(
          Xd_cur, wvl + 3 * HDIM, ald1, ND,
          Xc_cur, wvl + 5 * HDIM, ald2, NC,
          out32, nz, bs1, bs2);
    }

    // ---- dp aggregate + cp slice-aggregate, one launch (independent phases)
    {
      int bsplit = cdiv(ND, 4);
      agg_dp_cp_kernel<<<bsplit + NC * SLICES, 256, 0, stream>>>(
          rp_dp, sd_dp, als1, ald1, aggh, aggl, ND, bsplit,
          rp_cp, sd_cp, als2, ald2, out32, NC, Xpb);
    }

    // ---- d-p transform (M=ND)
    gemm_launch<64, 1>(stream, aggh, aggl, WTdph + WOFF, WTdpl + WOFF, HDIM,
                       b_dp + VOFF, Xd, ND, HDIM, HDIM);

    // ---- c-p: split -> transform (M=NC)
    f32_to_split_kernel<<<cdiv(NC * HDIM, 256), 256, 0, stream>>>(out32, cth, ctl, NC * HDIM);
    gemm_launch<64, 1>(stream, cth, ctl, WTcph + WOFF, WTcpl + WOFF, HDIM,
                       b_cp + VOFF, Xc, NC, HDIM, HDIM);
  }

  // ---------------- head
  l2norm_split_dc_kernel<<<cdiv(ND, 4) + cdiv(NC, 4), 256, 0, stream>>>(
      Xd, xdnh, xdnl, ND, Xc, xcnh, xcnl, NC, cdiv(ND, 4));

  const int N1 = 6 * HDIM;   // 1536
  const int N2 = 2 * HDIM;   // 512
  const int K1 = 3 * HDIM;   // 768
  ushort* W1Th = (ushort*)(wsb + S0);                   // [1536][768]
  ushort* W1Tl = W1Th + (size_t)N1 * K1;
  ushort* W2Th = W1Tl + (size_t)N1 * K1;                // [512][1536]
  ushort* W2Tl = W2Th + (size_t)N2 * N1;
  float* P1 = (float*)(W2Tl + (size_t)N2 * N1);         // [ND][1536]
  float* P2 = P1 + (size_t)ND * N1;
  float* P3 = P2 + (size_t)ND * N1;                     // [NC][1536]
  ushort* h1h = (ushort*)(P3 + (size_t)NC * N1);        // [CH][1536] split
  size_t wsz = ws_size ? ws_size : ((size_t)1 << 30);
  size_t fixed = S0 + ((size_t)N1 * K1 + (size_t)N2 * N1) * 4
               + ((size_t)(2 * ND + NC) * N1) * 4;
  int CH = 8192;
  while (CH > 1024 && fixed + (size_t)CH * N1 * 4 > wsz) CH >>= 1;
  ushort* h1l = h1h + (size_t)CH * N1;

  wconv_split_kernel<<<cdiv(K1 * N1, 256), 256, 0, stream>>>(W1, W1Th, W1Tl, K1, N1);
  wconv_split_kernel<<<cdiv(N1 * N2, 256), 256, 0, stream>>>(W2, W2Th, W2Tl, N1, N2);

  gemm_launch<64, 0>(stream, xdnh, xdnl, W1Th, W1Tl, K1, nullptr, P1, ND, N1, HDIM);
  gemm_launch<64, 0>(stream, xdnh, xdnl, W1Th + HDIM, W1Tl + HDIM, K1, nullptr, P2, ND, N1, HDIM);
  gemm_launch<64, 0>(stream, xcnh, xcnl, W1Th + 2 * HDIM, W1Tl + 2 * HDIM, K1, b1, P3, NC, N1, HDIM);

  float* outp = (float*)d_out;
  fill_out2_kernel<<<cdiv(B, 256), 256, 0, stream>>>(outp, b3, B);
  for (int c0 = 0; c0 < B; c0 += CH) {
    int M = (B - c0) < CH ? (B - c0) : CH;
    combine_h1_kernel<<<cdiv(M * (N1 / 4), 256), 256, 0, stream>>>(
        P1, P2, P3, drug1, drug2, cellb, c0, h1h, h1l, M, N1);
    gemm_launch_f3(stream, h1h, h1l, W2Th, W2Tl, N1, b2, W3,
                   outp + (size_t)c0 * 2, M, N2, N1);
  }
}

// Round 16
// 653.207 us; speedup vs baseline: 1.1322x; 1.0413x over previous
//
#include <hip/hip_runtime.h>
#include <hip/hip_bf16.h>

#define HDIM 256
#define NEG_SLOPE 0.2f
#define NB 128          // blocks for hist/scatter
#define SLICES 8        // edge slices per dst in the big-degree aggregator
#define TBN 64
#define TBK 32

typedef __attribute__((ext_vector_type(8))) short bf16x8;
typedef __attribute__((ext_vector_type(4))) float f32x4;

// split-bf16: x ~= bf16(hi) + bf16(lo); stored as two separate ushort arrays
__device__ inline uint f2pl(float x) {
  __hip_bfloat16 h = __float2bfloat16(x);
  ushort hi = *(ushort*)&h;
  float r = x - __bfloat162float(h);
  __hip_bfloat16 l = __float2bfloat16(r);
  ushort lo = *(ushort*)&l;
  return (uint)hi | ((uint)lo << 16);
}
__device__ inline ushort f2b(float x) {
  __hip_bfloat16 h = __float2bfloat16(x);
  return *(ushort*)&h;
}
__device__ inline float b2f(ushort u) {
  uint x = ((uint)u) << 16;
  return __int_as_float((int)x);
}

static inline int cdiv(int a, int b) { return (a + b - 1) / b; }

// ---------------------------------------------------------------- utilities
__global__ void fill_out2_kernel(float* __restrict__ out, const float* __restrict__ b3, int M) {
  int i = blockIdx.x * 256 + threadIdx.x;
  if (i >= M) return;
  out[(size_t)i * 2 + 0] = b3[0];
  out[(size_t)i * 2 + 1] = b3[1];
}

// W[K][N] fp32 -> WTh/WTl[N][K] split
__global__ void wconv_split_kernel(const float* __restrict__ W,
                                   ushort* __restrict__ WTh, ushort* __restrict__ WTl,
                                   int K, int N) {
  int i = blockIdx.x * 256 + threadIdx.x;
  if (i >= K * N) return;
  int k = i / N, n = i - k * N;
  uint p = f2pl(W[i]);
  WTh[(size_t)n * K + k] = (ushort)(p & 0xffff);
  WTl[(size_t)n * K + k] = (ushort)(p >> 16);
}

// batched layer-weight conversion: all 3 edge types x L layers in one launch
__global__ void wconv_split3_kernel(
    const float* __restrict__ Wpp, const float* __restrict__ Wdp, const float* __restrict__ Wcp,
    ushort* __restrict__ WTpph, ushort* __restrict__ WTppl,
    ushort* __restrict__ WTdph, ushort* __restrict__ WTdpl,
    ushort* __restrict__ WTcph, ushort* __restrict__ WTcpl, int L) {
  const int per = HDIM * HDIM;
  int i = blockIdx.x * 256 + threadIdx.x;
  if (i >= 3 * L * per) return;
  int mat = i / per;
  int r = i - mat * per;
  int l = mat / 3, ty = mat - l * 3;
  const float* W = (ty == 0 ? Wpp : ty == 1 ? Wdp : Wcp) + (size_t)l * per;
  ushort* Th = (ty == 0 ? WTpph : ty == 1 ? WTdph : WTcph) + (size_t)l * per;
  ushort* Tl = (ty == 0 ? WTppl : ty == 1 ? WTdpl : WTcpl) + (size_t)l * per;
  int k = r >> 8, n = r & (HDIM - 1);    // r = k*HDIM + n
  uint p = f2pl(W[r]);
  Th[(size_t)n * HDIM + k] = (ushort)(p & 0xffff);
  Tl[(size_t)n * HDIM + k] = (ushort)(p >> 16);
}

__global__ void f32_to_split_kernel(const float* __restrict__ in,
                                    ushort* __restrict__ oh, ushort* __restrict__ ol, int n) {
  int i = blockIdx.x * 256 + threadIdx.x;
  if (i >= n) return;
  uint p = f2pl(in[i]);
  oh[i] = (ushort)(p & 0xffff);
  ol[i] = (ushort)(p >> 16);
}

// wv[b][k] = sum_n W[k][n]*a[n]  (the folded attention vector W @ a)
__global__ __launch_bounds__(256) void matvec_all_kernel(
    const float* __restrict__ Wpp, const float* __restrict__ aspp, const float* __restrict__ adpp,
    const float* __restrict__ Wdp, const float* __restrict__ asdp, const float* __restrict__ addp,
    const float* __restrict__ Wcp, const float* __restrict__ ascp, const float* __restrict__ adcp,
    float* __restrict__ wv) {
  int b = blockIdx.x;
  int l = b / 6, r = b - l * 6, type = r >> 1, isd = r & 1;
  const float* W = (type == 0 ? Wpp : type == 1 ? Wdp : Wcp) + (size_t)l * HDIM * HDIM;
  const float* a = (type == 0 ? (isd ? adpp : aspp)
                  : type == 1 ? (isd ? addp : asdp)
                              : (isd ? adcp : ascp)) + (size_t)l * HDIM;
  int k = threadIdx.x;
  const float4* Wr = (const float4*)(W + (size_t)k * HDIM);
  float s = 0.f;
#pragma unroll 8
  for (int n4 = 0; n4 < HDIM / 4; ++n4) {
    float4 w = Wr[n4];
    float4 av = *(const float4*)(a + n4 * 4);
    s += w.x * av.x + w.y * av.y + w.z * av.z + w.w * av.w;
  }
  wv[(size_t)b * HDIM + k] = s;
}

// layer-0 protein prep: bf16 copy of prot_emb + the two pp rowdots, one pass
__global__ __launch_bounds__(256) void prep_p_kernel(
    const float* __restrict__ in, ushort* __restrict__ outb,
    const float* __restrict__ a1, const float* __restrict__ a2,
    float* __restrict__ o1, float* __restrict__ o2, int n) {
  int row = blockIdx.x * 4 + (threadIdx.x >> 6);
  if (row >= n) return;
  int lane = threadIdx.x & 63;
  float s1 = 0.f, s2 = 0.f;
#pragma unroll
  for (int u = 0; u < 4; ++u) {
    int c = lane + u * 64;
    float hv = in[(size_t)row * HDIM + c];
    outb[(size_t)row * HDIM + c] = f2b(hv);
    s1 += hv * a1[c];
    s2 += hv * a2[c];
  }
#pragma unroll
  for (int off = 32; off; off >>= 1) {
    s1 += __shfl_down(s1, off);
    s2 += __shfl_down(s2, off);
  }
  if (lane == 0) { o1[row] = s1; o2[row] = s2; }
}

// h1 combine -> split planes (P3 carries bias b1). Done ONCE per element.
__global__ __launch_bounds__(256) void combine_h1_kernel(
    const float* __restrict__ P1, const float* __restrict__ P2, const float* __restrict__ P3,
    const int* __restrict__ g1, const int* __restrict__ g2, const int* __restrict__ g3,
    int row0, ushort* __restrict__ h1h, ushort* __restrict__ h1l, int M, int K) {
  int t = blockIdx.x * 256 + threadIdx.x;
  int kq = K >> 2;
  if (t >= M * kq) return;
  int row = t / kq, c4 = t - row * kq;
  int bi = row0 + row;
  size_t o = (size_t)c4 * 4;
  float4 a = *(const float4*)(P1 + (size_t)g1[bi] * K + o);
  float4 b = *(const float4*)(P2 + (size_t)g2[bi] * K + o);
  float4 c = *(const float4*)(P3 + (size_t)g3[bi] * K + o);
  uint p0 = f2pl(fmaxf(a.x + b.x + c.x, 0.f));
  uint p1 = f2pl(fmaxf(a.y + b.y + c.y, 0.f));
  uint p2 = f2pl(fmaxf(a.z + b.z + c.z, 0.f));
  uint p3 = f2pl(fmaxf(a.w + b.w + c.w, 0.f));
  ushort4 h = {(ushort)(p0 & 0xffff), (ushort)(p1 & 0xffff), (ushort)(p2 & 0xffff), (ushort)(p3 & 0xffff)};
  ushort4 l = {(ushort)(p0 >> 16), (ushort)(p1 >> 16), (ushort)(p2 >> 16), (ushort)(p3 >> 16)};
  *(ushort4*)(h1h + (size_t)row * K + o) = h;
  *(ushort4*)(h1l + (size_t)row * K + o) = l;
}

// ---------------------------------------------------------------- MFMA GEMM
// C = act(A@B + bias), fp32 out. A,B pre-split hi/lo ushort arrays.
// ROUND-10 PROVEN STRUCTURE (best known; all structural neighbors regressed).
// Body refactored VERBATIM into a device function taking (mb, nb) + a shared
// struct reference so it can be driven either by a 2D grid (standalone) or
// by a flat segmented grid (merged small GEMMs). M-fast ordering preserved.
// LDS layout: granule-major WITH slot rotation; 2-deep register pipeline;
// one barrier per k-step. FUSE3: head3 fused epilogue (atomicAdd logits).
template <int TBM_>
struct GemmSmem {
  ushort Ah[2][4][TBM_ / 16][16][8];
  ushort Al[2][4][TBM_ / 16][16][8];
  ushort Bh[2][4][TBN / 16][16][8];
  ushort Bl[2][4][TBN / 16][16][8];
};

template <int TBM_, int ACT, int FUSE3>
__device__ __forceinline__ void gemm_body(
    GemmSmem<TBM_>& sm,
    const ushort* __restrict__ Ahg, const ushort* __restrict__ Alg,
    const ushort* __restrict__ Bhg, const ushort* __restrict__ Blg,
    int ldb, const float* __restrict__ bias, const float* __restrict__ W3g,
    float* __restrict__ C, int M, int N, int K, int mb, int nb) {
  constexpr int NU = TBM_ / 64;   // A 16B-load instrs per thread (64 rows/round)
  constexpr int TM = TBM_ / 32;   // 16-row tiles per wave (M dir)

  const int tid = threadIdx.x;
  const int lane = tid & 63;
  const int wid = tid >> 6;
  const int wm = wid & 1, wn = wid >> 1;
  const int l16 = lane & 15;
  const int quad = lane >> 4;
  const int m0 = mb * TBM_;
  const int n0 = nb * TBN;

  const int gq = lane & 3;         // k-granule (8 ushorts = 16B) this lane stages
  const int co = gq * 8;           // ushort col within 32-ushort k-chunk
  const int r4 = lane >> 2;        // row within 16-row stripe
  const int wslot = (r4 + 2 * gq) & 15;          // rotated write slot
  const int rslot = (l16 + 2 * quad) & 15;       // rotated read slot

  uint4 rah0[NU], ral0[NU], rbh0, rbl0;   // register set 0
  uint4 rah1[NU], ral1[NU], rbh1, rbl1;   // register set 1

  auto LOADA = [&](uint4* rah, uint4* ral, uint4& rbh, uint4& rbl, int k0) {
#pragma unroll
    for (int u = 0; u < NU; ++u) {
      int r = wid * (TBM_ / 4) + r4 + 16 * u;
      int gm = m0 + r;
      if (gm < M) {
        size_t o = (size_t)gm * K + k0 + co;
        rah[u] = *(const uint4*)(Ahg + o);
        ral[u] = *(const uint4*)(Alg + o);
      } else {
        rah[u] = make_uint4(0, 0, 0, 0);
        ral[u] = make_uint4(0, 0, 0, 0);
      }
    }
    {
      int r = wid * 16 + r4;
      size_t o = (size_t)(n0 + r) * ldb + k0 + co;
      rbh = *(const uint4*)(Bhg + o);
      rbl = *(const uint4*)(Blg + o);
    }
  };
  auto STORE = [&](const uint4* rah, const uint4* ral, const uint4& rbh, const uint4& rbl, int b) {
#pragma unroll
    for (int u = 0; u < NU; ++u) {
      int ch = (wid * (TBM_ / 4) + 16 * u) >> 4;   // row chunk (r4 < 16)
      *(uint4*)&sm.Ah[b][gq][ch][wslot][0] = rah[u];
      *(uint4*)&sm.Al[b][gq][ch][wslot][0] = ral[u];
    }
    *(uint4*)&sm.Bh[b][gq][wid][wslot][0] = rbh;
    *(uint4*)&sm.Bl[b][gq][wid][wslot][0] = rbl;
  };

  f32x4 acc[TM][2];
#pragma unroll
  for (int i = 0; i < TM; ++i)
#pragma unroll
    for (int j = 0; j < 2; ++j) acc[i][j] = (f32x4){0.f, 0.f, 0.f, 0.f};

  auto COMPUTE = [&](int b) {
    bf16x8 ahf[TM], alf[TM], bhf[2], blf[2];
#pragma unroll
    for (int t = 0; t < TM; ++t) {
      int ch = wm * (TBM_ / 32) + t;
      ahf[t] = *(const bf16x8*)&sm.Ah[b][quad][ch][rslot][0];
      alf[t] = *(const bf16x8*)&sm.Al[b][quad][ch][rslot][0];
    }
#pragma unroll
    for (int t = 0; t < 2; ++t) {
      int ch = wn * 2 + t;
      bhf[t] = *(const bf16x8*)&sm.Bh[b][quad][ch][rslot][0];
      blf[t] = *(const bf16x8*)&sm.Bl[b][quad][ch][rslot][0];
    }
#pragma unroll
    for (int tm = 0; tm < TM; ++tm)
#pragma unroll
      for (int tn = 0; tn < 2; ++tn) {
        acc[tm][tn] = __builtin_amdgcn_mfma_f32_16x16x32_bf16(ahf[tm], bhf[tn], acc[tm][tn], 0, 0, 0);
        acc[tm][tn] = __builtin_amdgcn_mfma_f32_16x16x32_bf16(ahf[tm], blf[tn], acc[tm][tn], 0, 0, 0);
        acc[tm][tn] = __builtin_amdgcn_mfma_f32_16x16x32_bf16(alf[tm], bhf[tn], acc[tm][tn], 0, 0, 0);
      }
  };

  // prologue: tiles t0,t1 in regs; t0 -> buf0
  const int NK = K / TBK;            // even, >= 4 for all shapes used
  LOADA(rah0, ral0, rbh0, rbl0, 0);
  LOADA(rah1, ral1, rbh1, rbl1, TBK);
  STORE(rah0, ral0, rbh0, rbl0, 0);
  int k = 2 * TBK;
  for (int t = 0; t < (NK - 2) / 2; ++t) {
    __syncthreads();
    LOADA(rah0, ral0, rbh0, rbl0, k);   // t+2 in flight
    COMPUTE(0);                          // tile t (buf0)
    STORE(rah1, ral1, rbh1, rbl1, 1);    // t+1 -> buf1
    k += TBK;
    __syncthreads();
    LOADA(rah1, ral1, rbh1, rbl1, k);
    COMPUTE(1);
    STORE(rah0, ral0, rbh0, rbl0, 0);
    k += TBK;
  }
  __syncthreads();
  COMPUTE(0);
  STORE(rah1, ral1, rbh1, rbl1, 1);
  __syncthreads();
  COMPUTE(1);

  if (FUSE3) {
    // relu(acc+bias) . W3 -> per-row (s0,s1); reduce over the 16 l16 lanes
    // sharing a row; leader atomicAdds into b3-prefilled C[M][2].
#pragma unroll
    for (int tm = 0; tm < TM; ++tm) {
#pragma unroll
      for (int r = 0; r < 4; ++r) {
        int row = m0 + wm * (TBM_ / 2) + tm * 16 + quad * 4 + r;
        float s0 = 0.f, s1 = 0.f;
#pragma unroll
        for (int tn = 0; tn < 2; ++tn) {
          int col = n0 + wn * 32 + tn * 16 + l16;
          float v = fmaxf(acc[tm][tn][r] + bias[col], 0.f);
          s0 += v * W3g[col * 2 + 0];
          s1 += v * W3g[col * 2 + 1];
        }
#pragma unroll
        for (int o = 1; o < 16; o <<= 1) {
          s0 += __shfl_xor(s0, o);
          s1 += __shfl_xor(s1, o);
        }
        if (l16 == 0 && row < M) {
          atomicAdd(&C[(size_t)row * 2 + 0], s0);
          atomicAdd(&C[(size_t)row * 2 + 1], s1);
        }
      }
    }
  } else {
#pragma unroll
    for (int tn = 0; tn < 2; ++tn) {
      int col = n0 + wn * 32 + tn * 16 + l16;
      float bv = bias ? bias[col] : 0.f;
#pragma unroll
      for (int tm = 0; tm < TM; ++tm) {
#pragma unroll
        for (int r = 0; r < 4; ++r) {
          int row = m0 + wm * (TBM_ / 2) + tm * 16 + quad * 4 + r;
          if (row >= M) continue;
          float v = acc[tm][tn][r] + bv;
          if (ACT == 1) v = fmaxf(v, 0.f);
          C[(size_t)row * N + col] = v;
        }
      }
    }
  }
}

template <int TBM_, int ACT, int FUSE3>
__global__ __launch_bounds__(256) void mfma_gemm(
    const ushort* __restrict__ Ahg, const ushort* __restrict__ Alg,
    const ushort* __restrict__ Bhg, const ushort* __restrict__ Blg,
    int ldb, const float* __restrict__ bias, const float* __restrict__ W3g,
    float* __restrict__ C, int M, int N, int K) {
  __shared__ GemmSmem<TBM_> sm;
  gemm_body<TBM_, ACT, FUSE3>(sm, Ahg, Alg, Bhg, Blg, ldb, bias, W3g, C, M, N, K,
                              blockIdx.x, blockIdx.y);
}

// up-to-3-way segmented GEMM: flat grid, per-segment params, M-fast mapping
// (mb = t % mblk). Blocks are uniform per segment; bodies identical to the
// proven gemm_body; one shared-mem instance serves all 3 exclusive branches.
struct GArg {
  const ushort* Ah; const ushort* Al; const ushort* Bh; const ushort* Bl;
  const float* bias; float* C;
  int ldb; int M; int N; int K; int mblk;
};

template <int TBM_, int ACT>
__global__ __launch_bounds__(256) void mfma_gemm_seg3(
    GArg g0, GArg g1, GArg g2, int b1, int b2) {
  __shared__ GemmSmem<TBM_> sm;
  int bid = blockIdx.x;
  if (bid < b1) {
    gemm_body<TBM_, ACT, 0>(sm, g0.Ah, g0.Al, g0.Bh, g0.Bl, g0.ldb, g0.bias, nullptr,
                            g0.C, g0.M, g0.N, g0.K, bid % g0.mblk, bid / g0.mblk);
  } else if (bid < b2) {
    int t = bid - b1;
    gemm_body<TBM_, ACT, 0>(sm, g1.Ah, g1.Al, g1.Bh, g1.Bl, g1.ldb, g1.bias, nullptr,
                            g1.C, g1.M, g1.N, g1.K, t % g1.mblk, t / g1.mblk);
  } else {
    int t = bid - b2;
    gemm_body<TBM_, ACT, 0>(sm, g2.Ah, g2.Al, g2.Bh, g2.Bl, g2.ldb, g2.bias, nullptr,
                            g2.C, g2.M, g2.N, g2.K, t % g2.mblk, t / g2.mblk);
  }
}

template <int TBM_, int ACT>
static void gemm_launch(hipStream_t s,
                        const ushort* Ahg, const ushort* Alg,
                        const ushort* Bhg, const ushort* Blg,
                        int ldb, const float* bias, float* C,
                        int M, int N, int K) {
  dim3 g(cdiv(M, TBM_), N / TBN);   // M fast: XCD-local A-panel reuse
  mfma_gemm<TBM_, ACT, 0><<<g, 256, 0, s>>>(Ahg, Alg, Bhg, Blg, ldb, bias, nullptr, C, M, N, K);
}

static void gemm_launch_f3(hipStream_t s,
                           const ushort* Ahg, const ushort* Alg,
                           const ushort* Bhg, const ushort* Blg,
                           int ldb, const float* bias, const float* W3,
                           float* C, int M, int N, int K) {
  dim3 g(cdiv(M, 128), N / TBN);
  mfma_gemm<128, 1, 1><<<g, 256, 0, s>>>(Ahg, Alg, Bhg, Blg, ldb, bias, W3, C, M, N, K);
}

// ---------------------------------------------------------------- row dots + out32 zero
__global__ __launch_bounds__(256) void rowdot_dc_z_kernel(
    const float* __restrict__ Hd, const float* __restrict__ ad, float* __restrict__ od, int nd,
    const float* __restrict__ Hc, const float* __restrict__ ac, float* __restrict__ oc, int nc,
    float* __restrict__ z, int nz, int bs1, int bs2) {
  int b = blockIdx.x;
  if (b >= bs2) {                        // zero segment
    int i = (b - bs2) * 256 + threadIdx.x;
    if (i < nz) z[i] = 0.f;
    return;
  }
  const float* H; const float* a; float* o; int n; int row;
  if (b < bs1) { H = Hd; a = ad; o = od; n = nd; row = b * 4 + (threadIdx.x >> 6); }
  else         { H = Hc; a = ac; o = oc; n = nc; row = (b - bs1) * 4 + (threadIdx.x >> 6); }
  if (row >= n) return;
  int lane = threadIdx.x & 63;
  const float* h = H + (size_t)row * HDIM;
  float s = 0.f;
#pragma unroll
  for (int u = 0; u < 4; ++u) {
    int c = lane + u * 64;
    s += h[c] * a[c];
  }
#pragma unroll
  for (int off = 32; off; off >>= 1) s += __shfl_down(s, off);
  if (lane == 0) o[row] = s;
}

// ---------------------------------------------------------------- counting sort by dst
__global__ __launch_bounds__(256) void hist_kernel(
    const int* __restrict__ src, const int* __restrict__ dst, int E, int nloops,
    int Nd, int* __restrict__ offs) {
  extern __shared__ int bins[];
  int tot = E + nloops;
  int chunk = (tot + NB - 1) / NB;
  int b = blockIdx.x;
  int s0 = b * chunk, s1 = min(s0 + chunk, tot);
  for (int i = threadIdx.x; i < Nd; i += 256) bins[i] = 0;
  __syncthreads();
  for (int i = s0 + threadIdx.x; i < s1; i += 256) {
    int d = (i < E) ? dst[i] : (i - E);
    atomicAdd(&bins[d], 1);
  }
  __syncthreads();
  for (int i = threadIdx.x; i < Nd; i += 256) offs[(size_t)i * NB + b] = bins[i];
}

__global__ __launch_bounds__(256) void scan_bins_kernel(
    int* __restrict__ offs, int* __restrict__ binsum, int Nd) {
  int d = blockIdx.x * 4 + (threadIdx.x >> 6);
  if (d >= Nd) return;
  int lane = threadIdx.x & 63;
  int* p = offs + (size_t)d * NB;
  int v0 = p[2 * lane], v1 = p[2 * lane + 1];
  int s = v0 + v1;
  int t = s;
#pragma unroll
  for (int o = 1; o < 64; o <<= 1) { int u = __shfl_up(t, o); if (lane >= o) t += u; }
  int excl = t - s;
  p[2 * lane] = excl;
  p[2 * lane + 1] = excl + v0;
  if (lane == 63) binsum[d] = t;
}

__global__ __launch_bounds__(256) void scan_base_kernel(
    const int* __restrict__ binsum, int* __restrict__ rowptr, int Nd) {
  __shared__ int wsum[4];
  __shared__ int carry;
  if (threadIdx.x == 0) carry = 0;
  __syncthreads();
  int lane = threadIdx.x & 63, w = threadIdx.x >> 6;
  for (int t0 = 0; t0 < Nd; t0 += 256) {
    int i = t0 + threadIdx.x;
    int v = (i < Nd) ? binsum[i] : 0;
    int t = v;
#pragma unroll
    for (int o = 1; o < 64; o <<= 1) { int u = __shfl_up(t, o); if (lane >= o) t += u; }
    if (lane == 63) wsum[w] = t;
    __syncthreads();
    int add = carry;
    for (int k = 0; k < w; ++k) add += wsum[k];
    if (i < Nd) rowptr[i] = t - v + add;
    __syncthreads();
    if (threadIdx.x == 0) carry += wsum[0] + wsum[1] + wsum[2] + wsum[3];
    __syncthreads();
  }
  if (threadIdx.x == 0) rowptr[Nd] = carry;
}

__global__ __launch_bounds__(256) void scatter_kernel(
    const int* __restrict__ src, const int* __restrict__ dst, int E, int nloops,
    int Nd, const int* __restrict__ offs, const int* __restrict__ rowptr,
    uint* __restrict__ sd) {
  extern __shared__ int bins[];
  int tot = E + nloops;
  int chunk = (tot + NB - 1) / NB;
  int b = blockIdx.x;
  int s0 = b * chunk, s1 = min(s0 + chunk, tot);
  for (int i = threadIdx.x; i < Nd; i += 256) bins[i] = 0;
  __syncthreads();
  for (int i = s0 + threadIdx.x; i < s1; i += 256) {
    int s_, d_;
    if (i < E) { s_ = src[i]; d_ = dst[i]; }
    else       { s_ = d_ = i - E; }
    int local = atomicAdd(&bins[d_], 1);
    int pos = rowptr[d_] + offs[(size_t)d_ * NB + b] + local;
    sd[pos] = (uint)s_ | ((uint)d_ << 16);
  }
}

// ---------------------------------------------------------------- fused GAT edge phase
// pp aggregator: wave per dst, split-plane output (proven body)
__global__ __launch_bounds__(256) void gat_agg_split(
    const int* __restrict__ rowptr, const uint* __restrict__ sd,
    const float* __restrict__ als, const float* __restrict__ ald,
    const ushort* __restrict__ Xb,
    ushort* __restrict__ aggh, ushort* __restrict__ aggl, int n) {
  int d = blockIdx.x * 4 + (threadIdx.x >> 6);
  if (d >= n) return;
  int lane = threadIdx.x & 63;
  int r0 = rowptr[d], r1 = rowptr[d + 1];
  float aldd = ald[d];
  float dsum = 0.f;
  for (int j = r0 + lane; j < r1; j += 64) {
    float e = als[sd[j] & 0xffff] + aldd;
    e = (e > 0.f) ? e : NEG_SLOPE * e;
    dsum += __expf(e);
  }
#pragma unroll
  for (int o = 32; o; o >>= 1) dsum += __shfl_xor(dsum, o);
  float rden = 1.f / (dsum + 1e-16f);

  float4 acc = make_float4(0.f, 0.f, 0.f, 0.f);
  for (int b = r0; b < r1; b += 64) {
    int j = b + lane;
    float exv = 0.f; int srcv = 0;
    if (j < r1) {
      uint p = sd[j];
      srcv = p & 0xffff;
      float e = als[srcv] + aldd;
      e = (e > 0.f) ? e : NEG_SLOPE * e;
      exv = __expf(e) * rden;
    }
    int cnt = min(64, r1 - b);
    for (int t0 = 0; t0 < cnt; t0 += 8) {
      float cf[8]; int sv[8];
#pragma unroll
      for (int u = 0; u < 8; ++u) {
        cf[u] = __shfl(exv, t0 + u);
        sv[u] = __shfl(srcv, t0 + u);
      }
      ushort4 hv[8];
#pragma unroll
      for (int u = 0; u < 8; ++u)
        hv[u] = *(const ushort4*)(Xb + (size_t)sv[u] * HDIM + lane * 4);
#pragma unroll
      for (int u = 0; u < 8; ++u) {
        acc.x += cf[u] * b2f(hv[u].x);
        acc.y += cf[u] * b2f(hv[u].y);
        acc.z += cf[u] * b2f(hv[u].z);
        acc.w += cf[u] * b2f(hv[u].w);
      }
    }
  }
  uint p0 = f2pl(acc.x), p1 = f2pl(acc.y), p2 = f2pl(acc.z), p3 = f2pl(acc.w);
  ushort4 h = {(ushort)(p0 & 0xffff), (ushort)(p1 & 0xffff), (ushort)(p2 & 0xffff), (ushort)(p3 & 0xffff)};
  ushort4 l = {(ushort)(p0 >> 16), (ushort)(p1 >> 16), (ushort)(p2 >> 16), (ushort)(p3 >> 16)};
  *(ushort4*)(aggh + (size_t)d * HDIM + lane * 4) = h;
  *(ushort4*)(aggl + (size_t)d * HDIM + lane * 4) = l;
}

// dp aggregate + cp slice-aggregate in ONE launch (proven round-15 kernel)
__global__ __launch_bounds__(256) void agg_dp_cp_kernel(
    const int* __restrict__ rp_d, const uint* __restrict__ sd_d,
    const float* __restrict__ als_d, const float* __restrict__ ald_d,
    ushort* __restrict__ aggh, ushort* __restrict__ aggl, int nd, int bsplit,
    const int* __restrict__ rp_c, const uint* __restrict__ sd_c,
    const float* __restrict__ als_c, const float* __restrict__ ald_c,
    float* __restrict__ out32, int nc, const ushort* __restrict__ Xb) {
  __shared__ float wd[4];
  if (blockIdx.x < bsplit) {
    // ---- dp: gat_agg_split body
    int d = blockIdx.x * 4 + (threadIdx.x >> 6);
    if (d >= nd) return;
    int lane = threadIdx.x & 63;
    int r0 = rp_d[d], r1 = rp_d[d + 1];
    float aldd = ald_d[d];
    float dsum = 0.f;
    for (int j = r0 + lane; j < r1; j += 64) {
      float e = als_d[sd_d[j] & 0xffff] + aldd;
      e = (e > 0.f) ? e : NEG_SLOPE * e;
      dsum += __expf(e);
    }
#pragma unroll
    for (int o = 32; o; o >>= 1) dsum += __shfl_xor(dsum, o);
    float rden = 1.f / (dsum + 1e-16f);

    float4 acc = make_float4(0.f, 0.f, 0.f, 0.f);
    for (int b = r0; b < r1; b += 64) {
      int j = b + lane;
      float exv = 0.f; int srcv = 0;
      if (j < r1) {
        uint p = sd_d[j];
        srcv = p & 0xffff;
        float e = als_d[srcv] + aldd;
        e = (e > 0.f) ? e : NEG_SLOPE * e;
        exv = __expf(e) * rden;
      }
      int cnt = min(64, r1 - b);
      for (int t0 = 0; t0 < cnt; t0 += 8) {
        float cf[8]; int sv[8];
#pragma unroll
        for (int u = 0; u < 8; ++u) {
          cf[u] = __shfl(exv, t0 + u);
          sv[u] = __shfl(srcv, t0 + u);
        }
        ushort4 hv[8];
#pragma unroll
        for (int u = 0; u < 8; ++u)
          hv[u] = *(const ushort4*)(Xb + (size_t)sv[u] * HDIM + lane * 4);
#pragma unroll
        for (int u = 0; u < 8; ++u) {
          acc.x += cf[u] * b2f(hv[u].x);
          acc.y += cf[u] * b2f(hv[u].y);
          acc.z += cf[u] * b2f(hv[u].z);
          acc.w += cf[u] * b2f(hv[u].w);
        }
      }
    }
    uint p0 = f2pl(acc.x), p1 = f2pl(acc.y), p2 = f2pl(acc.z), p3 = f2pl(acc.w);
    ushort4 h = {(ushort)(p0 & 0xffff), (ushort)(p1 & 0xffff), (ushort)(p2 & 0xffff), (ushort)(p3 & 0xffff)};
    ushort4 l = {(ushort)(p0 >> 16), (ushort)(p1 >> 16), (ushort)(p2 >> 16), (ushort)(p3 >> 16)};
    *(ushort4*)(aggh + (size_t)d * HDIM + lane * 4) = h;
    *(ushort4*)(aggl + (size_t)d * HDIM + lane * 4) = l;
  } else {
    // ---- cp: gat_agg_slice body (atomicAdd partials into pre-zeroed out32)
    int bb = blockIdx.x - bsplit;
    int d = bb / SLICES;
    int sl = bb - d * SLICES;
    if (d >= nc) return;
    int lane = threadIdx.x & 63, w = threadIdx.x >> 6;
    int r0 = rp_c[d], r1 = rp_c[d + 1];
    float aldd = ald_c[d];
    float dsum = 0.f;
    for (int j = r0 + threadIdx.x; j < r1; j += 256) {
      float e = als_c[sd_c[j] & 0xffff] + aldd;
      e = (e > 0.f) ? e : NEG_SLOPE * e;
      dsum += __expf(e);
    }
#pragma unroll
    for (int o = 32; o; o >>= 1) dsum += __shfl_xor(dsum, o);
    if (lane == 0) wd[w] = dsum;
    __syncthreads();
    float rden = 1.f / (wd[0] + wd[1] + wd[2] + wd[3] + 1e-16f);
    int deg = r1 - r0;
    int per_b = (deg + SLICES - 1) / SLICES;
    int b0 = r0 + sl * per_b, b1 = min(b0 + per_b, r1);
    int wdeg = b1 - b0;
    if (wdeg <= 0) return;
    int per_w = (wdeg + 3) >> 2;
    int w0 = b0 + w * per_w, w1 = min(w0 + per_w, b1);

    float4 acc = make_float4(0.f, 0.f, 0.f, 0.f);
    for (int b = w0; b < w1; b += 64) {
      int j = b + lane;
      float exv = 0.f; int srcv = 0;
      if (j < w1) {
        uint p = sd_c[j];
        srcv = p & 0xffff;
        float e = als_c[srcv] + aldd;
        e = (e > 0.f) ? e : NEG_SLOPE * e;
        exv = __expf(e) * rden;
      }
      int cnt = min(64, w1 - b);
      for (int t0 = 0; t0 < cnt; t0 += 8) {
        float cf[8]; int sv[8];
#pragma unroll
        for (int u = 0; u < 8; ++u) {
          cf[u] = __shfl(exv, t0 + u);
          sv[u] = __shfl(srcv, t0 + u);
        }
        ushort4 hv[8];
#pragma unroll
        for (int u = 0; u < 8; ++u)
          hv[u] = *(const ushort4*)(Xb + (size_t)sv[u] * HDIM + lane * 4);
#pragma unroll
        for (int u = 0; u < 8; ++u) {
          acc.x += cf[u] * b2f(hv[u].x);
          acc.y += cf[u] * b2f(hv[u].y);
          acc.z += cf[u] * b2f(hv[u].z);
          acc.w += cf[u] * b2f(hv[u].w);
        }
      }
    }
    float* o = out32 + (size_t)d * HDIM + lane * 4;
    atomicAdd(o + 0, acc.x); atomicAdd(o + 1, acc.y);
    atomicAdd(o + 2, acc.z); atomicAdd(o + 3, acc.w);
  }
}

// ---------------------------------------------------------------- norms
__global__ __launch_bounds__(256) void l2norm_f32b_dots_kernel(
    const float* __restrict__ in, float* __restrict__ outf, ushort* __restrict__ outb,
    const float* __restrict__ v1, const float* __restrict__ v2,
    const float* __restrict__ v3, const float* __restrict__ v4,
    float* __restrict__ o1, float* __restrict__ o2,
    float* __restrict__ o3, float* __restrict__ o4, int n) {
  int row = blockIdx.x * 4 + (threadIdx.x >> 6);
  if (row >= n) return;
  int lane = threadIdx.x & 63;
  float v[4];
  float ss = 0.f;
#pragma unroll
  for (int u = 0; u < 4; ++u) {
    float t = in[(size_t)row * HDIM + lane + u * 64];
    v[u] = t; ss += t * t;
  }
#pragma unroll
  for (int off = 32; off; off >>= 1) ss += __shfl_xor(ss, off);
  float sc = 1.0f / fmaxf(sqrtf(ss), 1e-12f);
  float d1 = 0.f, d2 = 0.f, d3 = 0.f, d4 = 0.f;
#pragma unroll
  for (int u = 0; u < 4; ++u) {
    float f = v[u] * sc;
    int c = lane + u * 64;
    outf[(size_t)row * HDIM + c] = f;
    outb[(size_t)row * HDIM + c] = f2b(f);
    d1 += f * v1[c];
    d2 += f * v2[c];
    if (o3) { d3 += f * v3[c]; d4 += f * v4[c]; }
  }
#pragma unroll
  for (int off = 32; off; off >>= 1) {
    d1 += __shfl_xor(d1, off);
    d2 += __shfl_xor(d2, off);
    if (o3) { d3 += __shfl_xor(d3, off); d4 += __shfl_xor(d4, off); }
  }
  if (lane == 0) {
    o1[row] = d1; o2[row] = d2;
    if (o3) { o3[row] = d3; o4[row] = d4; }
  }
}

// fp32 in -> l2norm -> split hi/lo out; drug + cell tables in ONE launch
__global__ __launch_bounds__(256) void l2norm_split_dc_kernel(
    const float* __restrict__ Xd, ushort* __restrict__ dh, ushort* __restrict__ dl, int nd,
    const float* __restrict__ Xc, ushort* __restrict__ ch, ushort* __restrict__ cl, int nc,
    int bsplit) {
  int b = blockIdx.x;
  const float* in; ushort* oh; ushort* ol; int n; int row;
  if (b < bsplit) { in = Xd; oh = dh; ol = dl; n = nd; row = b * 4 + (threadIdx.x >> 6); }
  else            { in = Xc; oh = ch; ol = cl; n = nc; row = (b - bsplit) * 4 + (threadIdx.x >> 6); }
  if (row >= n) return;
  int lane = threadIdx.x & 63;
  float v[4];
  float ss = 0.f;
#pragma unroll
  for (int u = 0; u < 4; ++u) {
    int c = lane + u * 64;
    float t = in[(size_t)row * HDIM + c];
    v[u] = t;
    ss += t * t;
  }
#pragma unroll
  for (int off = 32; off; off >>= 1) ss += __shfl_xor(ss, off);
  float sc = 1.0f / fmaxf(sqrtf(ss), 1e-12f);
#pragma unroll
  for (int u = 0; u < 4; ++u) {
    int c = lane + u * 64;
    uint p = f2pl(v[u] * sc);
    oh[(size_t)row * HDIM + c] = (ushort)(p & 0xffff);
    ol[(size_t)row * HDIM + c] = (ushort)(p >> 16);
  }
}

// ---------------------------------------------------------------- host side
static void build_sorted(hipStream_t stream,
                         const int* src, const int* dst, int E, int nloops, int Nd,
                         int* offs, int* binsum, int* rowptr, uint* sd) {
  size_t lds = (size_t)Nd * sizeof(int);
  hist_kernel<<<NB, 256, lds, stream>>>(src, dst, E, nloops, Nd, offs);
  scan_bins_kernel<<<cdiv(Nd, 4), 256, 0, stream>>>(offs, binsum, Nd);
  scan_base_kernel<<<1, 256, 0, stream>>>(binsum, rowptr, Nd);
  scatter_kernel<<<NB, 256, lds, stream>>>(src, dst, E, nloops, Nd, offs, rowptr, sd);
}

extern "C" void kernel_launch(void* const* d_in, const int* in_sizes, int n_in,
                              void* d_out, int out_size, void* d_ws, size_t ws_size,
                              hipStream_t stream) {
  const float* drug_emb = (const float*)d_in[0];
  const float* prot_emb = (const float*)d_in[1];
  const float* cell_emb = (const float*)d_in[2];
  const float* W_pp = (const float*)d_in[3];
  const float* as_pp = (const float*)d_in[4];
  const float* ad_pp = (const float*)d_in[5];
  const float* b_pp = (const float*)d_in[6];
  const float* W_dp = (const float*)d_in[7];
  const float* as_dp = (const float*)d_in[8];
  const float* ad_dp = (const float*)d_in[9];
  const float* b_dp = (const float*)d_in[10];
  const float* W_cp = (const float*)d_in[11];
  const float* as_cp = (const float*)d_in[12];
  const float* ad_cp = (const float*)d_in[13];
  const float* b_cp = (const float*)d_in[14];
  const float* W1 = (const float*)d_in[15];
  const float* b1 = (const float*)d_in[16];
  const float* W2 = (const float*)d_in[17];
  const float* b2 = (const float*)d_in[18];
  const float* W3 = (const float*)d_in[19];
  const float* b3 = (const float*)d_in[20];
  const int* edge_pp = (const int*)d_in[21];
  const int* edge_dp = (const int*)d_in[22];
  const int* edge_cp = (const int*)d_in[23];
  const int* drug1 = (const int*)d_in[24];
  const int* drug2 = (const int*)d_in[25];
  const int* cellb = (const int*)d_in[26];

  const int ND = in_sizes[0] / HDIM;   // 2000
  const int NP = in_sizes[1] / HDIM;   // 19000
  const int NC = in_sizes[2] / HDIM;   // 100
  const int L = in_sizes[3] / (HDIM * HDIM);  // 2
  const int E_pp = in_sizes[21] / 2;
  const int E_dp = in_sizes[22] / 2;
  const int E_cp = in_sizes[23] / 2;
  const int B = in_sizes[24];          // 8192
  (void)n_in; (void)out_size;

  const int* src_pp = edge_pp;          const int* dst_pp = edge_pp + E_pp;
  const int* src_dp = edge_dp;          const int* dst_dp = edge_dp + E_dp;
  const int* src_cp = edge_cp;          const int* dst_cp = edge_cp + E_cp;
  const int tot_pp = E_pp + NP, tot_dp = E_dp, tot_cp = E_cp;
  int maxN = NP > ND ? NP : ND; if (NC > maxN) maxN = NC;

  // ---------------- workspace
  char* wsb = (char*)d_ws;
  size_t off = 0;
  auto alloc = [&](size_t bytes) -> void* {
    void* p = wsb + off;
    off += (bytes + 255) & ~(size_t)255;
    return p;
  };

  float* Xp  = (float*)alloc((size_t)NP * HDIM * 4);    // protein state fp32
  ushort* Xpb = (ushort*)alloc((size_t)NP * HDIM * 2);  // protein state bf16 (gather)
  float* Xd  = (float*)alloc((size_t)ND * HDIM * 4);
  float* Xc  = (float*)alloc((size_t)NC * HDIM * 4);
  ushort* xdnh = (ushort*)alloc((size_t)ND * HDIM * 2);
  ushort* xdnl = (ushort*)alloc((size_t)ND * HDIM * 2);
  ushort* xcnh = (ushort*)alloc((size_t)NC * HDIM * 2);
  ushort* xcnl = (ushort*)alloc((size_t)NC * HDIM * 2);
  ushort* WTpph = (ushort*)alloc((size_t)L * HDIM * HDIM * 2);
  ushort* WTppl = (ushort*)alloc((size_t)L * HDIM * HDIM * 2);
  ushort* WTdph = (ushort*)alloc((size_t)L * HDIM * HDIM * 2);
  ushort* WTdpl = (ushort*)alloc((size_t)L * HDIM * HDIM * 2);
  ushort* WTcph = (ushort*)alloc((size_t)L * HDIM * HDIM * 2);
  ushort* WTcpl = (ushort*)alloc((size_t)L * HDIM * HDIM * 2);
  ushort* cth = (ushort*)alloc((size_t)NC * HDIM * 2);  // cp split staging
  ushort* ctl = (ushort*)alloc((size_t)NC * HDIM * 2);
  float* wv  = (float*)alloc((size_t)L * 6 * HDIM * 4); // folded W@a vectors
  float* pals = (float*)alloc((size_t)maxN * 4);        // pp src logits
  float* pald = (float*)alloc((size_t)maxN * 4);        // pp dst logits
  float* als1 = (float*)alloc((size_t)maxN * 4);        // dp src logits
  float* als2 = (float*)alloc((size_t)maxN * 4);        // cp src logits
  float* ald1 = (float*)alloc((size_t)maxN * 4);
  float* ald2 = (float*)alloc((size_t)maxN * 4);
  int* binsum = (int*)alloc((size_t)maxN * 4);
  int* rp_pp = (int*)alloc((size_t)(NP + 1) * 4);
  int* rp_dp = (int*)alloc((size_t)(ND + 1) * 4);
  int* rp_cp = (int*)alloc((size_t)(NC + 1) * 4);
  uint* sd_pp = (uint*)alloc((size_t)tot_pp * 4);
  uint* sd_dp = (uint*)alloc((size_t)tot_dp * 4);
  uint* sd_cp = (uint*)alloc((size_t)tot_cp * 4);
  float* out32 = (float*)alloc((size_t)NC * HDIM * 4);  // cp partial accumulator
  size_t S0 = off;

  // scratch S overlays: [offs] -> [aggh|aggl|tmp] -> [W1T*|W2T*|P1|P2|P3|h1*]
  int* offs = (int*)(wsb + S0);
  build_sorted(stream, src_pp, dst_pp, E_pp, NP, NP, offs, binsum, rp_pp, sd_pp);
  build_sorted(stream, src_dp, dst_dp, E_dp, 0, ND, offs, binsum, rp_dp, sd_dp);
  build_sorted(stream, src_cp, dst_cp, E_cp, 0, NC, offs, binsum, rp_cp, sd_cp);

  // ---- weight split planes (batched) + folded attention vectors + protein prep
  wconv_split3_kernel<<<cdiv(3 * L * HDIM * HDIM, 256), 256, 0, stream>>>(
      W_pp, W_dp, W_cp, WTpph, WTppl, WTdph, WTdpl, WTcph, WTcpl, L);
  matvec_all_kernel<<<L * 6, 256, 0, stream>>>(W_pp, as_pp, ad_pp, W_dp, as_dp, ad_dp,
                                               W_cp, as_cp, ad_cp, wv);
  // layer-0: Xpb bf16 copy + pp logits in one pass over prot_emb
  prep_p_kernel<<<cdiv(NP, 4), 256, 0, stream>>>(prot_emb, Xpb, wv + 0 * HDIM, wv + 1 * HDIM,
                                                 pals, pald, NP);

  size_t aggB = ((size_t)NP * HDIM * 2 + 255) & ~(size_t)255;
  ushort* aggh = (ushort*)(wsb + S0);
  ushort* aggl = (ushort*)(wsb + S0 + aggB);
  float* tmp = (float*)(wsb + S0 + 2 * aggB);

  for (int l = 0; l < L; ++l) {
    const int WOFF = l * HDIM * HDIM, VOFF = l * HDIM;
    const float* wvl = wv + (size_t)l * 6 * HDIM;
    bool last = (l == L - 1);
    const float* wvn = last ? wvl : wv + (size_t)(l + 1) * 6 * HDIM;
    const float* Xd_cur = (l == 0) ? drug_emb : Xd;
    const float* Xc_cur = (l == 0) ? cell_emb : Xc;

    // ---- p-p: aggregate x -> transform -> l2norm (+fused dots for dp/cp/next-pp)
    gat_agg_split<<<cdiv(NP, 4), 256, 0, stream>>>(rp_pp, sd_pp, pals, pald, Xpb, aggh, aggl, NP);
    gemm_launch<128, 0>(stream, aggh, aggl, WTpph + WOFF, WTppl + WOFF, HDIM,
                        b_pp + VOFF, tmp, NP, HDIM, HDIM);
    l2norm_f32b_dots_kernel<<<cdiv(NP, 4), 256, 0, stream>>>(
        tmp, Xp, Xpb,
        wvl + 2 * HDIM, wvl + 4 * HDIM,
        last ? nullptr : (wvn + 0 * HDIM), last ? nullptr : (wvn + 1 * HDIM),
        als1, als2, last ? nullptr : pals, last ? nullptr : pald, NP);

    // dp rowdot + cp rowdot + out32 zeroing, one launch
    {
      int bs1 = cdiv(ND, 4), bs2 = bs1 + cdiv(NC, 4);
      int nz = NC * HDIM;
      rowdot_dc_z_kernel<<<bs2 + cdiv(nz, 256), 256, 0, stream>>>(
          Xd_cur, wvl + 3 * HDIM, ald1, ND,
          Xc_cur, wvl + 5 * HDIM, ald2, NC,
          out32, nz, bs1, bs2);
    }

    // ---- dp aggregate + cp slice-aggregate, one launch (independent phases)
    {
      int bsplit = cdiv(ND, 4);
      agg_dp_cp_kernel<<<bsplit + NC * SLICES, 256, 0, stream>>>(
          rp_dp, sd_dp, als1, ald1, aggh, aggl, ND, bsplit,
          rp_cp, sd_cp, als2, ald2, out32, NC, Xpb);
    }

    // ---- cp split (tiny), then dp-GEMM + cp-GEMM in ONE segmented launch
    f32_to_split_kernel<<<cdiv(NC * HDIM, 256), 256, 0, stream>>>(out32, cth, ctl, NC * HDIM);
    {
      int mbd = cdiv(ND, 64), mbc = cdiv(NC, 64);
      int bd = mbd * (HDIM / TBN);          // dp blocks (M fast)
      int bc = mbc * (HDIM / TBN);          // cp blocks
      GArg gd{aggh, aggl, WTdph + WOFF, WTdpl + WOFF, b_dp + VOFF, Xd,
              HDIM, ND, HDIM, HDIM, mbd};
      GArg gc{cth, ctl, WTcph + WOFF, WTcpl + WOFF, b_cp + VOFF, Xc,
              HDIM, NC, HDIM, HDIM, mbc};
      mfma_gemm_seg3<64, 1><<<bd + bc, 256, 0, stream>>>(gd, gc, gc, bd, bd + bc);
    }
  }

  // ---------------- head
  l2norm_split_dc_kernel<<<cdiv(ND, 4) + cdiv(NC, 4), 256, 0, stream>>>(
      Xd, xdnh, xdnl, ND, Xc, xcnh, xcnl, NC, cdiv(ND, 4));

  const int N1 = 6 * HDIM;   // 1536
  const int N2 = 2 * HDIM;   // 512
  const int K1 = 3 * HDIM;   // 768
  ushort* W1Th = (ushort*)(wsb + S0);                   // [1536][768]
  ushort* W1Tl = W1Th + (size_t)N1 * K1;
  ushort* W2Th = W1Tl + (size_t)N1 * K1;                // [512][1536]
  ushort* W2Tl = W2Th + (size_t)N2 * N1;
  float* P1 = (float*)(W2Tl + (size_t)N2 * N1);         // [ND][1536]
  float* P2 = P1 + (size_t)ND * N1;
  float* P3 = P2 + (size_t)ND * N1;                     // [NC][1536]
  ushort* h1h = (ushort*)(P3 + (size_t)NC * N1);        // [CH][1536] split
  size_t wsz = ws_size ? ws_size : ((size_t)1 << 30);
  size_t fixed = S0 + ((size_t)N1 * K1 + (size_t)N2 * N1) * 4
               + ((size_t)(2 * ND + NC) * N1) * 4;
  int CH = 8192;
  while (CH > 1024 && fixed + (size_t)CH * N1 * 4 > wsz) CH >>= 1;
  ushort* h1l = h1h + (size_t)CH * N1;

  wconv_split_kernel<<<cdiv(K1 * N1, 256), 256, 0, stream>>>(W1, W1Th, W1Tl, K1, N1);
  wconv_split_kernel<<<cdiv(N1 * N2, 256), 256, 0, stream>>>(W2, W2Th, W2Tl, N1, N2);

  // P1 + P2 + P3 GEMMs in ONE segmented launch (independent outputs)
  {
    int mbd = cdiv(ND, 64), mbc = cdiv(NC, 64);
    int q1 = mbd * (N1 / TBN);            // 32*24 = 768
    int q3 = mbc * (N1 / TBN);            // 2*24 = 48
    GArg p1a{xdnh, xdnl, W1Th, W1Tl, nullptr, P1, K1, ND, N1, HDIM, mbd};
    GArg p2a{xdnh, xdnl, W1Th + HDIM, W1Tl + HDIM, nullptr, P2, K1, ND, N1, HDIM, mbd};
    GArg p3a{xcnh, xcnl, W1Th + 2 * HDIM, W1Tl + 2 * HDIM, b1, P3, K1, NC, N1, HDIM, mbc};
    mfma_gemm_seg3<64, 0><<<q1 + q1 + q3, 256, 0, stream>>>(p1a, p2a, p3a, q1, 2 * q1);
  }

  float* outp = (float*)d_out;
  fill_out2_kernel<<<cdiv(B, 256), 256, 0, stream>>>(outp, b3, B);
  for (int c0 = 0; c0 < B; c0 += CH) {
    int M = (B - c0) < CH ? (B - c0) : CH;
    combine_h1_kernel<<<cdiv(M * (N1 / 4), 256), 256, 0, stream>>>(
        P1, P2, P3, drug1, drug2, cellb, c0, h1h, h1l, M, N1);
    gemm_launch_f3(stream, h1h, h1l, W2Th, W2Tl, N1, b2, W3,
                   outp + (size_t)c0 * 2, M, N2, N1);
  }
}

// Round 17
// 648.087 us; speedup vs baseline: 1.1411x; 1.0079x over previous
//
#include <hip/hip_runtime.h>
#include <hip/hip_bf16.h>

#define HDIM 256
#define NEG_SLOPE 0.2f
#define NB 128          // blocks for hist/scatter
#define SLICES 8        // edge slices per dst in the big-degree aggregator
#define TBN 64
#define TBK 32

typedef __attribute__((ext_vector_type(8))) short bf16x8;
typedef __attribute__((ext_vector_type(4))) float f32x4;

// split-bf16: x ~= bf16(hi) + bf16(lo); stored as two separate ushort arrays
__device__ inline uint f2pl(float x) {
  __hip_bfloat16 h = __float2bfloat16(x);
  ushort hi = *(ushort*)&h;
  float r = x - __bfloat162float(h);
  __hip_bfloat16 l = __float2bfloat16(r);
  ushort lo = *(ushort*)&l;
  return (uint)hi | ((uint)lo << 16);
}
__device__ inline ushort f2b(float x) {
  __hip_bfloat16 h = __float2bfloat16(x);
  return *(ushort*)&h;
}
__device__ inline float b2f(ushort u) {
  uint x = ((uint)u) << 16;
  return __int_as_float((int)x);
}

static inline int cdiv(int a, int b) { return (a + b - 1) / b; }

// ---------------------------------------------------------------- utilities
// batched layer-weight conversion: all 3 edge types x L layers in one launch
__global__ void wconv_split3_kernel(
    const float* __restrict__ Wpp, const float* __restrict__ Wdp, const float* __restrict__ Wcp,
    ushort* __restrict__ WTpph, ushort* __restrict__ WTppl,
    ushort* __restrict__ WTdph, ushort* __restrict__ WTdpl,
    ushort* __restrict__ WTcph, ushort* __restrict__ WTcpl, int L) {
  const int per = HDIM * HDIM;
  int i = blockIdx.x * 256 + threadIdx.x;
  if (i >= 3 * L * per) return;
  int mat = i / per;
  int r = i - mat * per;
  int l = mat / 3, ty = mat - l * 3;
  const float* W = (ty == 0 ? Wpp : ty == 1 ? Wdp : Wcp) + (size_t)l * per;
  ushort* Th = (ty == 0 ? WTpph : ty == 1 ? WTdph : WTcph) + (size_t)l * per;
  ushort* Tl = (ty == 0 ? WTppl : ty == 1 ? WTdpl : WTcpl) + (size_t)l * per;
  int k = r >> 8, n = r & (HDIM - 1);    // r = k*HDIM + n
  uint p = f2pl(W[r]);
  Th[(size_t)n * HDIM + k] = (ushort)(p & 0xffff);
  Tl[(size_t)n * HDIM + k] = (ushort)(p >> 16);
}

__global__ void f32_to_split_kernel(const float* __restrict__ in,
                                    ushort* __restrict__ oh, ushort* __restrict__ ol, int n) {
  int i = blockIdx.x * 256 + threadIdx.x;
  if (i >= n) return;
  uint p = f2pl(in[i]);
  oh[i] = (ushort)(p & 0xffff);
  ol[i] = (ushort)(p >> 16);
}

// wv[b][k] = sum_n W[k][n]*a[n]  (the folded attention vector W @ a)
__global__ __launch_bounds__(256) void matvec_all_kernel(
    const float* __restrict__ Wpp, const float* __restrict__ aspp, const float* __restrict__ adpp,
    const float* __restrict__ Wdp, const float* __restrict__ asdp, const float* __restrict__ addp,
    const float* __restrict__ Wcp, const float* __restrict__ ascp, const float* __restrict__ adcp,
    float* __restrict__ wv) {
  int b = blockIdx.x;
  int l = b / 6, r = b - l * 6, type = r >> 1, isd = r & 1;
  const float* W = (type == 0 ? Wpp : type == 1 ? Wdp : Wcp) + (size_t)l * HDIM * HDIM;
  const float* a = (type == 0 ? (isd ? adpp : aspp)
                  : type == 1 ? (isd ? addp : asdp)
                              : (isd ? adcp : ascp)) + (size_t)l * HDIM;
  int k = threadIdx.x;
  const float4* Wr = (const float4*)(W + (size_t)k * HDIM);
  float s = 0.f;
#pragma unroll 8
  for (int n4 = 0; n4 < HDIM / 4; ++n4) {
    float4 w = Wr[n4];
    float4 av = *(const float4*)(a + n4 * 4);
    s += w.x * av.x + w.y * av.y + w.z * av.z + w.w * av.w;
  }
  wv[(size_t)b * HDIM + k] = s;
}

// layer-0 protein prep: bf16 copy of prot_emb + the two pp rowdots, one pass
__global__ __launch_bounds__(256) void prep_p_kernel(
    const float* __restrict__ in, ushort* __restrict__ outb,
    const float* __restrict__ a1, const float* __restrict__ a2,
    float* __restrict__ o1, float* __restrict__ o2, int n) {
  int row = blockIdx.x * 4 + (threadIdx.x >> 6);
  if (row >= n) return;
  int lane = threadIdx.x & 63;
  float s1 = 0.f, s2 = 0.f;
#pragma unroll
  for (int u = 0; u < 4; ++u) {
    int c = lane + u * 64;
    float hv = in[(size_t)row * HDIM + c];
    outb[(size_t)row * HDIM + c] = f2b(hv);
    s1 += hv * a1[c];
    s2 += hv * a2[c];
  }
#pragma unroll
  for (int off = 32; off; off >>= 1) {
    s1 += __shfl_down(s1, off);
    s2 += __shfl_down(s2, off);
  }
  if (lane == 0) { o1[row] = s1; o2[row] = s2; }
}

// h1 combine -> split planes (P3 carries bias b1), PLUS optional b3-prefill
// segment for the logits buffer (independent of combine; both precede W2).
__global__ __launch_bounds__(256) void combine_h1_fill_kernel(
    const float* __restrict__ P1, const float* __restrict__ P2, const float* __restrict__ P3,
    const int* __restrict__ g1, const int* __restrict__ g2, const int* __restrict__ g3,
    int row0, ushort* __restrict__ h1h, ushort* __restrict__ h1l, int M, int K,
    float* __restrict__ outp, const float* __restrict__ b3, int Bn, int bsC) {
  if (blockIdx.x >= bsC) {               // fill segment
    int i = (blockIdx.x - bsC) * 256 + threadIdx.x;
    if (i < Bn) {
      outp[(size_t)i * 2 + 0] = b3[0];
      outp[(size_t)i * 2 + 1] = b3[1];
    }
    return;
  }
  int t = blockIdx.x * 256 + threadIdx.x;
  int kq = K >> 2;
  if (t >= M * kq) return;
  int row = t / kq, c4 = t - row * kq;
  int bi = row0 + row;
  size_t o = (size_t)c4 * 4;
  float4 a = *(const float4*)(P1 + (size_t)g1[bi] * K + o);
  float4 b = *(const float4*)(P2 + (size_t)g2[bi] * K + o);
  float4 c = *(const float4*)(P3 + (size_t)g3[bi] * K + o);
  uint p0 = f2pl(fmaxf(a.x + b.x + c.x, 0.f));
  uint p1 = f2pl(fmaxf(a.y + b.y + c.y, 0.f));
  uint p2 = f2pl(fmaxf(a.z + b.z + c.z, 0.f));
  uint p3 = f2pl(fmaxf(a.w + b.w + c.w, 0.f));
  ushort4 h = {(ushort)(p0 & 0xffff), (ushort)(p1 & 0xffff), (ushort)(p2 & 0xffff), (ushort)(p3 & 0xffff)};
  ushort4 l = {(ushort)(p0 >> 16), (ushort)(p1 >> 16), (ushort)(p2 >> 16), (ushort)(p3 >> 16)};
  *(ushort4*)(h1h + (size_t)row * K + o) = h;
  *(ushort4*)(h1l + (size_t)row * K + o) = l;
}

// ---------------------------------------------------------------- MFMA GEMM
// C = act(A@B + bias), fp32 out. A,B pre-split hi/lo ushort arrays.
// ROUND-10 PROVEN STRUCTURE (best known; all structural neighbors regressed).
// Body refactored VERBATIM into a device function taking (mb, nb) + a shared
// struct reference so it can be driven either by a 2D grid (standalone) or
// by a flat segmented grid (merged small GEMMs). M-fast ordering preserved.
// LDS layout: granule-major WITH slot rotation; 2-deep register pipeline;
// one barrier per k-step. FUSE3: head3 fused epilogue (atomicAdd logits).
template <int TBM_>
struct GemmSmem {
  ushort Ah[2][4][TBM_ / 16][16][8];
  ushort Al[2][4][TBM_ / 16][16][8];
  ushort Bh[2][4][TBN / 16][16][8];
  ushort Bl[2][4][TBN / 16][16][8];
};

template <int TBM_, int ACT, int FUSE3>
__device__ __forceinline__ void gemm_body(
    GemmSmem<TBM_>& sm,
    const ushort* __restrict__ Ahg, const ushort* __restrict__ Alg,
    const ushort* __restrict__ Bhg, const ushort* __restrict__ Blg,
    int ldb, const float* __restrict__ bias, const float* __restrict__ W3g,
    float* __restrict__ C, int M, int N, int K, int mb, int nb) {
  constexpr int NU = TBM_ / 64;   // A 16B-load instrs per thread (64 rows/round)
  constexpr int TM = TBM_ / 32;   // 16-row tiles per wave (M dir)

  const int tid = threadIdx.x;
  const int lane = tid & 63;
  const int wid = tid >> 6;
  const int wm = wid & 1, wn = wid >> 1;
  const int l16 = lane & 15;
  const int quad = lane >> 4;
  const int m0 = mb * TBM_;
  const int n0 = nb * TBN;

  const int gq = lane & 3;         // k-granule (8 ushorts = 16B) this lane stages
  const int co = gq * 8;           // ushort col within 32-ushort k-chunk
  const int r4 = lane >> 2;        // row within 16-row stripe
  const int wslot = (r4 + 2 * gq) & 15;          // rotated write slot
  const int rslot = (l16 + 2 * quad) & 15;       // rotated read slot

  uint4 rah0[NU], ral0[NU], rbh0, rbl0;   // register set 0
  uint4 rah1[NU], ral1[NU], rbh1, rbl1;   // register set 1

  auto LOADA = [&](uint4* rah, uint4* ral, uint4& rbh, uint4& rbl, int k0) {
#pragma unroll
    for (int u = 0; u < NU; ++u) {
      int r = wid * (TBM_ / 4) + r4 + 16 * u;
      int gm = m0 + r;
      if (gm < M) {
        size_t o = (size_t)gm * K + k0 + co;
        rah[u] = *(const uint4*)(Ahg + o);
        ral[u] = *(const uint4*)(Alg + o);
      } else {
        rah[u] = make_uint4(0, 0, 0, 0);
        ral[u] = make_uint4(0, 0, 0, 0);
      }
    }
    {
      int r = wid * 16 + r4;
      size_t o = (size_t)(n0 + r) * ldb + k0 + co;
      rbh = *(const uint4*)(Bhg + o);
      rbl = *(const uint4*)(Blg + o);
    }
  };
  auto STORE = [&](const uint4* rah, const uint4* ral, const uint4& rbh, const uint4& rbl, int b) {
#pragma unroll
    for (int u = 0; u < NU; ++u) {
      int ch = (wid * (TBM_ / 4) + 16 * u) >> 4;   // row chunk (r4 < 16)
      *(uint4*)&sm.Ah[b][gq][ch][wslot][0] = rah[u];
      *(uint4*)&sm.Al[b][gq][ch][wslot][0] = ral[u];
    }
    *(uint4*)&sm.Bh[b][gq][wid][wslot][0] = rbh;
    *(uint4*)&sm.Bl[b][gq][wid][wslot][0] = rbl;
  };

  f32x4 acc[TM][2];
#pragma unroll
  for (int i = 0; i < TM; ++i)
#pragma unroll
    for (int j = 0; j < 2; ++j) acc[i][j] = (f32x4){0.f, 0.f, 0.f, 0.f};

  auto COMPUTE = [&](int b) {
    bf16x8 ahf[TM], alf[TM], bhf[2], blf[2];
#pragma unroll
    for (int t = 0; t < TM; ++t) {
      int ch = wm * (TBM_ / 32) + t;
      ahf[t] = *(const bf16x8*)&sm.Ah[b][quad][ch][rslot][0];
      alf[t] = *(const bf16x8*)&sm.Al[b][quad][ch][rslot][0];
    }
#pragma unroll
    for (int t = 0; t < 2; ++t) {
      int ch = wn * 2 + t;
      bhf[t] = *(const bf16x8*)&sm.Bh[b][quad][ch][rslot][0];
      blf[t] = *(const bf16x8*)&sm.Bl[b][quad][ch][rslot][0];
    }
#pragma unroll
    for (int tm = 0; tm < TM; ++tm)
#pragma unroll
      for (int tn = 0; tn < 2; ++tn) {
        acc[tm][tn] = __builtin_amdgcn_mfma_f32_16x16x32_bf16(ahf[tm], bhf[tn], acc[tm][tn], 0, 0, 0);
        acc[tm][tn] = __builtin_amdgcn_mfma_f32_16x16x32_bf16(ahf[tm], blf[tn], acc[tm][tn], 0, 0, 0);
        acc[tm][tn] = __builtin_amdgcn_mfma_f32_16x16x32_bf16(alf[tm], bhf[tn], acc[tm][tn], 0, 0, 0);
      }
  };

  // prologue: tiles t0,t1 in regs; t0 -> buf0
  const int NK = K / TBK;            // even, >= 4 for all shapes used
  LOADA(rah0, ral0, rbh0, rbl0, 0);
  LOADA(rah1, ral1, rbh1, rbl1, TBK);
  STORE(rah0, ral0, rbh0, rbl0, 0);
  int k = 2 * TBK;
  for (int t = 0; t < (NK - 2) / 2; ++t) {
    __syncthreads();
    LOADA(rah0, ral0, rbh0, rbl0, k);   // t+2 in flight
    COMPUTE(0);                          // tile t (buf0)
    STORE(rah1, ral1, rbh1, rbl1, 1);    // t+1 -> buf1
    k += TBK;
    __syncthreads();
    LOADA(rah1, ral1, rbh1, rbl1, k);
    COMPUTE(1);
    STORE(rah0, ral0, rbh0, rbl0, 0);
    k += TBK;
  }
  __syncthreads();
  COMPUTE(0);
  STORE(rah1, ral1, rbh1, rbl1, 1);
  __syncthreads();
  COMPUTE(1);

  if (FUSE3) {
    // relu(acc+bias) . W3 -> per-row (s0,s1); reduce over the 16 l16 lanes
    // sharing a row; leader atomicAdds into b3-prefilled C[M][2].
#pragma unroll
    for (int tm = 0; tm < TM; ++tm) {
#pragma unroll
      for (int r = 0; r < 4; ++r) {
        int row = m0 + wm * (TBM_ / 2) + tm * 16 + quad * 4 + r;
        float s0 = 0.f, s1 = 0.f;
#pragma unroll
        for (int tn = 0; tn < 2; ++tn) {
          int col = n0 + wn * 32 + tn * 16 + l16;
          float v = fmaxf(acc[tm][tn][r] + bias[col], 0.f);
          s0 += v * W3g[col * 2 + 0];
          s1 += v * W3g[col * 2 + 1];
        }
#pragma unroll
        for (int o = 1; o < 16; o <<= 1) {
          s0 += __shfl_xor(s0, o);
          s1 += __shfl_xor(s1, o);
        }
        if (l16 == 0 && row < M) {
          atomicAdd(&C[(size_t)row * 2 + 0], s0);
          atomicAdd(&C[(size_t)row * 2 + 1], s1);
        }
      }
    }
  } else {
#pragma unroll
    for (int tn = 0; tn < 2; ++tn) {
      int col = n0 + wn * 32 + tn * 16 + l16;
      float bv = bias ? bias[col] : 0.f;
#pragma unroll
      for (int tm = 0; tm < TM; ++tm) {
#pragma unroll
        for (int r = 0; r < 4; ++r) {
          int row = m0 + wm * (TBM_ / 2) + tm * 16 + quad * 4 + r;
          if (row >= M) continue;
          float v = acc[tm][tn][r] + bv;
          if (ACT == 1) v = fmaxf(v, 0.f);
          C[(size_t)row * N + col] = v;
        }
      }
    }
  }
}

template <int TBM_, int ACT, int FUSE3>
__global__ __launch_bounds__(256) void mfma_gemm(
    const ushort* __restrict__ Ahg, const ushort* __restrict__ Alg,
    const ushort* __restrict__ Bhg, const ushort* __restrict__ Blg,
    int ldb, const float* __restrict__ bias, const float* __restrict__ W3g,
    float* __restrict__ C, int M, int N, int K) {
  __shared__ GemmSmem<TBM_> sm;
  gemm_body<TBM_, ACT, FUSE3>(sm, Ahg, Alg, Bhg, Blg, ldb, bias, W3g, C, M, N, K,
                              blockIdx.x, blockIdx.y);
}

// up-to-3-way segmented GEMM: flat grid, per-segment params, M-fast mapping
// (mb = t % mblk). Blocks are uniform per segment; bodies identical to the
// proven gemm_body; one shared-mem instance serves all 3 exclusive branches.
struct GArg {
  const ushort* Ah; const ushort* Al; const ushort* Bh; const ushort* Bl;
  const float* bias; float* C;
  int ldb; int M; int N; int K; int mblk;
};

template <int TBM_, int ACT>
__global__ __launch_bounds__(256) void mfma_gemm_seg3(
    GArg g0, GArg g1, GArg g2, int b1, int b2) {
  __shared__ GemmSmem<TBM_> sm;
  int bid = blockIdx.x;
  if (bid < b1) {
    gemm_body<TBM_, ACT, 0>(sm, g0.Ah, g0.Al, g0.Bh, g0.Bl, g0.ldb, g0.bias, nullptr,
                            g0.C, g0.M, g0.N, g0.K, bid % g0.mblk, bid / g0.mblk);
  } else if (bid < b2) {
    int t = bid - b1;
    gemm_body<TBM_, ACT, 0>(sm, g1.Ah, g1.Al, g1.Bh, g1.Bl, g1.ldb, g1.bias, nullptr,
                            g1.C, g1.M, g1.N, g1.K, t % g1.mblk, t / g1.mblk);
  } else {
    int t = bid - b2;
    gemm_body<TBM_, ACT, 0>(sm, g2.Ah, g2.Al, g2.Bh, g2.Bl, g2.ldb, g2.bias, nullptr,
                            g2.C, g2.M, g2.N, g2.K, t % g2.mblk, t / g2.mblk);
  }
}

template <int TBM_, int ACT>
static void gemm_launch(hipStream_t s,
                        const ushort* Ahg, const ushort* Alg,
                        const ushort* Bhg, const ushort* Blg,
                        int ldb, const float* bias, float* C,
                        int M, int N, int K) {
  dim3 g(cdiv(M, TBM_), N / TBN);   // M fast: XCD-local A-panel reuse
  mfma_gemm<TBM_, ACT, 0><<<g, 256, 0, s>>>(Ahg, Alg, Bhg, Blg, ldb, bias, nullptr, C, M, N, K);
}

static void gemm_launch_f3(hipStream_t s,
                           const ushort* Ahg, const ushort* Alg,
                           const ushort* Bhg, const ushort* Blg,
                           int ldb, const float* bias, const float* W3,
                           float* C, int M, int N, int K) {
  dim3 g(cdiv(M, 128), N / TBN);
  mfma_gemm<128, 1, 1><<<g, 256, 0, s>>>(Ahg, Alg, Bhg, Blg, ldb, bias, W3, C, M, N, K);
}

// ---------------------------------------------------------------- row dots + out32 zero
__global__ __launch_bounds__(256) void rowdot_dc_z_kernel(
    const float* __restrict__ Hd, const float* __restrict__ ad, float* __restrict__ od, int nd,
    const float* __restrict__ Hc, const float* __restrict__ ac, float* __restrict__ oc, int nc,
    float* __restrict__ z, int nz, int bs1, int bs2) {
  int b = blockIdx.x;
  if (b >= bs2) {                        // zero segment
    int i = (b - bs2) * 256 + threadIdx.x;
    if (i < nz) z[i] = 0.f;
    return;
  }
  const float* H; const float* a; float* o; int n; int row;
  if (b < bs1) { H = Hd; a = ad; o = od; n = nd; row = b * 4 + (threadIdx.x >> 6); }
  else         { H = Hc; a = ac; o = oc; n = nc; row = (b - bs1) * 4 + (threadIdx.x >> 6); }
  if (row >= n) return;
  int lane = threadIdx.x & 63;
  const float* h = H + (size_t)row * HDIM;
  float s = 0.f;
#pragma unroll
  for (int u = 0; u < 4; ++u) {
    int c = lane + u * 64;
    s += h[c] * a[c];
  }
#pragma unroll
  for (int off = 32; off; off >>= 1) s += __shfl_down(s, off);
  if (lane == 0) o[row] = s;
}

// ---------------------------------------------------------------- counting sort by dst
__global__ __launch_bounds__(256) void hist_kernel(
    const int* __restrict__ src, const int* __restrict__ dst, int E, int nloops,
    int Nd, int* __restrict__ offs) {
  extern __shared__ int bins[];
  int tot = E + nloops;
  int chunk = (tot + NB - 1) / NB;
  int b = blockIdx.x;
  int s0 = b * chunk, s1 = min(s0 + chunk, tot);
  for (int i = threadIdx.x; i < Nd; i += 256) bins[i] = 0;
  __syncthreads();
  for (int i = s0 + threadIdx.x; i < s1; i += 256) {
    int d = (i < E) ? dst[i] : (i - E);
    atomicAdd(&bins[d], 1);
  }
  __syncthreads();
  for (int i = threadIdx.x; i < Nd; i += 256) offs[(size_t)i * NB + b] = bins[i];
}

__global__ __launch_bounds__(256) void scan_bins_kernel(
    int* __restrict__ offs, int* __restrict__ binsum, int Nd) {
  int d = blockIdx.x * 4 + (threadIdx.x >> 6);
  if (d >= Nd) return;
  int lane = threadIdx.x & 63;
  int* p = offs + (size_t)d * NB;
  int v0 = p[2 * lane], v1 = p[2 * lane + 1];
  int s = v0 + v1;
  int t = s;
#pragma unroll
  for (int o = 1; o < 64; o <<= 1) { int u = __shfl_up(t, o); if (lane >= o) t += u; }
  int excl = t - s;
  p[2 * lane] = excl;
  p[2 * lane + 1] = excl + v0;
  if (lane == 63) binsum[d] = t;
}

__global__ __launch_bounds__(256) void scan_base_kernel(
    const int* __restrict__ binsum, int* __restrict__ rowptr, int Nd) {
  __shared__ int wsum[4];
  __shared__ int carry;
  if (threadIdx.x == 0) carry = 0;
  __syncthreads();
  int lane = threadIdx.x & 63, w = threadIdx.x >> 6;
  for (int t0 = 0; t0 < Nd; t0 += 256) {
    int i = t0 + threadIdx.x;
    int v = (i < Nd) ? binsum[i] : 0;
    int t = v;
#pragma unroll
    for (int o = 1; o < 64; o <<= 1) { int u = __shfl_up(t, o); if (lane >= o) t += u; }
    if (lane == 63) wsum[w] = t;
    __syncthreads();
    int add = carry;
    for (int k = 0; k < w; ++k) add += wsum[k];
    if (i < Nd) rowptr[i] = t - v + add;
    __syncthreads();
    if (threadIdx.x == 0) carry += wsum[0] + wsum[1] + wsum[2] + wsum[3];
    __syncthreads();
  }
  if (threadIdx.x == 0) rowptr[Nd] = carry;
}

__global__ __launch_bounds__(256) void scatter_kernel(
    const int* __restrict__ src, const int* __restrict__ dst, int E, int nloops,
    int Nd, const int* __restrict__ offs, const int* __restrict__ rowptr,
    uint* __restrict__ sd) {
  extern __shared__ int bins[];
  int tot = E + nloops;
  int chunk = (tot + NB - 1) / NB;
  int b = blockIdx.x;
  int s0 = b * chunk, s1 = min(s0 + chunk, tot);
  for (int i = threadIdx.x; i < Nd; i += 256) bins[i] = 0;
  __syncthreads();
  for (int i = s0 + threadIdx.x; i < s1; i += 256) {
    int s_, d_;
    if (i < E) { s_ = src[i]; d_ = dst[i]; }
    else       { s_ = d_ = i - E; }
    int local = atomicAdd(&bins[d_], 1);
    int pos = rowptr[d_] + offs[(size_t)d_ * NB + b] + local;
    sd[pos] = (uint)s_ | ((uint)d_ << 16);
  }
}

// ---------------------------------------------------------------- fused GAT edge phase
// pp aggregator: wave per dst, split-plane output (proven body)
__global__ __launch_bounds__(256) void gat_agg_split(
    const int* __restrict__ rowptr, const uint* __restrict__ sd,
    const float* __restrict__ als, const float* __restrict__ ald,
    const ushort* __restrict__ Xb,
    ushort* __restrict__ aggh, ushort* __restrict__ aggl, int n) {
  int d = blockIdx.x * 4 + (threadIdx.x >> 6);
  if (d >= n) return;
  int lane = threadIdx.x & 63;
  int r0 = rowptr[d], r1 = rowptr[d + 1];
  float aldd = ald[d];
  float dsum = 0.f;
  for (int j = r0 + lane; j < r1; j += 64) {
    float e = als[sd[j] & 0xffff] + aldd;
    e = (e > 0.f) ? e : NEG_SLOPE * e;
    dsum += __expf(e);
  }
#pragma unroll
  for (int o = 32; o; o >>= 1) dsum += __shfl_xor(dsum, o);
  float rden = 1.f / (dsum + 1e-16f);

  float4 acc = make_float4(0.f, 0.f, 0.f, 0.f);
  for (int b = r0; b < r1; b += 64) {
    int j = b + lane;
    float exv = 0.f; int srcv = 0;
    if (j < r1) {
      uint p = sd[j];
      srcv = p & 0xffff;
      float e = als[srcv] + aldd;
      e = (e > 0.f) ? e : NEG_SLOPE * e;
      exv = __expf(e) * rden;
    }
    int cnt = min(64, r1 - b);
    for (int t0 = 0; t0 < cnt; t0 += 8) {
      float cf[8]; int sv[8];
#pragma unroll
      for (int u = 0; u < 8; ++u) {
        cf[u] = __shfl(exv, t0 + u);
        sv[u] = __shfl(srcv, t0 + u);
      }
      ushort4 hv[8];
#pragma unroll
      for (int u = 0; u < 8; ++u)
        hv[u] = *(const ushort4*)(Xb + (size_t)sv[u] * HDIM + lane * 4);
#pragma unroll
      for (int u = 0; u < 8; ++u) {
        acc.x += cf[u] * b2f(hv[u].x);
        acc.y += cf[u] * b2f(hv[u].y);
        acc.z += cf[u] * b2f(hv[u].z);
        acc.w += cf[u] * b2f(hv[u].w);
      }
    }
  }
  uint p0 = f2pl(acc.x), p1 = f2pl(acc.y), p2 = f2pl(acc.z), p3 = f2pl(acc.w);
  ushort4 h = {(ushort)(p0 & 0xffff), (ushort)(p1 & 0xffff), (ushort)(p2 & 0xffff), (ushort)(p3 & 0xffff)};
  ushort4 l = {(ushort)(p0 >> 16), (ushort)(p1 >> 16), (ushort)(p2 >> 16), (ushort)(p3 >> 16)};
  *(ushort4*)(aggh + (size_t)d * HDIM + lane * 4) = h;
  *(ushort4*)(aggl + (size_t)d * HDIM + lane * 4) = l;
}

// dp aggregate + cp slice-aggregate in ONE launch (proven round-15 kernel)
__global__ __launch_bounds__(256) void agg_dp_cp_kernel(
    const int* __restrict__ rp_d, const uint* __restrict__ sd_d,
    const float* __restrict__ als_d, const float* __restrict__ ald_d,
    ushort* __restrict__ aggh, ushort* __restrict__ aggl, int nd, int bsplit,
    const int* __restrict__ rp_c, const uint* __restrict__ sd_c,
    const float* __restrict__ als_c, const float* __restrict__ ald_c,
    float* __restrict__ out32, int nc, const ushort* __restrict__ Xb) {
  __shared__ float wd[4];
  if (blockIdx.x < bsplit) {
    // ---- dp: gat_agg_split body
    int d = blockIdx.x * 4 + (threadIdx.x >> 6);
    if (d >= nd) return;
    int lane = threadIdx.x & 63;
    int r0 = rp_d[d], r1 = rp_d[d + 1];
    float aldd = ald_d[d];
    float dsum = 0.f;
    for (int j = r0 + lane; j < r1; j += 64) {
      float e = als_d[sd_d[j] & 0xffff] + aldd;
      e = (e > 0.f) ? e : NEG_SLOPE * e;
      dsum += __expf(e);
    }
#pragma unroll
    for (int o = 32; o; o >>= 1) dsum += __shfl_xor(dsum, o);
    float rden = 1.f / (dsum + 1e-16f);

    float4 acc = make_float4(0.f, 0.f, 0.f, 0.f);
    for (int b = r0; b < r1; b += 64) {
      int j = b + lane;
      float exv = 0.f; int srcv = 0;
      if (j < r1) {
        uint p = sd_d[j];
        srcv = p & 0xffff;
        float e = als_d[srcv] + aldd;
        e = (e > 0.f) ? e : NEG_SLOPE * e;
        exv = __expf(e) * rden;
      }
      int cnt = min(64, r1 - b);
      for (int t0 = 0; t0 < cnt; t0 += 8) {
        float cf[8]; int sv[8];
#pragma unroll
        for (int u = 0; u < 8; ++u) {
          cf[u] = __shfl(exv, t0 + u);
          sv[u] = __shfl(srcv, t0 + u);
        }
        ushort4 hv[8];
#pragma unroll
        for (int u = 0; u < 8; ++u)
          hv[u] = *(const ushort4*)(Xb + (size_t)sv[u] * HDIM + lane * 4);
#pragma unroll
        for (int u = 0; u < 8; ++u) {
          acc.x += cf[u] * b2f(hv[u].x);
          acc.y += cf[u] * b2f(hv[u].y);
          acc.z += cf[u] * b2f(hv[u].z);
          acc.w += cf[u] * b2f(hv[u].w);
        }
      }
    }
    uint p0 = f2pl(acc.x), p1 = f2pl(acc.y), p2 = f2pl(acc.z), p3 = f2pl(acc.w);
    ushort4 h = {(ushort)(p0 & 0xffff), (ushort)(p1 & 0xffff), (ushort)(p2 & 0xffff), (ushort)(p3 & 0xffff)};
    ushort4 l = {(ushort)(p0 >> 16), (ushort)(p1 >> 16), (ushort)(p2 >> 16), (ushort)(p3 >> 16)};
    *(ushort4*)(aggh + (size_t)d * HDIM + lane * 4) = h;
    *(ushort4*)(aggl + (size_t)d * HDIM + lane * 4) = l;
  } else {
    // ---- cp: gat_agg_slice body (atomicAdd partials into pre-zeroed out32)
    int bb = blockIdx.x - bsplit;
    int d = bb / SLICES;
    int sl = bb - d * SLICES;
    if (d >= nc) return;
    int lane = threadIdx.x & 63, w = threadIdx.x >> 6;
    int r0 = rp_c[d], r1 = rp_c[d + 1];
    float aldd = ald_c[d];
    float dsum = 0.f;
    for (int j = r0 + threadIdx.x; j < r1; j += 256) {
      float e = als_c[sd_c[j] & 0xffff] + aldd;
      e = (e > 0.f) ? e : NEG_SLOPE * e;
      dsum += __expf(e);
    }
#pragma unroll
    for (int o = 32; o; o >>= 1) dsum += __shfl_xor(dsum, o);
    if (lane == 0) wd[w] = dsum;
    __syncthreads();
    float rden = 1.f / (wd[0] + wd[1] + wd[2] + wd[3] + 1e-16f);
    int deg = r1 - r0;
    int per_b = (deg + SLICES - 1) / SLICES;
    int b0 = r0 + sl * per_b, b1 = min(b0 + per_b, r1);
    int wdeg = b1 - b0;
    if (wdeg <= 0) return;
    int per_w = (wdeg + 3) >> 2;
    int w0 = b0 + w * per_w, w1 = min(w0 + per_w, b1);

    float4 acc = make_float4(0.f, 0.f, 0.f, 0.f);
    for (int b = w0; b < w1; b += 64) {
      int j = b + lane;
      float exv = 0.f; int srcv = 0;
      if (j < w1) {
        uint p = sd_c[j];
        srcv = p & 0xffff;
        float e = als_c[srcv] + aldd;
        e = (e > 0.f) ? e : NEG_SLOPE * e;
        exv = __expf(e) * rden;
      }
      int cnt = min(64, w1 - b);
      for (int t0 = 0; t0 < cnt; t0 += 8) {
        float cf[8]; int sv[8];
#pragma unroll
        for (int u = 0; u < 8; ++u) {
          cf[u] = __shfl(exv, t0 + u);
          sv[u] = __shfl(srcv, t0 + u);
        }
        ushort4 hv[8];
#pragma unroll
        for (int u = 0; u < 8; ++u)
          hv[u] = *(const ushort4*)(Xb + (size_t)sv[u] * HDIM + lane * 4);
#pragma unroll
        for (int u = 0; u < 8; ++u) {
          acc.x += cf[u] * b2f(hv[u].x);
          acc.y += cf[u] * b2f(hv[u].y);
          acc.z += cf[u] * b2f(hv[u].z);
          acc.w += cf[u] * b2f(hv[u].w);
        }
      }
    }
    float* o = out32 + (size_t)d * HDIM + lane * 4;
    atomicAdd(o + 0, acc.x); atomicAdd(o + 1, acc.y);
    atomicAdd(o + 2, acc.z); atomicAdd(o + 3, acc.w);
  }
}

// ---------------------------------------------------------------- norms
__global__ __launch_bounds__(256) void l2norm_f32b_dots_kernel(
    const float* __restrict__ in, float* __restrict__ outf, ushort* __restrict__ outb,
    const float* __restrict__ v1, const float* __restrict__ v2,
    const float* __restrict__ v3, const float* __restrict__ v4,
    float* __restrict__ o1, float* __restrict__ o2,
    float* __restrict__ o3, float* __restrict__ o4, int n) {
  int row = blockIdx.x * 4 + (threadIdx.x >> 6);
  if (row >= n) return;
  int lane = threadIdx.x & 63;
  float v[4];
  float ss = 0.f;
#pragma unroll
  for (int u = 0; u < 4; ++u) {
    float t = in[(size_t)row * HDIM + lane + u * 64];
    v[u] = t; ss += t * t;
  }
#pragma unroll
  for (int off = 32; off; off >>= 1) ss += __shfl_xor(ss, off);
  float sc = 1.0f / fmaxf(sqrtf(ss), 1e-12f);
  float d1 = 0.f, d2 = 0.f, d3 = 0.f, d4 = 0.f;
#pragma unroll
  for (int u = 0; u < 4; ++u) {
    float f = v[u] * sc;
    int c = lane + u * 64;
    outf[(size_t)row * HDIM + c] = f;
    outb[(size_t)row * HDIM + c] = f2b(f);
    d1 += f * v1[c];
    d2 += f * v2[c];
    if (o3) { d3 += f * v3[c]; d4 += f * v4[c]; }
  }
#pragma unroll
  for (int off = 32; off; off >>= 1) {
    d1 += __shfl_xor(d1, off);
    d2 += __shfl_xor(d2, off);
    if (o3) { d3 += __shfl_xor(d3, off); d4 += __shfl_xor(d4, off); }
  }
  if (lane == 0) {
    o1[row] = d1; o2[row] = d2;
    if (o3) { o3[row] = d3; o4[row] = d4; }
  }
}

// head prep, ONE launch: l2norm-split of drug + cell tables, plus the two
// head weight conversions (W1, W2). All four segments are independent
// (disjoint inputs/outputs); bodies identical to the proven kernels.
__global__ __launch_bounds__(256) void head_prep_kernel(
    const float* __restrict__ Xd, ushort* __restrict__ dh, ushort* __restrict__ dl, int nd,
    const float* __restrict__ Xc, ushort* __restrict__ ch, ushort* __restrict__ cl, int nc,
    const float* __restrict__ W1, ushort* __restrict__ W1h, ushort* __restrict__ W1l,
    int K1, int N1_,
    const float* __restrict__ W2, ushort* __restrict__ W2h, ushort* __restrict__ W2l,
    int N2_, int bs1, int bs2, int bs3) {
  int b = blockIdx.x;
  if (b >= bs3) {                        // wconv W2: [N1_][N2_] -> [N2_][N1_]
    int i = (b - bs3) * 256 + threadIdx.x;
    if (i >= N1_ * N2_) return;
    int k = i / N2_, n = i - k * N2_;
    uint p = f2pl(W2[i]);
    W2h[(size_t)n * N1_ + k] = (ushort)(p & 0xffff);
    W2l[(size_t)n * N1_ + k] = (ushort)(p >> 16);
    return;
  }
  if (b >= bs2) {                        // wconv W1: [K1][N1_] -> [N1_][K1]
    int i = (b - bs2) * 256 + threadIdx.x;
    if (i >= K1 * N1_) return;
    int k = i / N1_, n = i - k * N1_;
    uint p = f2pl(W1[i]);
    W1h[(size_t)n * K1 + k] = (ushort)(p & 0xffff);
    W1l[(size_t)n * K1 + k] = (ushort)(p >> 16);
    return;
  }
  // l2norm-split segments (drug rows then cell rows)
  const float* in; ushort* oh; ushort* ol; int n; int row;
  if (b < bs1) { in = Xd; oh = dh; ol = dl; n = nd; row = b * 4 + (threadIdx.x >> 6); }
  else         { in = Xc; oh = ch; ol = cl; n = nc; row = (b - bs1) * 4 + (threadIdx.x >> 6); }
  if (row >= n) return;
  int lane = threadIdx.x & 63;
  float v[4];
  float ss = 0.f;
#pragma unroll
  for (int u = 0; u < 4; ++u) {
    int c = lane + u * 64;
    float t = in[(size_t)row * HDIM + c];
    v[u] = t;
    ss += t * t;
  }
#pragma unroll
  for (int off = 32; off; off >>= 1) ss += __shfl_xor(ss, off);
  float sc = 1.0f / fmaxf(sqrtf(ss), 1e-12f);
#pragma unroll
  for (int u = 0; u < 4; ++u) {
    int c = lane + u * 64;
    uint p = f2pl(v[u] * sc);
    oh[(size_t)row * HDIM + c] = (ushort)(p & 0xffff);
    ol[(size_t)row * HDIM + c] = (ushort)(p >> 16);
  }
}

// ---------------------------------------------------------------- host side
static void build_sorted(hipStream_t stream,
                         const int* src, const int* dst, int E, int nloops, int Nd,
                         int* offs, int* binsum, int* rowptr, uint* sd) {
  size_t lds = (size_t)Nd * sizeof(int);
  hist_kernel<<<NB, 256, lds, stream>>>(src, dst, E, nloops, Nd, offs);
  scan_bins_kernel<<<cdiv(Nd, 4), 256, 0, stream>>>(offs, binsum, Nd);
  scan_base_kernel<<<1, 256, 0, stream>>>(binsum, rowptr, Nd);
  scatter_kernel<<<NB, 256, lds, stream>>>(src, dst, E, nloops, Nd, offs, rowptr, sd);
}

extern "C" void kernel_launch(void* const* d_in, const int* in_sizes, int n_in,
                              void* d_out, int out_size, void* d_ws, size_t ws_size,
                              hipStream_t stream) {
  const float* drug_emb = (const float*)d_in[0];
  const float* prot_emb = (const float*)d_in[1];
  const float* cell_emb = (const float*)d_in[2];
  const float* W_pp = (const float*)d_in[3];
  const float* as_pp = (const float*)d_in[4];
  const float* ad_pp = (const float*)d_in[5];
  const float* b_pp = (const float*)d_in[6];
  const float* W_dp = (const float*)d_in[7];
  const float* as_dp = (const float*)d_in[8];
  const float* ad_dp = (const float*)d_in[9];
  const float* b_dp = (const float*)d_in[10];
  const float* W_cp = (const float*)d_in[11];
  const float* as_cp = (const float*)d_in[12];
  const float* ad_cp = (const float*)d_in[13];
  const float* b_cp = (const float*)d_in[14];
  const float* W1 = (const float*)d_in[15];
  const float* b1 = (const float*)d_in[16];
  const float* W2 = (const float*)d_in[17];
  const float* b2 = (const float*)d_in[18];
  const float* W3 = (const float*)d_in[19];
  const float* b3 = (const float*)d_in[20];
  const int* edge_pp = (const int*)d_in[21];
  const int* edge_dp = (const int*)d_in[22];
  const int* edge_cp = (const int*)d_in[23];
  const int* drug1 = (const int*)d_in[24];
  const int* drug2 = (const int*)d_in[25];
  const int* cellb = (const int*)d_in[26];

  const int ND = in_sizes[0] / HDIM;   // 2000
  const int NP = in_sizes[1] / HDIM;   // 19000
  const int NC = in_sizes[2] / HDIM;   // 100
  const int L = in_sizes[3] / (HDIM * HDIM);  // 2
  const int E_pp = in_sizes[21] / 2;
  const int E_dp = in_sizes[22] / 2;
  const int E_cp = in_sizes[23] / 2;
  const int B = in_sizes[24];          // 8192
  (void)n_in; (void)out_size;

  const int* src_pp = edge_pp;          const int* dst_pp = edge_pp + E_pp;
  const int* src_dp = edge_dp;          const int* dst_dp = edge_dp + E_dp;
  const int* src_cp = edge_cp;          const int* dst_cp = edge_cp + E_cp;
  const int tot_pp = E_pp + NP, tot_dp = E_dp, tot_cp = E_cp;
  int maxN = NP > ND ? NP : ND; if (NC > maxN) maxN = NC;

  // ---------------- workspace
  char* wsb = (char*)d_ws;
  size_t off = 0;
  auto alloc = [&](size_t bytes) -> void* {
    void* p = wsb + off;
    off += (bytes + 255) & ~(size_t)255;
    return p;
  };

  float* Xp  = (float*)alloc((size_t)NP * HDIM * 4);    // protein state fp32
  ushort* Xpb = (ushort*)alloc((size_t)NP * HDIM * 2);  // protein state bf16 (gather)
  float* Xd  = (float*)alloc((size_t)ND * HDIM * 4);
  float* Xc  = (float*)alloc((size_t)NC * HDIM * 4);
  ushort* xdnh = (ushort*)alloc((size_t)ND * HDIM * 2);
  ushort* xdnl = (ushort*)alloc((size_t)ND * HDIM * 2);
  ushort* xcnh = (ushort*)alloc((size_t)NC * HDIM * 2);
  ushort* xcnl = (ushort*)alloc((size_t)NC * HDIM * 2);
  ushort* WTpph = (ushort*)alloc((size_t)L * HDIM * HDIM * 2);
  ushort* WTppl = (ushort*)alloc((size_t)L * HDIM * HDIM * 2);
  ushort* WTdph = (ushort*)alloc((size_t)L * HDIM * HDIM * 2);
  ushort* WTdpl = (ushort*)alloc((size_t)L * HDIM * HDIM * 2);
  ushort* WTcph = (ushort*)alloc((size_t)L * HDIM * HDIM * 2);
  ushort* WTcpl = (ushort*)alloc((size_t)L * HDIM * HDIM * 2);
  ushort* cth = (ushort*)alloc((size_t)NC * HDIM * 2);  // cp split staging
  ushort* ctl = (ushort*)alloc((size_t)NC * HDIM * 2);
  float* wv  = (float*)alloc((size_t)L * 6 * HDIM * 4); // folded W@a vectors
  float* pals = (float*)alloc((size_t)maxN * 4);        // pp src logits
  float* pald = (float*)alloc((size_t)maxN * 4);        // pp dst logits
  float* als1 = (float*)alloc((size_t)maxN * 4);        // dp src logits
  float* als2 = (float*)alloc((size_t)maxN * 4);        // cp src logits
  float* ald1 = (float*)alloc((size_t)maxN * 4);
  float* ald2 = (float*)alloc((size_t)maxN * 4);
  int* binsum = (int*)alloc((size_t)maxN * 4);
  int* rp_pp = (int*)alloc((size_t)(NP + 1) * 4);
  int* rp_dp = (int*)alloc((size_t)(ND + 1) * 4);
  int* rp_cp = (int*)alloc((size_t)(NC + 1) * 4);
  uint* sd_pp = (uint*)alloc((size_t)tot_pp * 4);
  uint* sd_dp = (uint*)alloc((size_t)tot_dp * 4);
  uint* sd_cp = (uint*)alloc((size_t)tot_cp * 4);
  float* out32 = (float*)alloc((size_t)NC * HDIM * 4);  // cp partial accumulator
  size_t S0 = off;

  // scratch S overlays: [offs] -> [aggh|aggl|tmp] -> [W1T*|W2T*|P1|P2|P3|h1*]
  int* offs = (int*)(wsb + S0);
  build_sorted(stream, src_pp, dst_pp, E_pp, NP, NP, offs, binsum, rp_pp, sd_pp);
  build_sorted(stream, src_dp, dst_dp, E_dp, 0, ND, offs, binsum, rp_dp, sd_dp);
  build_sorted(stream, src_cp, dst_cp, E_cp, 0, NC, offs, binsum, rp_cp, sd_cp);

  // ---- weight split planes (batched) + folded attention vectors + protein prep
  wconv_split3_kernel<<<cdiv(3 * L * HDIM * HDIM, 256), 256, 0, stream>>>(
      W_pp, W_dp, W_cp, WTpph, WTppl, WTdph, WTdpl, WTcph, WTcpl, L);
  matvec_all_kernel<<<L * 6, 256, 0, stream>>>(W_pp, as_pp, ad_pp, W_dp, as_dp, ad_dp,
                                               W_cp, as_cp, ad_cp, wv);
  // layer-0: Xpb bf16 copy + pp logits in one pass over prot_emb
  prep_p_kernel<<<cdiv(NP, 4), 256, 0, stream>>>(prot_emb, Xpb, wv + 0 * HDIM, wv + 1 * HDIM,
                                                 pals, pald, NP);

  size_t aggB = ((size_t)NP * HDIM * 2 + 255) & ~(size_t)255;
  ushort* aggh = (ushort*)(wsb + S0);
  ushort* aggl = (ushort*)(wsb + S0 + aggB);
  float* tmp = (float*)(wsb + S0 + 2 * aggB);

  for (int l = 0; l < L; ++l) {
    const int WOFF = l * HDIM * HDIM, VOFF = l * HDIM;
    const float* wvl = wv + (size_t)l * 6 * HDIM;
    bool last = (l == L - 1);
    const float* wvn = last ? wvl : wv + (size_t)(l + 1) * 6 * HDIM;
    const float* Xd_cur = (l == 0) ? drug_emb : Xd;
    const float* Xc_cur = (l == 0) ? cell_emb : Xc;

    // ---- p-p: aggregate x -> transform -> l2norm (+fused dots for dp/cp/next-pp)
    gat_agg_split<<<cdiv(NP, 4), 256, 0, stream>>>(rp_pp, sd_pp, pals, pald, Xpb, aggh, aggl, NP);
    gemm_launch<128, 0>(stream, aggh, aggl, WTpph + WOFF, WTppl + WOFF, HDIM,
                        b_pp + VOFF, tmp, NP, HDIM, HDIM);
    l2norm_f32b_dots_kernel<<<cdiv(NP, 4), 256, 0, stream>>>(
        tmp, Xp, Xpb,
        wvl + 2 * HDIM, wvl + 4 * HDIM,
        last ? nullptr : (wvn + 0 * HDIM), last ? nullptr : (wvn + 1 * HDIM),
        als1, als2, last ? nullptr : pals, last ? nullptr : pald, NP);

    // dp rowdot + cp rowdot + out32 zeroing, one launch
    {
      int bs1 = cdiv(ND, 4), bs2 = bs1 + cdiv(NC, 4);
      int nz = NC * HDIM;
      rowdot_dc_z_kernel<<<bs2 + cdiv(nz, 256), 256, 0, stream>>>(
          Xd_cur, wvl + 3 * HDIM, ald1, ND,
          Xc_cur, wvl + 5 * HDIM, ald2, NC,
          out32, nz, bs1, bs2);
    }

    // ---- dp aggregate + cp slice-aggregate, one launch (independent phases)
    {
      int bsplit = cdiv(ND, 4);
      agg_dp_cp_kernel<<<bsplit + NC * SLICES, 256, 0, stream>>>(
          rp_dp, sd_dp, als1, ald1, aggh, aggl, ND, bsplit,
          rp_cp, sd_cp, als2, ald2, out32, NC, Xpb);
    }

    // ---- cp split (tiny), then dp-GEMM + cp-GEMM in ONE segmented launch
    f32_to_split_kernel<<<cdiv(NC * HDIM, 256), 256, 0, stream>>>(out32, cth, ctl, NC * HDIM);
    {
      int mbd = cdiv(ND, 64), mbc = cdiv(NC, 64);
      int bd = mbd * (HDIM / TBN);          // dp blocks (M fast)
      int bc = mbc * (HDIM / TBN);          // cp blocks
      GArg gd{aggh, aggl, WTdph + WOFF, WTdpl + WOFF, b_dp + VOFF, Xd,
              HDIM, ND, HDIM, HDIM, mbd};
      GArg gc{cth, ctl, WTcph + WOFF, WTcpl + WOFF, b_cp + VOFF, Xc,
              HDIM, NC, HDIM, HDIM, mbc};
      mfma_gemm_seg3<64, 1><<<bd + bc, 256, 0, stream>>>(gd, gc, gc, bd, bd + bc);
    }
  }

  // ---------------- head
  const int N1 = 6 * HDIM;   // 1536
  const int N2 = 2 * HDIM;   // 512
  const int K1 = 3 * HDIM;   // 768
  ushort* W1Th = (ushort*)(wsb + S0);                   // [1536][768]
  ushort* W1Tl = W1Th + (size_t)N1 * K1;
  ushort* W2Th = W1Tl + (size_t)N1 * K1;                // [512][1536]
  ushort* W2Tl = W2Th + (size_t)N2 * N1;
  float* P1 = (float*)(W2Tl + (size_t)N2 * N1);         // [ND][1536]
  float* P2 = P1 + (size_t)ND * N1;
  float* P3 = P2 + (size_t)ND * N1;                     // [NC][1536]
  ushort* h1h = (ushort*)(P3 + (size_t)NC * N1);        // [CH][1536] split
  size_t wsz = ws_size ? ws_size : ((size_t)1 << 30);
  size_t fixed = S0 + ((size_t)N1 * K1 + (size_t)N2 * N1) * 4
               + ((size_t)(2 * ND + NC) * N1) * 4;
  int CH = 8192;
  while (CH > 1024 && fixed + (size_t)CH * N1 * 4 > wsz) CH >>= 1;
  ushort* h1l = h1h + (size_t)CH * N1;

  // l2norm-split (drug+cell) + wconv(W1) + wconv(W2), ONE launch
  {
    int bs1 = cdiv(ND, 4);
    int bs2 = bs1 + cdiv(NC, 4);
    int bs3 = bs2 + cdiv(K1 * N1, 256);
    int btot = bs3 + cdiv(N1 * N2, 256);
    head_prep_kernel<<<btot, 256, 0, stream>>>(
        Xd, xdnh, xdnl, ND, Xc, xcnh, xcnl, NC,
        W1, W1Th, W1Tl, K1, N1, W2, W2Th, W2Tl, N2, bs1, bs2, bs3);
  }

  // P1 + P2 + P3 GEMMs in ONE segmented launch (independent outputs)
  {
    int mbd = cdiv(ND, 64), mbc = cdiv(NC, 64);
    int q1 = mbd * (N1 / TBN);            // 32*24 = 768
    int q3 = mbc * (N1 / TBN);            // 2*24 = 48
    GArg p1a{xdnh, xdnl, W1Th, W1Tl, nullptr, P1, K1, ND, N1, HDIM, mbd};
    GArg p2a{xdnh, xdnl, W1Th + HDIM, W1Tl + HDIM, nullptr, P2, K1, ND, N1, HDIM, mbd};
    GArg p3a{xcnh, xcnl, W1Th + 2 * HDIM, W1Tl + 2 * HDIM, b1, P3, K1, NC, N1, HDIM, mbc};
    mfma_gemm_seg3<64, 0><<<q1 + q1 + q3, 256, 0, stream>>>(p1a, p2a, p3a, q1, 2 * q1);
  }

  float* outp = (float*)d_out;
  for (int c0 = 0; c0 < B; c0 += CH) {
    int M = (B - c0) < CH ? (B - c0) : CH;
    int bsC = cdiv(M * (N1 / 4), 256);
    int fillB = (c0 == 0) ? cdiv(B, 256) : 0;   // b3-prefill once, before first W2
    combine_h1_fill_kernel<<<bsC + fillB, 256, 0, stream>>>(
        P1, P2, P3, drug1, drug2, cellb, c0, h1h, h1l, M, N1,
        outp, b3, (c0 == 0) ? B : 0, bsC);
    gemm_launch_f3(stream, h1h, h1l, W2Th, W2Tl, N1, b2, W3,
                   outp + (size_t)c0 * 2, M, N2, N1);
  }
}

// Round 18
// 638.154 us; speedup vs baseline: 1.1589x; 1.0156x over previous
//
#include <hip/hip_runtime.h>
#include <hip/hip_bf16.h>

#define HDIM 256
#define NEG_SLOPE 0.2f
#define NB 128          // blocks for hist/scatter
#define SLICES 8        // edge slices per dst in the big-degree aggregator
#define TBN 64
#define TBK 32

typedef __attribute__((ext_vector_type(8))) short bf16x8;
typedef __attribute__((ext_vector_type(4))) float f32x4;

// split-bf16: x ~= bf16(hi) + bf16(lo); stored as two separate ushort arrays
__device__ inline uint f2pl(float x) {
  __hip_bfloat16 h = __float2bfloat16(x);
  ushort hi = *(ushort*)&h;
  float r = x - __bfloat162float(h);
  __hip_bfloat16 l = __float2bfloat16(r);
  ushort lo = *(ushort*)&l;
  return (uint)hi | ((uint)lo << 16);
}
__device__ inline ushort f2b(float x) {
  __hip_bfloat16 h = __float2bfloat16(x);
  return *(ushort*)&h;
}
__device__ inline float b2f(ushort u) {
  uint x = ((uint)u) << 16;
  return __int_as_float((int)x);
}

static inline int cdiv(int a, int b) { return (a + b - 1) / b; }

// ---------------------------------------------------------------- setup (ONE launch)
// segments: [0,c1) layer-weight conversion (3 edge types x L layers);
// [c1,c2) folded attention matvecs; [c2,..) protein prep (bf16 copy + pp rowdots).
// All independent (disjoint inputs/outputs); bodies verbatim from the proven
// wconv_split3 / matvec_all / prep_p kernels.
__global__ __launch_bounds__(256) void init_prep_kernel(
    const float* __restrict__ Wpp, const float* __restrict__ Wdp, const float* __restrict__ Wcp,
    ushort* __restrict__ WTpph, ushort* __restrict__ WTppl,
    ushort* __restrict__ WTdph, ushort* __restrict__ WTdpl,
    ushort* __restrict__ WTcph, ushort* __restrict__ WTcpl, int L,
    const float* __restrict__ aspp, const float* __restrict__ adpp,
    const float* __restrict__ asdp, const float* __restrict__ addp,
    const float* __restrict__ ascp, const float* __restrict__ adcp,
    float* __restrict__ wv,
    const float* __restrict__ pe, ushort* __restrict__ Xpb,
    float* __restrict__ o1, float* __restrict__ o2, int np,
    int c1, int c2) {
  const int per = HDIM * HDIM;
  int blk = blockIdx.x;
  if (blk < c1) {                        // ---- wconv_split3 body
    int i = blk * 256 + threadIdx.x;
    if (i >= 3 * L * per) return;
    int mat = i / per;
    int r = i - mat * per;
    int l = mat / 3, ty = mat - l * 3;
    const float* W = (ty == 0 ? Wpp : ty == 1 ? Wdp : Wcp) + (size_t)l * per;
    ushort* Th = (ty == 0 ? WTpph : ty == 1 ? WTdph : WTcph) + (size_t)l * per;
    ushort* Tl = (ty == 0 ? WTppl : ty == 1 ? WTdpl : WTcpl) + (size_t)l * per;
    int k = r >> 8, n = r & (HDIM - 1);  // r = k*HDIM + n
    uint p = f2pl(W[r]);
    Th[(size_t)n * HDIM + k] = (ushort)(p & 0xffff);
    Tl[(size_t)n * HDIM + k] = (ushort)(p >> 16);
    return;
  }
  if (blk < c2) {                        // ---- matvec_all body
    int b = blk - c1;
    int l = b / 6, r = b - l * 6, type = r >> 1, isd = r & 1;
    const float* W = (type == 0 ? Wpp : type == 1 ? Wdp : Wcp) + (size_t)l * per;
    const float* a = (type == 0 ? (isd ? adpp : aspp)
                    : type == 1 ? (isd ? addp : asdp)
                                : (isd ? adcp : ascp)) + (size_t)l * HDIM;
    int k = threadIdx.x;
    const float4* Wr = (const float4*)(W + (size_t)k * HDIM);
    float s = 0.f;
#pragma unroll 8
    for (int n4 = 0; n4 < HDIM / 4; ++n4) {
      float4 w = Wr[n4];
      float4 av = *(const float4*)(a + n4 * 4);
      s += w.x * av.x + w.y * av.y + w.z * av.z + w.w * av.w;
    }
    wv[(size_t)b * HDIM + k] = s;
    return;
  }
  // ---- prep_p body (layer-0 protein prep)
  int row = (blk - c2) * 4 + (threadIdx.x >> 6);
  if (row >= np) return;
  int lane = threadIdx.x & 63;
  const float* a1 = wv + 0 * HDIM;
  const float* a2 = wv + 1 * HDIM;
  // NOTE: a1/a2 are wv entries written by the matvec segment of THIS SAME
  // launch -- NOT allowed. So prep_p must read raw attention vectors and
  // weights instead. To preserve exact arithmetic we compute the dots
  // against the FOLDED vectors, which requires wv. Therefore this segment
  // must NOT depend on wv: we recompute the two folded dots directly as
  // (x . (W @ a)) == ((x @ W) . a)? NO -- different rounding. Instead we
  // keep the dependency-free formulation: load the folded vectors from wv
  // is invalid; so this segment reads a1/a2 from a SEPARATE precomputed
  // buffer filled on a previous launch. See host: wv01 filled by
  // matvec_all01_kernel before this launch.
  (void)a1; (void)a2;
  return;  // unreachable in this configuration (c2 == total); kept for safety
}

// folded attention vectors for layer-0 pp only (2 blocks) -- must precede
// init_prep's prep_p segment... (superseded: prep_p stays separate; see host)
__global__ __launch_bounds__(256) void matvec_all_kernel(
    const float* __restrict__ Wpp, const float* __restrict__ aspp, const float* __restrict__ adpp,
    const float* __restrict__ Wdp, const float* __restrict__ asdp, const float* __restrict__ addp,
    const float* __restrict__ Wcp, const float* __restrict__ ascp, const float* __restrict__ adcp,
    float* __restrict__ wv) {
  int b = blockIdx.x;
  int l = b / 6, r = b - l * 6, type = r >> 1, isd = r & 1;
  const float* W = (type == 0 ? Wpp : type == 1 ? Wdp : Wcp) + (size_t)l * HDIM * HDIM;
  const float* a = (type == 0 ? (isd ? adpp : aspp)
                  : type == 1 ? (isd ? addp : asdp)
                              : (isd ? adcp : ascp)) + (size_t)l * HDIM;
  int k = threadIdx.x;
  const float4* Wr = (const float4*)(W + (size_t)k * HDIM);
  float s = 0.f;
#pragma unroll 8
  for (int n4 = 0; n4 < HDIM / 4; ++n4) {
    float4 w = Wr[n4];
    float4 av = *(const float4*)(a + n4 * 4);
    s += w.x * av.x + w.y * av.y + w.z * av.z + w.w * av.w;
  }
  wv[(size_t)b * HDIM + k] = s;
}

// weight conversion + protein prep in ONE launch (both independent of the
// matvec launch's wv EXCEPT prep_p's dots -- so matvec runs FIRST, then this
// merged kernel; still saves one launch vs the round-17 trio).
__global__ __launch_bounds__(256) void wconv_prep_kernel(
    const float* __restrict__ Wpp, const float* __restrict__ Wdp, const float* __restrict__ Wcp,
    ushort* __restrict__ WTpph, ushort* __restrict__ WTppl,
    ushort* __restrict__ WTdph, ushort* __restrict__ WTdpl,
    ushort* __restrict__ WTcph, ushort* __restrict__ WTcpl, int L,
    const float* __restrict__ pe, ushort* __restrict__ Xpb,
    const float* __restrict__ a1, const float* __restrict__ a2,
    float* __restrict__ o1, float* __restrict__ o2, int np, int c1) {
  const int per = HDIM * HDIM;
  int blk = blockIdx.x;
  if (blk < c1) {                        // ---- wconv_split3 body
    int i = blk * 256 + threadIdx.x;
    if (i >= 3 * L * per) return;
    int mat = i / per;
    int r = i - mat * per;
    int l = mat / 3, ty = mat - l * 3;
    const float* W = (ty == 0 ? Wpp : ty == 1 ? Wdp : Wcp) + (size_t)l * per;
    ushort* Th = (ty == 0 ? WTpph : ty == 1 ? WTdph : WTcph) + (size_t)l * per;
    ushort* Tl = (ty == 0 ? WTppl : ty == 1 ? WTdpl : WTcpl) + (size_t)l * per;
    int k = r >> 8, n = r & (HDIM - 1);  // r = k*HDIM + n
    uint p = f2pl(W[r]);
    Th[(size_t)n * HDIM + k] = (ushort)(p & 0xffff);
    Tl[(size_t)n * HDIM + k] = (ushort)(p >> 16);
    return;
  }
  // ---- prep_p body (bf16 copy + two pp rowdots vs folded vectors a1,a2)
  int row = (blk - c1) * 4 + (threadIdx.x >> 6);
  if (row >= np) return;
  int lane = threadIdx.x & 63;
  float s1 = 0.f, s2 = 0.f;
#pragma unroll
  for (int u = 0; u < 4; ++u) {
    int c = lane + u * 64;
    float hv = pe[(size_t)row * HDIM + c];
    Xpb[(size_t)row * HDIM + c] = f2b(hv);
    s1 += hv * a1[c];
    s2 += hv * a2[c];
  }
#pragma unroll
  for (int off = 32; off; off >>= 1) {
    s1 += __shfl_down(s1, off);
    s2 += __shfl_down(s2, off);
  }
  if (lane == 0) { o1[row] = s1; o2[row] = s2; }
}

// h1 combine -> split planes (P3 carries bias b1), PLUS optional b3-prefill
// segment for the logits buffer (independent of combine; both precede W2).
__global__ __launch_bounds__(256) void combine_h1_fill_kernel(
    const float* __restrict__ P1, const float* __restrict__ P2, const float* __restrict__ P3,
    const int* __restrict__ g1, const int* __restrict__ g2, const int* __restrict__ g3,
    int row0, ushort* __restrict__ h1h, ushort* __restrict__ h1l, int M, int K,
    float* __restrict__ outp, const float* __restrict__ b3, int Bn, int bsC) {
  if (blockIdx.x >= bsC) {               // fill segment
    int i = (blockIdx.x - bsC) * 256 + threadIdx.x;
    if (i < Bn) {
      outp[(size_t)i * 2 + 0] = b3[0];
      outp[(size_t)i * 2 + 1] = b3[1];
    }
    return;
  }
  int t = blockIdx.x * 256 + threadIdx.x;
  int kq = K >> 2;
  if (t >= M * kq) return;
  int row = t / kq, c4 = t - row * kq;
  int bi = row0 + row;
  size_t o = (size_t)c4 * 4;
  float4 a = *(const float4*)(P1 + (size_t)g1[bi] * K + o);
  float4 b = *(const float4*)(P2 + (size_t)g2[bi] * K + o);
  float4 c = *(const float4*)(P3 + (size_t)g3[bi] * K + o);
  uint p0 = f2pl(fmaxf(a.x + b.x + c.x, 0.f));
  uint p1 = f2pl(fmaxf(a.y + b.y + c.y, 0.f));
  uint p2 = f2pl(fmaxf(a.z + b.z + c.z, 0.f));
  uint p3 = f2pl(fmaxf(a.w + b.w + c.w, 0.f));
  ushort4 h = {(ushort)(p0 & 0xffff), (ushort)(p1 & 0xffff), (ushort)(p2 & 0xffff), (ushort)(p3 & 0xffff)};
  ushort4 l = {(ushort)(p0 >> 16), (ushort)(p1 >> 16), (ushort)(p2 >> 16), (ushort)(p3 >> 16)};
  *(ushort4*)(h1h + (size_t)row * K + o) = h;
  *(ushort4*)(h1l + (size_t)row * K + o) = l;
}

// ---------------------------------------------------------------- MFMA GEMM
// ROUND-10 PROVEN STRUCTURE. See prior rounds for full rationale.
template <int TBM_>
struct GemmSmem {
  ushort Ah[2][4][TBM_ / 16][16][8];
  ushort Al[2][4][TBM_ / 16][16][8];
  ushort Bh[2][4][TBN / 16][16][8];
  ushort Bl[2][4][TBN / 16][16][8];
};

template <int TBM_, int ACT, int FUSE3>
__device__ __forceinline__ void gemm_body(
    GemmSmem<TBM_>& sm,
    const ushort* __restrict__ Ahg, const ushort* __restrict__ Alg,
    const ushort* __restrict__ Bhg, const ushort* __restrict__ Blg,
    int ldb, const float* __restrict__ bias, const float* __restrict__ W3g,
    float* __restrict__ C, int M, int N, int K, int mb, int nb) {
  constexpr int NU = TBM_ / 64;   // A 16B-load instrs per thread (64 rows/round)
  constexpr int TM = TBM_ / 32;   // 16-row tiles per wave (M dir)

  const int tid = threadIdx.x;
  const int lane = tid & 63;
  const int wid = tid >> 6;
  const int wm = wid & 1, wn = wid >> 1;
  const int l16 = lane & 15;
  const int quad = lane >> 4;
  const int m0 = mb * TBM_;
  const int n0 = nb * TBN;

  const int gq = lane & 3;         // k-granule (8 ushorts = 16B) this lane stages
  const int co = gq * 8;           // ushort col within 32-ushort k-chunk
  const int r4 = lane >> 2;        // row within 16-row stripe
  const int wslot = (r4 + 2 * gq) & 15;          // rotated write slot
  const int rslot = (l16 + 2 * quad) & 15;       // rotated read slot

  uint4 rah0[NU], ral0[NU], rbh0, rbl0;   // register set 0
  uint4 rah1[NU], ral1[NU], rbh1, rbl1;   // register set 1

  auto LOADA = [&](uint4* rah, uint4* ral, uint4& rbh, uint4& rbl, int k0) {
#pragma unroll
    for (int u = 0; u < NU; ++u) {
      int r = wid * (TBM_ / 4) + r4 + 16 * u;
      int gm = m0 + r;
      if (gm < M) {
        size_t o = (size_t)gm * K + k0 + co;
        rah[u] = *(const uint4*)(Ahg + o);
        ral[u] = *(const uint4*)(Alg + o);
      } else {
        rah[u] = make_uint4(0, 0, 0, 0);
        ral[u] = make_uint4(0, 0, 0, 0);
      }
    }
    {
      int r = wid * 16 + r4;
      size_t o = (size_t)(n0 + r) * ldb + k0 + co;
      rbh = *(const uint4*)(Bhg + o);
      rbl = *(const uint4*)(Blg + o);
    }
  };
  auto STORE = [&](const uint4* rah, const uint4* ral, const uint4& rbh, const uint4& rbl, int b) {
#pragma unroll
    for (int u = 0; u < NU; ++u) {
      int ch = (wid * (TBM_ / 4) + 16 * u) >> 4;   // row chunk (r4 < 16)
      *(uint4*)&sm.Ah[b][gq][ch][wslot][0] = rah[u];
      *(uint4*)&sm.Al[b][gq][ch][wslot][0] = ral[u];
    }
    *(uint4*)&sm.Bh[b][gq][wid][wslot][0] = rbh;
    *(uint4*)&sm.Bl[b][gq][wid][wslot][0] = rbl;
  };

  f32x4 acc[TM][2];
#pragma unroll
  for (int i = 0; i < TM; ++i)
#pragma unroll
    for (int j = 0; j < 2; ++j) acc[i][j] = (f32x4){0.f, 0.f, 0.f, 0.f};

  auto COMPUTE = [&](int b) {
    bf16x8 ahf[TM], alf[TM], bhf[2], blf[2];
#pragma unroll
    for (int t = 0; t < TM; ++t) {
      int ch = wm * (TBM_ / 32) + t;
      ahf[t] = *(const bf16x8*)&sm.Ah[b][quad][ch][rslot][0];
      alf[t] = *(const bf16x8*)&sm.Al[b][quad][ch][rslot][0];
    }
#pragma unroll
    for (int t = 0; t < 2; ++t) {
      int ch = wn * 2 + t;
      bhf[t] = *(const bf16x8*)&sm.Bh[b][quad][ch][rslot][0];
      blf[t] = *(const bf16x8*)&sm.Bl[b][quad][ch][rslot][0];
    }
#pragma unroll
    for (int tm = 0; tm < TM; ++tm)
#pragma unroll
      for (int tn = 0; tn < 2; ++tn) {
        acc[tm][tn] = __builtin_amdgcn_mfma_f32_16x16x32_bf16(ahf[tm], bhf[tn], acc[tm][tn], 0, 0, 0);
        acc[tm][tn] = __builtin_amdgcn_mfma_f32_16x16x32_bf16(ahf[tm], blf[tn], acc[tm][tn], 0, 0, 0);
        acc[tm][tn] = __builtin_amdgcn_mfma_f32_16x16x32_bf16(alf[tm], bhf[tn], acc[tm][tn], 0, 0, 0);
      }
  };

  // prologue: tiles t0,t1 in regs; t0 -> buf0
  const int NK = K / TBK;            // even, >= 4 for all shapes used
  LOADA(rah0, ral0, rbh0, rbl0, 0);
  LOADA(rah1, ral1, rbh1, rbl1, TBK);
  STORE(rah0, ral0, rbh0, rbl0, 0);
  int k = 2 * TBK;
  for (int t = 0; t < (NK - 2) / 2; ++t) {
    __syncthreads();
    LOADA(rah0, ral0, rbh0, rbl0, k);   // t+2 in flight
    COMPUTE(0);                          // tile t (buf0)
    STORE(rah1, ral1, rbh1, rbl1, 1);    // t+1 -> buf1
    k += TBK;
    __syncthreads();
    LOADA(rah1, ral1, rbh1, rbl1, k);
    COMPUTE(1);
    STORE(rah0, ral0, rbh0, rbl0, 0);
    k += TBK;
  }
  __syncthreads();
  COMPUTE(0);
  STORE(rah1, ral1, rbh1, rbl1, 1);
  __syncthreads();
  COMPUTE(1);

  if (FUSE3) {
    // relu(acc+bias) . W3 -> per-row (s0,s1); reduce over the 16 l16 lanes
    // sharing a row; leader atomicAdds into b3-prefilled C[M][2].
#pragma unroll
    for (int tm = 0; tm < TM; ++tm) {
#pragma unroll
      for (int r = 0; r < 4; ++r) {
        int row = m0 + wm * (TBM_ / 2) + tm * 16 + quad * 4 + r;
        float s0 = 0.f, s1 = 0.f;
#pragma unroll
        for (int tn = 0; tn < 2; ++tn) {
          int col = n0 + wn * 32 + tn * 16 + l16;
          float v = fmaxf(acc[tm][tn][r] + bias[col], 0.f);
          s0 += v * W3g[col * 2 + 0];
          s1 += v * W3g[col * 2 + 1];
        }
#pragma unroll
        for (int o = 1; o < 16; o <<= 1) {
          s0 += __shfl_xor(s0, o);
          s1 += __shfl_xor(s1, o);
        }
        if (l16 == 0 && row < M) {
          atomicAdd(&C[(size_t)row * 2 + 0], s0);
          atomicAdd(&C[(size_t)row * 2 + 1], s1);
        }
      }
    }
  } else {
#pragma unroll
    for (int tn = 0; tn < 2; ++tn) {
      int col = n0 + wn * 32 + tn * 16 + l16;
      float bv = bias ? bias[col] : 0.f;
#pragma unroll
      for (int tm = 0; tm < TM; ++tm) {
#pragma unroll
        for (int r = 0; r < 4; ++r) {
          int row = m0 + wm * (TBM_ / 2) + tm * 16 + quad * 4 + r;
          if (row >= M) continue;
          float v = acc[tm][tn][r] + bv;
          if (ACT == 1) v = fmaxf(v, 0.f);
          C[(size_t)row * N + col] = v;
        }
      }
    }
  }
}

template <int TBM_, int ACT, int FUSE3>
__global__ __launch_bounds__(256) void mfma_gemm(
    const ushort* __restrict__ Ahg, const ushort* __restrict__ Alg,
    const ushort* __restrict__ Bhg, const ushort* __restrict__ Blg,
    int ldb, const float* __restrict__ bias, const float* __restrict__ W3g,
    float* __restrict__ C, int M, int N, int K) {
  __shared__ GemmSmem<TBM_> sm;
  gemm_body<TBM_, ACT, FUSE3>(sm, Ahg, Alg, Bhg, Blg, ldb, bias, W3g, C, M, N, K,
                              blockIdx.x, blockIdx.y);
}

// up-to-3-way segmented GEMM: flat grid, per-segment params, M-fast mapping
struct GArg {
  const ushort* Ah; const ushort* Al; const ushort* Bh; const ushort* Bl;
  const float* bias; float* C;
  int ldb; int M; int N; int K; int mblk;
};

template <int TBM_, int ACT>
__global__ __launch_bounds__(256) void mfma_gemm_seg3(
    GArg g0, GArg g1, GArg g2, int b1, int b2) {
  __shared__ GemmSmem<TBM_> sm;
  int bid = blockIdx.x;
  if (bid < b1) {
    gemm_body<TBM_, ACT, 0>(sm, g0.Ah, g0.Al, g0.Bh, g0.Bl, g0.ldb, g0.bias, nullptr,
                            g0.C, g0.M, g0.N, g0.K, bid % g0.mblk, bid / g0.mblk);
  } else if (bid < b2) {
    int t = bid - b1;
    gemm_body<TBM_, ACT, 0>(sm, g1.Ah, g1.Al, g1.Bh, g1.Bl, g1.ldb, g1.bias, nullptr,
                            g1.C, g1.M, g1.N, g1.K, t % g1.mblk, t / g1.mblk);
  } else {
    int t = bid - b2;
    gemm_body<TBM_, ACT, 0>(sm, g2.Ah, g2.Al, g2.Bh, g2.Bl, g2.ldb, g2.bias, nullptr,
                            g2.C, g2.M, g2.N, g2.K, t % g2.mblk, t / g2.mblk);
  }
}

template <int TBM_, int ACT>
static void gemm_launch(hipStream_t s,
                        const ushort* Ahg, const ushort* Alg,
                        const ushort* Bhg, const ushort* Blg,
                        int ldb, const float* bias, float* C,
                        int M, int N, int K) {
  dim3 g(cdiv(M, TBM_), N / TBN);   // M fast: XCD-local A-panel reuse
  mfma_gemm<TBM_, ACT, 0><<<g, 256, 0, s>>>(Ahg, Alg, Bhg, Blg, ldb, bias, nullptr, C, M, N, K);
}

static void gemm_launch_f3(hipStream_t s,
                           const ushort* Ahg, const ushort* Alg,
                           const ushort* Bhg, const ushort* Blg,
                           int ldb, const float* bias, const float* W3,
                           float* C, int M, int N, int K) {
  dim3 g(cdiv(M, 128), N / TBN);
  mfma_gemm<128, 1, 1><<<g, 256, 0, s>>>(Ahg, Alg, Bhg, Blg, ldb, bias, W3, C, M, N, K);
}

// ---------------------------------------------------------------- counting sort by dst
__global__ __launch_bounds__(256) void hist_kernel(
    const int* __restrict__ src, const int* __restrict__ dst, int E, int nloops,
    int Nd, int* __restrict__ offs) {
  extern __shared__ int bins[];
  int tot = E + nloops;
  int chunk = (tot + NB - 1) / NB;
  int b = blockIdx.x;
  int s0 = b * chunk, s1 = min(s0 + chunk, tot);
  for (int i = threadIdx.x; i < Nd; i += 256) bins[i] = 0;
  __syncthreads();
  for (int i = s0 + threadIdx.x; i < s1; i += 256) {
    int d = (i < E) ? dst[i] : (i - E);
    atomicAdd(&bins[d], 1);
  }
  __syncthreads();
  for (int i = threadIdx.x; i < Nd; i += 256) offs[(size_t)i * NB + b] = bins[i];
}

__global__ __launch_bounds__(256) void scan_bins_kernel(
    int* __restrict__ offs, int* __restrict__ binsum, int Nd) {
  int d = blockIdx.x * 4 + (threadIdx.x >> 6);
  if (d >= Nd) return;
  int lane = threadIdx.x & 63;
  int* p = offs + (size_t)d * NB;
  int v0 = p[2 * lane], v1 = p[2 * lane + 1];
  int s = v0 + v1;
  int t = s;
#pragma unroll
  for (int o = 1; o < 64; o <<= 1) { int u = __shfl_up(t, o); if (lane >= o) t += u; }
  int excl = t - s;
  p[2 * lane] = excl;
  p[2 * lane + 1] = excl + v0;
  if (lane == 63) binsum[d] = t;
}

__global__ __launch_bounds__(256) void scan_base_kernel(
    const int* __restrict__ binsum, int* __restrict__ rowptr, int Nd) {
  __shared__ int wsum[4];
  __shared__ int carry;
  if (threadIdx.x == 0) carry = 0;
  __syncthreads();
  int lane = threadIdx.x & 63, w = threadIdx.x >> 6;
  for (int t0 = 0; t0 < Nd; t0 += 256) {
    int i = t0 + threadIdx.x;
    int v = (i < Nd) ? binsum[i] : 0;
    int t = v;
#pragma unroll
    for (int o = 1; o < 64; o <<= 1) { int u = __shfl_up(t, o); if (lane >= o) t += u; }
    if (lane == 63) wsum[w] = t;
    __syncthreads();
    int add = carry;
    for (int k = 0; k < w; ++k) add += wsum[k];
    if (i < Nd) rowptr[i] = t - v + add;
    __syncthreads();
    if (threadIdx.x == 0) carry += wsum[0] + wsum[1] + wsum[2] + wsum[3];
    __syncthreads();
  }
  if (threadIdx.x == 0) rowptr[Nd] = carry;
}

__global__ __launch_bounds__(256) void scatter_kernel(
    const int* __restrict__ src, const int* __restrict__ dst, int E, int nloops,
    int Nd, const int* __restrict__ offs, const int* __restrict__ rowptr,
    uint* __restrict__ sd) {
  extern __shared__ int bins[];
  int tot = E + nloops;
  int chunk = (tot + NB - 1) / NB;
  int b = blockIdx.x;
  int s0 = b * chunk, s1 = min(s0 + chunk, tot);
  for (int i = threadIdx.x; i < Nd; i += 256) bins[i] = 0;
  __syncthreads();
  for (int i = s0 + threadIdx.x; i < s1; i += 256) {
    int s_, d_;
    if (i < E) { s_ = src[i]; d_ = dst[i]; }
    else       { s_ = d_ = i - E; }
    int local = atomicAdd(&bins[d_], 1);
    int pos = rowptr[d_] + offs[(size_t)d_ * NB + b] + local;
    sd[pos] = (uint)s_ | ((uint)d_ << 16);
  }
}

// ---------------------------------------------------------------- fused GAT edge phase
// pp aggregator (wave per dst) PLUS dp/cp rowdots PLUS out32 zeroing, ONE
// launch: the rowdot/zero segments read the PREVIOUS layer's Xd/Xc and the
// precomputed wv -- independent of the pp aggregation segment.
__global__ __launch_bounds__(256) void agg_pp_rdz_kernel(
    const int* __restrict__ rowptr, const uint* __restrict__ sd,
    const float* __restrict__ als, const float* __restrict__ ald,
    const ushort* __restrict__ Xb,
    ushort* __restrict__ aggh, ushort* __restrict__ aggl, int n,
    const float* __restrict__ Hd, const float* __restrict__ ad, float* __restrict__ od, int nd,
    const float* __restrict__ Hc, const float* __restrict__ ac, float* __restrict__ oc, int nc,
    float* __restrict__ z, int nz, int bsA, int bs1, int bs2) {
  int blk = blockIdx.x;
  if (blk >= bsA) {
    int b = blk - bsA;
    if (b >= bs2) {                      // zero segment
      int i = (b - bs2) * 256 + threadIdx.x;
      if (i < nz) z[i] = 0.f;
      return;
    }
    const float* H; const float* a; float* o; int nn; int row;
    if (b < bs1) { H = Hd; a = ad; o = od; nn = nd; row = b * 4 + (threadIdx.x >> 6); }
    else         { H = Hc; a = ac; o = oc; nn = nc; row = (b - bs1) * 4 + (threadIdx.x >> 6); }
    if (row >= nn) return;
    int lane = threadIdx.x & 63;
    const float* h = H + (size_t)row * HDIM;
    float s = 0.f;
#pragma unroll
    for (int u = 0; u < 4; ++u) {
      int c = lane + u * 64;
      s += h[c] * a[c];
    }
#pragma unroll
    for (int off = 32; off; off >>= 1) s += __shfl_down(s, off);
    if (lane == 0) o[row] = s;
    return;
  }
  // ---- pp: gat_agg_split body
  int d = blk * 4 + (threadIdx.x >> 6);
  if (d >= n) return;
  int lane = threadIdx.x & 63;
  int r0 = rowptr[d], r1 = rowptr[d + 1];
  float aldd = ald[d];
  float dsum = 0.f;
  for (int j = r0 + lane; j < r1; j += 64) {
    float e = als[sd[j] & 0xffff] + aldd;
    e = (e > 0.f) ? e : NEG_SLOPE * e;
    dsum += __expf(e);
  }
#pragma unroll
  for (int o = 32; o; o >>= 1) dsum += __shfl_xor(dsum, o);
  float rden = 1.f / (dsum + 1e-16f);

  float4 acc = make_float4(0.f, 0.f, 0.f, 0.f);
  for (int b = r0; b < r1; b += 64) {
    int j = b + lane;
    float exv = 0.f; int srcv = 0;
    if (j < r1) {
      uint p = sd[j];
      srcv = p & 0xffff;
      float e = als[srcv] + aldd;
      e = (e > 0.f) ? e : NEG_SLOPE * e;
      exv = __expf(e) * rden;
    }
    int cnt = min(64, r1 - b);
    for (int t0 = 0; t0 < cnt; t0 += 8) {
      float cf[8]; int sv[8];
#pragma unroll
      for (int u = 0; u < 8; ++u) {
        cf[u] = __shfl(exv, t0 + u);
        sv[u] = __shfl(srcv, t0 + u);
      }
      ushort4 hv[8];
#pragma unroll
      for (int u = 0; u < 8; ++u)
        hv[u] = *(const ushort4*)(Xb + (size_t)sv[u] * HDIM + lane * 4);
#pragma unroll
      for (int u = 0; u < 8; ++u) {
        acc.x += cf[u] * b2f(hv[u].x);
        acc.y += cf[u] * b2f(hv[u].y);
        acc.z += cf[u] * b2f(hv[u].z);
        acc.w += cf[u] * b2f(hv[u].w);
      }
    }
  }
  uint p0 = f2pl(acc.x), p1 = f2pl(acc.y), p2 = f2pl(acc.z), p3 = f2pl(acc.w);
  ushort4 h = {(ushort)(p0 & 0xffff), (ushort)(p1 & 0xffff), (ushort)(p2 & 0xffff), (ushort)(p3 & 0xffff)};
  ushort4 l = {(ushort)(p0 >> 16), (ushort)(p1 >> 16), (ushort)(p2 >> 16), (ushort)(p3 >> 16)};
  *(ushort4*)(aggh + (size_t)d * HDIM + lane * 4) = h;
  *(ushort4*)(aggl + (size_t)d * HDIM + lane * 4) = l;
}

// dp aggregate + cp slice-aggregate in ONE launch (proven round-15 kernel)
__global__ __launch_bounds__(256) void agg_dp_cp_kernel(
    const int* __restrict__ rp_d, const uint* __restrict__ sd_d,
    const float* __restrict__ als_d, const float* __restrict__ ald_d,
    ushort* __restrict__ aggh, ushort* __restrict__ aggl, int nd, int bsplit,
    const int* __restrict__ rp_c, const uint* __restrict__ sd_c,
    const float* __restrict__ als_c, const float* __restrict__ ald_c,
    float* __restrict__ out32, int nc, const ushort* __restrict__ Xb) {
  __shared__ float wd[4];
  if (blockIdx.x < bsplit) {
    // ---- dp: gat_agg_split body
    int d = blockIdx.x * 4 + (threadIdx.x >> 6);
    if (d >= nd) return;
    int lane = threadIdx.x & 63;
    int r0 = rp_d[d], r1 = rp_d[d + 1];
    float aldd = ald_d[d];
    float dsum = 0.f;
    for (int j = r0 + lane; j < r1; j += 64) {
      float e = als_d[sd_d[j] & 0xffff] + aldd;
      e = (e > 0.f) ? e : NEG_SLOPE * e;
      dsum += __expf(e);
    }
#pragma unroll
    for (int o = 32; o; o >>= 1) dsum += __shfl_xor(dsum, o);
    float rden = 1.f / (dsum + 1e-16f);

    float4 acc = make_float4(0.f, 0.f, 0.f, 0.f);
    for (int b = r0; b < r1; b += 64) {
      int j = b + lane;
      float exv = 0.f; int srcv = 0;
      if (j < r1) {
        uint p = sd_d[j];
        srcv = p & 0xffff;
        float e = als_d[srcv] + aldd;
        e = (e > 0.f) ? e : NEG_SLOPE * e;
        exv = __expf(e) * rden;
      }
      int cnt = min(64, r1 - b);
      for (int t0 = 0; t0 < cnt; t0 += 8) {
        float cf[8]; int sv[8];
#pragma unroll
        for (int u = 0; u < 8; ++u) {
          cf[u] = __shfl(exv, t0 + u);
          sv[u] = __shfl(srcv, t0 + u);
        }
        ushort4 hv[8];
#pragma unroll
        for (int u = 0; u < 8; ++u)
          hv[u] = *(const ushort4*)(Xb + (size_t)sv[u] * HDIM + lane * 4);
#pragma unroll
        for (int u = 0; u < 8; ++u) {
          acc.x += cf[u] * b2f(hv[u].x);
          acc.y += cf[u] * b2f(hv[u].y);
          acc.z += cf[u] * b2f(hv[u].z);
          acc.w += cf[u] * b2f(hv[u].w);
        }
      }
    }
    uint p0 = f2pl(acc.x), p1 = f2pl(acc.y), p2 = f2pl(acc.z), p3 = f2pl(acc.w);
    ushort4 h = {(ushort)(p0 & 0xffff), (ushort)(p1 & 0xffff), (ushort)(p2 & 0xffff), (ushort)(p3 & 0xffff)};
    ushort4 l = {(ushort)(p0 >> 16), (ushort)(p1 >> 16), (ushort)(p2 >> 16), (ushort)(p3 >> 16)};
    *(ushort4*)(aggh + (size_t)d * HDIM + lane * 4) = h;
    *(ushort4*)(aggl + (size_t)d * HDIM + lane * 4) = l;
  } else {
    // ---- cp: gat_agg_slice body (atomicAdd partials into pre-zeroed out32)
    int bb = blockIdx.x - bsplit;
    int d = bb / SLICES;
    int sl = bb - d * SLICES;
    if (d >= nc) return;
    int lane = threadIdx.x & 63, w = threadIdx.x >> 6;
    int r0 = rp_c[d], r1 = rp_c[d + 1];
    float aldd = ald_c[d];
    float dsum = 0.f;
    for (int j = r0 + threadIdx.x; j < r1; j += 256) {
      float e = als_c[sd_c[j] & 0xffff] + aldd;
      e = (e > 0.f) ? e : NEG_SLOPE * e;
      dsum += __expf(e);
    }
#pragma unroll
    for (int o = 32; o; o >>= 1) dsum += __shfl_xor(dsum, o);
    if (lane == 0) wd[w] = dsum;
    __syncthreads();
    float rden = 1.f / (wd[0] + wd[1] + wd[2] + wd[3] + 1e-16f);
    int deg = r1 - r0;
    int per_b = (deg + SLICES - 1) / SLICES;
    int b0 = r0 + sl * per_b, b1 = min(b0 + per_b, r1);
    int wdeg = b1 - b0;
    if (wdeg <= 0) return;
    int per_w = (wdeg + 3) >> 2;
    int w0 = b0 + w * per_w, w1 = min(w0 + per_w, b1);

    float4 acc = make_float4(0.f, 0.f, 0.f, 0.f);
    for (int b = w0; b < w1; b += 64) {
      int j = b + lane;
      float exv = 0.f; int srcv = 0;
      if (j < w1) {
        uint p = sd_c[j];
        srcv = p & 0xffff;
        float e = als_c[srcv] + aldd;
        e = (e > 0.f) ? e : NEG_SLOPE * e;
        exv = __expf(e) * rden;
      }
      int cnt = min(64, w1 - b);
      for (int t0 = 0; t0 < cnt; t0 += 8) {
        float cf[8]; int sv[8];
#pragma unroll
        for (int u = 0; u < 8; ++u) {
          cf[u] = __shfl(exv, t0 + u);
          sv[u] = __shfl(srcv, t0 + u);
        }
        ushort4 hv[8];
#pragma unroll
        for (int u = 0; u < 8; ++u)
          hv[u] = *(const ushort4*)(Xb + (size_t)sv[u] * HDIM + lane * 4);
#pragma unroll
        for (int u = 0; u < 8; ++u) {
          acc.x += cf[u] * b2f(hv[u].x);
          acc.y += cf[u] * b2f(hv[u].y);
          acc.z += cf[u] * b2f(hv[u].z);
          acc.w += cf[u] * b2f(hv[u].w);
        }
      }
    }
    float* o = out32 + (size_t)d * HDIM + lane * 4;
    atomicAdd(o + 0, acc.x); atomicAdd(o + 1, acc.y);
    atomicAdd(o + 2, acc.z); atomicAdd(o + 3, acc.w);
  }
}

__global__ void f32_to_split_kernel(const float* __restrict__ in,
                                    ushort* __restrict__ oh, ushort* __restrict__ ol, int n) {
  int i = blockIdx.x * 256 + threadIdx.x;
  if (i >= n) return;
  uint p = f2pl(in[i]);
  oh[i] = (ushort)(p & 0xffff);
  ol[i] = (ushort)(p >> 16);
}

// ---------------------------------------------------------------- norms
__global__ __launch_bounds__(256) void l2norm_f32b_dots_kernel(
    const float* __restrict__ in, float* __restrict__ outf, ushort* __restrict__ outb,
    const float* __restrict__ v1, const float* __restrict__ v2,
    const float* __restrict__ v3, const float* __restrict__ v4,
    float* __restrict__ o1, float* __restrict__ o2,
    float* __restrict__ o3, float* __restrict__ o4, int n) {
  int row = blockIdx.x * 4 + (threadIdx.x >> 6);
  if (row >= n) return;
  int lane = threadIdx.x & 63;
  float v[4];
  float ss = 0.f;
#pragma unroll
  for (int u = 0; u < 4; ++u) {
    float t = in[(size_t)row * HDIM + lane + u * 64];
    v[u] = t; ss += t * t;
  }
#pragma unroll
  for (int off = 32; off; off >>= 1) ss += __shfl_xor(ss, off);
  float sc = 1.0f / fmaxf(sqrtf(ss), 1e-12f);
  float d1 = 0.f, d2 = 0.f, d3 = 0.f, d4 = 0.f;
#pragma unroll
  for (int u = 0; u < 4; ++u) {
    float f = v[u] * sc;
    int c = lane + u * 64;
    outf[(size_t)row * HDIM + c] = f;
    outb[(size_t)row * HDIM + c] = f2b(f);
    d1 += f * v1[c];
    d2 += f * v2[c];
    if (o3) { d3 += f * v3[c]; d4 += f * v4[c]; }
  }
#pragma unroll
  for (int off = 32; off; off >>= 1) {
    d1 += __shfl_xor(d1, off);
    d2 += __shfl_xor(d2, off);
    if (o3) { d3 += __shfl_xor(d3, off); d4 += __shfl_xor(d4, off); }
  }
  if (lane == 0) {
    o1[row] = d1; o2[row] = d2;
    if (o3) { o3[row] = d3; o4[row] = d4; }
  }
}

// head prep, ONE launch: l2norm-split of drug + cell tables, plus the two
// head weight conversions (W1, W2). All four segments independent.
__global__ __launch_bounds__(256) void head_prep_kernel(
    const float* __restrict__ Xd, ushort* __restrict__ dh, ushort* __restrict__ dl, int nd,
    const float* __restrict__ Xc, ushort* __restrict__ ch, ushort* __restrict__ cl, int nc,
    const float* __restrict__ W1, ushort* __restrict__ W1h, ushort* __restrict__ W1l,
    int K1, int N1_,
    const float* __restrict__ W2, ushort* __restrict__ W2h, ushort* __restrict__ W2l,
    int N2_, int bs1, int bs2, int bs3) {
  int b = blockIdx.x;
  if (b >= bs3) {                        // wconv W2: [N1_][N2_] -> [N2_][N1_]
    int i = (b - bs3) * 256 + threadIdx.x;
    if (i >= N1_ * N2_) return;
    int k = i / N2_, n = i - k * N2_;
    uint p = f2pl(W2[i]);
    W2h[(size_t)n * N1_ + k] = (ushort)(p & 0xffff);
    W2l[(size_t)n * N1_ + k] = (ushort)(p >> 16);
    return;
  }
  if (b >= bs2) {                        // wconv W1: [K1][N1_] -> [N1_][K1]
    int i = (b - bs2) * 256 + threadIdx.x;
    if (i >= K1 * N1_) return;
    int k = i / N1_, n = i - k * N1_;
    uint p = f2pl(W1[i]);
    W1h[(size_t)n * K1 + k] = (ushort)(p & 0xffff);
    W1l[(size_t)n * K1 + k] = (ushort)(p >> 16);
    return;
  }
  // l2norm-split segments (drug rows then cell rows)
  const float* in; ushort* oh; ushort* ol; int n; int row;
  if (b < bs1) { in = Xd; oh = dh; ol = dl; n = nd; row = b * 4 + (threadIdx.x >> 6); }
  else         { in = Xc; oh = ch; ol = cl; n = nc; row = (b - bs1) * 4 + (threadIdx.x >> 6); }
  if (row >= n) return;
  int lane = threadIdx.x & 63;
  float v[4];
  float ss = 0.f;
#pragma unroll
  for (int u = 0; u < 4; ++u) {
    int c = lane + u * 64;
    float t = in[(size_t)row * HDIM + c];
    v[u] = t;
    ss += t * t;
  }
#pragma unroll
  for (int off = 32; off; off >>= 1) ss += __shfl_xor(ss, off);
  float sc = 1.0f / fmaxf(sqrtf(ss), 1e-12f);
#pragma unroll
  for (int u = 0; u < 4; ++u) {
    int c = lane + u * 64;
    uint p = f2pl(v[u] * sc);
    oh[(size_t)row * HDIM + c] = (ushort)(p & 0xffff);
    ol[(size_t)row * HDIM + c] = (ushort)(p >> 16);
  }
}

// ---------------------------------------------------------------- host side
static void build_sorted(hipStream_t stream,
                         const int* src, const int* dst, int E, int nloops, int Nd,
                         int* offs, int* binsum, int* rowptr, uint* sd) {
  size_t lds = (size_t)Nd * sizeof(int);
  hist_kernel<<<NB, 256, lds, stream>>>(src, dst, E, nloops, Nd, offs);
  scan_bins_kernel<<<cdiv(Nd, 4), 256, 0, stream>>>(offs, binsum, Nd);
  scan_base_kernel<<<1, 256, 0, stream>>>(binsum, rowptr, Nd);
  scatter_kernel<<<NB, 256, lds, stream>>>(src, dst, E, nloops, Nd, offs, rowptr, sd);
}

extern "C" void kernel_launch(void* const* d_in, const int* in_sizes, int n_in,
                              void* d_out, int out_size, void* d_ws, size_t ws_size,
                              hipStream_t stream) {
  const float* drug_emb = (const float*)d_in[0];
  const float* prot_emb = (const float*)d_in[1];
  const float* cell_emb = (const float*)d_in[2];
  const float* W_pp = (const float*)d_in[3];
  const float* as_pp = (const float*)d_in[4];
  const float* ad_pp = (const float*)d_in[5];
  const float* b_pp = (const float*)d_in[6];
  const float* W_dp = (const float*)d_in[7];
  const float* as_dp = (const float*)d_in[8];
  const float* ad_dp = (const float*)d_in[9];
  const float* b_dp = (const float*)d_in[10];
  const float* W_cp = (const float*)d_in[11];
  const float* as_cp = (const float*)d_in[12];
  const float* ad_cp = (const float*)d_in[13];
  const float* b_cp = (const float*)d_in[14];
  const float* W1 = (const float*)d_in[15];
  const float* b1 = (const float*)d_in[16];
  const float* W2 = (const float*)d_in[17];
  const float* b2 = (const float*)d_in[18];
  const float* W3 = (const float*)d_in[19];
  const float* b3 = (const float*)d_in[20];
  const int* edge_pp = (const int*)d_in[21];
  const int* edge_dp = (const int*)d_in[22];
  const int* edge_cp = (const int*)d_in[23];
  const int* drug1 = (const int*)d_in[24];
  const int* drug2 = (const int*)d_in[25];
  const int* cellb = (const int*)d_in[26];

  const int ND = in_sizes[0] / HDIM;   // 2000
  const int NP = in_sizes[1] / HDIM;   // 19000
  const int NC = in_sizes[2] / HDIM;   // 100
  const int L = in_sizes[3] / (HDIM * HDIM);  // 2
  const int E_pp = in_sizes[21] / 2;
  const int E_dp = in_sizes[22] / 2;
  const int E_cp = in_sizes[23] / 2;
  const int B = in_sizes[24];          // 8192
  (void)n_in; (void)out_size;

  const int* src_pp = edge_pp;          const int* dst_pp = edge_pp + E_pp;
  const int* src_dp = edge_dp;          const int* dst_dp = edge_dp + E_dp;
  const int* src_cp = edge_cp;          const int* dst_cp = edge_cp + E_cp;
  const int tot_pp = E_pp + NP, tot_dp = E_dp, tot_cp = E_cp;
  int maxN = NP > ND ? NP : ND; if (NC > maxN) maxN = NC;

  // ---------------- workspace
  char* wsb = (char*)d_ws;
  size_t off = 0;
  auto alloc = [&](size_t bytes) -> void* {
    void* p = wsb + off;
    off += (bytes + 255) & ~(size_t)255;
    return p;
  };

  float* Xp  = (float*)alloc((size_t)NP * HDIM * 4);    // protein state fp32
  ushort* Xpb = (ushort*)alloc((size_t)NP * HDIM * 2);  // protein state bf16 (gather)
  float* Xd  = (float*)alloc((size_t)ND * HDIM * 4);
  float* Xc  = (float*)alloc((size_t)NC * HDIM * 4);
  ushort* xdnh = (ushort*)alloc((size_t)ND * HDIM * 2);
  ushort* xdnl = (ushort*)alloc((size_t)ND * HDIM * 2);
  ushort* xcnh = (ushort*)alloc((size_t)NC * HDIM * 2);
  ushort* xcnl = (ushort*)alloc((size_t)NC * HDIM * 2);
  ushort* WTpph = (ushort*)alloc((size_t)L * HDIM * HDIM * 2);
  ushort* WTppl = (ushort*)alloc((size_t)L * HDIM * HDIM * 2);
  ushort* WTdph = (ushort*)alloc((size_t)L * HDIM * HDIM * 2);
  ushort* WTdpl = (ushort*)alloc((size_t)L * HDIM * HDIM * 2);
  ushort* WTcph = (ushort*)alloc((size_t)L * HDIM * HDIM * 2);
  ushort* WTcpl = (ushort*)alloc((size_t)L * HDIM * HDIM * 2);
  ushort* cth = (ushort*)alloc((size_t)NC * HDIM * 2);  // cp split staging
  ushort* ctl = (ushort*)alloc((size_t)NC * HDIM * 2);
  float* wv  = (float*)alloc((size_t)L * 6 * HDIM * 4); // folded W@a vectors
  float* pals = (float*)alloc((size_t)maxN * 4);        // pp src logits
  float* pald = (float*)alloc((size_t)maxN * 4);        // pp dst logits
  float* als1 = (float*)alloc((size_t)maxN * 4);        // dp src logits
  float* als2 = (float*)alloc((size_t)maxN * 4);        // cp src logits
  float* ald1 = (float*)alloc((size_t)maxN * 4);
  float* ald2 = (float*)alloc((size_t)maxN * 4);
  int* binsum = (int*)alloc((size_t)maxN * 4);
  int* rp_pp = (int*)alloc((size_t)(NP + 1) * 4);
  int* rp_dp = (int*)alloc((size_t)(ND + 1) * 4);
  int* rp_cp = (int*)alloc((size_t)(NC + 1) * 4);
  uint* sd_pp = (uint*)alloc((size_t)tot_pp * 4);
  uint* sd_dp = (uint*)alloc((size_t)tot_dp * 4);
  uint* sd_cp = (uint*)alloc((size_t)tot_cp * 4);
  float* out32 = (float*)alloc((size_t)NC * HDIM * 4);  // cp partial accumulator
  size_t S0 = off;

  // scratch S overlays: [offs] -> [aggh|aggl|tmp] -> [W1T*|W2T*|P1|P2|P3|h1*]
  int* offs = (int*)(wsb + S0);
  build_sorted(stream, src_pp, dst_pp, E_pp, NP, NP, offs, binsum, rp_pp, sd_pp);
  build_sorted(stream, src_dp, dst_dp, E_dp, 0, ND, offs, binsum, rp_dp, sd_dp);
  build_sorted(stream, src_cp, dst_cp, E_cp, 0, NC, offs, binsum, rp_cp, sd_cp);

  // ---- folded attention vectors (wv must precede prep_p's dots)
  matvec_all_kernel<<<L * 6, 256, 0, stream>>>(W_pp, as_pp, ad_pp, W_dp, as_dp, ad_dp,
                                               W_cp, as_cp, ad_cp, wv);
  // ---- weight split planes + layer-0 protein prep, ONE launch
  {
    int c1 = cdiv(3 * L * HDIM * HDIM, 256);
    int btot = c1 + cdiv(NP, 4);
    wconv_prep_kernel<<<btot, 256, 0, stream>>>(
        W_pp, W_dp, W_cp, WTpph, WTppl, WTdph, WTdpl, WTcph, WTcpl, L,
        prot_emb, Xpb, wv + 0 * HDIM, wv + 1 * HDIM, pals, pald, NP, c1);
  }

  size_t aggB = ((size_t)NP * HDIM * 2 + 255) & ~(size_t)255;
  ushort* aggh = (ushort*)(wsb + S0);
  ushort* aggl = (ushort*)(wsb + S0 + aggB);
  float* tmp = (float*)(wsb + S0 + 2 * aggB);

  for (int l = 0; l < L; ++l) {
    const int WOFF = l * HDIM * HDIM, VOFF = l * HDIM;
    const float* wvl = wv + (size_t)l * 6 * HDIM;
    bool last = (l == L - 1);
    const float* wvn = last ? wvl : wv + (size_t)(l + 1) * 6 * HDIM;
    const float* Xd_cur = (l == 0) ? drug_emb : Xd;
    const float* Xc_cur = (l == 0) ? cell_emb : Xc;

    // ---- pp aggregate + dp/cp rowdots + out32 zero, ONE launch
    {
      int bsA = cdiv(NP, 4);
      int bs1 = cdiv(ND, 4), bs2 = bs1 + cdiv(NC, 4);
      int nz = NC * HDIM;
      agg_pp_rdz_kernel<<<bsA + bs2 + cdiv(nz, 256), 256, 0, stream>>>(
          rp_pp, sd_pp, pals, pald, Xpb, aggh, aggl, NP,
          Xd_cur, wvl + 3 * HDIM, ald1, ND,
          Xc_cur, wvl + 5 * HDIM, ald2, NC,
          out32, nz, bsA, bs1, bs2);
    }
    gemm_launch<128, 0>(stream, aggh, aggl, WTpph + WOFF, WTppl + WOFF, HDIM,
                        b_pp + VOFF, tmp, NP, HDIM, HDIM);
    l2norm_f32b_dots_kernel<<<cdiv(NP, 4), 256, 0, stream>>>(
        tmp, Xp, Xpb,
        wvl + 2 * HDIM, wvl + 4 * HDIM,
        last ? nullptr : (wvn + 0 * HDIM), last ? nullptr : (wvn + 1 * HDIM),
        als1, als2, last ? nullptr : pals, last ? nullptr : pald, NP);

    // ---- dp aggregate + cp slice-aggregate, one launch (independent phases)
    {
      int bsplit = cdiv(ND, 4);
      agg_dp_cp_kernel<<<bsplit + NC * SLICES, 256, 0, stream>>>(
          rp_dp, sd_dp, als1, ald1, aggh, aggl, ND, bsplit,
          rp_cp, sd_cp, als2, ald2, out32, NC, Xpb);
    }

    // ---- cp split (tiny), then dp-GEMM + cp-GEMM in ONE segmented launch
    f32_to_split_kernel<<<cdiv(NC * HDIM, 256), 256, 0, stream>>>(out32, cth, ctl, NC * HDIM);
    {
      int mbd = cdiv(ND, 64), mbc = cdiv(NC, 64);
      int bd = mbd * (HDIM / TBN);          // dp blocks (M fast)
      int bc = mbc * (HDIM / TBN);          // cp blocks
      GArg gd{aggh, aggl, WTdph + WOFF, WTdpl + WOFF, b_dp + VOFF, Xd,
              HDIM, ND, HDIM, HDIM, mbd};
      GArg gc{cth, ctl, WTcph + WOFF, WTcpl + WOFF, b_cp + VOFF, Xc,
              HDIM, NC, HDIM, HDIM, mbc};
      mfma_gemm_seg3<64, 1><<<bd + bc, 256, 0, stream>>>(gd, gc, gc, bd, bd + bc);
    }
  }

  // ---------------- head
  const int N1 = 6 * HDIM;   // 1536
  const int N2 = 2 * HDIM;   // 512
  const int K1 = 3 * HDIM;   // 768
  ushort* W1Th = (ushort*)(wsb + S0);                   // [1536][768]
  ushort* W1Tl = W1Th + (size_t)N1 * K1;
  ushort* W2Th = W1Tl + (size_t)N1 * K1;                // [512][1536]
  ushort* W2Tl = W2Th + (size_t)N2 * N1;
  float* P1 = (float*)(W2Tl + (size_t)N2 * N1);         // [ND][1536]
  float* P2 = P1 + (size_t)ND * N1;
  float* P3 = P2 + (size_t)ND * N1;                     // [NC][1536]
  ushort* h1h = (ushort*)(P3 + (size_t)NC * N1);        // [CH][1536] split
  size_t wsz = ws_size ? ws_size : ((size_t)1 << 30);
  size_t fixed = S0 + ((size_t)N1 * K1 + (size_t)N2 * N1) * 4
               + ((size_t)(2 * ND + NC) * N1) * 4;
  int CH = 8192;
  while (CH > 1024 && fixed + (size_t)CH * N1 * 4 > wsz) CH >>= 1;
  ushort* h1l = h1h + (size_t)CH * N1;

  // l2norm-split (drug+cell) + wconv(W1) + wconv(W2), ONE launch
  {
    int bs1 = cdiv(ND, 4);
    int bs2 = bs1 + cdiv(NC, 4);
    int bs3 = bs2 + cdiv(K1 * N1, 256);
    int btot = bs3 + cdiv(N1 * N2, 256);
    head_prep_kernel<<<btot, 256, 0, stream>>>(
        Xd, xdnh, xdnl, ND, Xc, xcnh, xcnl, NC,
        W1, W1Th, W1Tl, K1, N1, W2, W2Th, W2Tl, N2, bs1, bs2, bs3);
  }

  // P1 + P2 + P3 GEMMs in ONE segmented launch (independent outputs)
  {
    int mbd = cdiv(ND, 64), mbc = cdiv(NC, 64);
    int q1 = mbd * (N1 / TBN);            // 32*24 = 768
    int q3 = mbc * (N1 / TBN);            // 2*24 = 48
    GArg p1a{xdnh, xdnl, W1Th, W1Tl, nullptr, P1, K1, ND, N1, HDIM, mbd};
    GArg p2a{xdnh, xdnl, W1Th + HDIM, W1Tl + HDIM, nullptr, P2, K1, ND, N1, HDIM, mbd};
    GArg p3a{xcnh, xcnl, W1Th + 2 * HDIM, W1Tl + 2 * HDIM, b1, P3, K1, NC, N1, HDIM, mbc};
    mfma_gemm_seg3<64, 0><<<q1 + q1 + q3, 256, 0, stream>>>(p1a, p2a, p3a, q1, 2 * q1);
  }

  float* outp = (float*)d_out;
  for (int c0 = 0; c0 < B; c0 += CH) {
    int M = (B - c0) < CH ? (B - c0) : CH;
    int bsC = cdiv(M * (N1 / 4), 256);
    int fillB = (c0 == 0) ? cdiv(B, 256) : 0;   // b3-prefill once, before first W2
    combine_h1_fill_kernel<<<bsC + fillB, 256, 0, stream>>>(
        P1, P2, P3, drug1, drug2, cellb, c0, h1h, h1l, M, N1,
        outp, b3, (c0 == 0) ? B : 0, bsC);
    gemm_launch_f3(stream, h1h, h1l, W2Th, W2Tl, N1, b2, W3,
                   outp + (size_t)c0 * 2, M, N2, N1);
  }
}